// Round 1
// baseline (2504.865 us; speedup 1.0000x reference)
//
#include <hip/hip_runtime.h>
#include <hip/hip_bf16.h>
#include <math.h>

#define BB 8
#define NN 2048
#define KK 20

// ---------------------------------------------------------------------------
// top-K (K=20) smallest-value tracker, fully register-resident (unrolled
// scans keep all indexing compile-time so nothing spills to scratch).
// Strict < keeps the earliest m on ties -> matches jax.lax.top_k tie-break.
// ---------------------------------------------------------------------------
__device__ __forceinline__ void topk_insert(float d, int m, float (&bd)[KK], int (&bi)[KK],
                                            float& worst, int& wslot) {
  if (d < worst) {
#pragma unroll
    for (int j = 0; j < KK; ++j) {
      if (j == wslot) { bd[j] = d; bi[j] = m; }
    }
    float w = -INFINITY;
    int s = 0;
#pragma unroll
    for (int j = 0; j < KK; ++j) {
      if (bd[j] > w) { w = bd[j]; s = j; }
    }
    worst = w;
    wslot = s;
  }
}

// ---------------------------------------------------------------------------
// kNN for conv1 (D=3): whole cloud staged in LDS (32 KB), one thread per point.
// ---------------------------------------------------------------------------
__global__ __launch_bounds__(256) void knn1_kernel(const float* __restrict__ pos,
                                                   int* __restrict__ idx1) {
  __shared__ float xs0[NN], xs1[NN], xs2[NN], ss[NN];
  const int b = blockIdx.x >> 3;
  const int chunk = blockIdx.x & 7;
  const int t = threadIdx.x;
  const float* posb = pos + (size_t)b * NN * 3;
  for (int i = t; i < NN; i += 256) {
    const float a0 = posb[i * 3 + 0];
    const float a1 = posb[i * 3 + 1];
    const float a2 = posb[i * 3 + 2];
    xs0[i] = a0; xs1[i] = a1; xs2[i] = a2;
    ss[i] = a0 * a0 + a1 * a1 + a2 * a2;
  }
  __syncthreads();
  const int n = chunk * 256 + t;
  const float xn0 = xs0[n], xn1 = xs1[n], xn2 = xs2[n], sn = ss[n];
  float bd[KK]; int bi[KK];
#pragma unroll
  for (int j = 0; j < KK; ++j) { bd[j] = INFINITY; bi[j] = 0; }
  float worst = INFINITY;
  int wslot = 0;
  for (int m = 0; m < NN; m += 8) {
    float dv[8];
#pragma unroll
    for (int u = 0; u < 8; ++u) {
      const int mm = m + u;
      // same expression shape as ss -> diagonal is (numerically) ~0
      dv[u] = sn + ss[mm] - 2.f * (xn0 * xs0[mm] + xn1 * xs1[mm] + xn2 * xs2[mm]);
    }
#pragma unroll
    for (int u = 0; u < 8; ++u) topk_insert(dv[u], m + u, bd, bi, worst, wslot);
  }
  int* op = idx1 + (size_t)(b * NN + n) * KK;
#pragma unroll
  for (int j = 0; j < KK; ++j) op[j] = bi[j];
}

// ---------------------------------------------------------------------------
// conv1 fused EdgeConv: one 64-thread block per point. Thread c owns output
// channel c; acc[k] register-blocks the 20 edges so each weight is read once
// per block. Edge/hidden activations live transposed in LDS ([d][k], k-padded
// to 24 so float4 reads stay 16B-aligned).
// ---------------------------------------------------------------------------
__global__ __launch_bounds__(64) void conv1_kernel(
    const float* __restrict__ pos, const int* __restrict__ idx,
    const float* __restrict__ w1, const float* __restrict__ b1,
    const float* __restrict__ w2, const float* __restrict__ b2,
    const float* __restrict__ w3, const float* __restrict__ b3,
    float* __restrict__ xout) {
  __shared__ float et[6][24];
  __shared__ float h1t[64][24];
  __shared__ float h2t[64][24];
  const int g = blockIdx.x;
  const int b = g >> 11, n = g & 2047;
  const float* posb = pos + (size_t)b * NN * 3;
  const int t = threadIdx.x;

  for (int item = t; item < 6 * KK; item += 64) {
    const int k = item / 6, d = item % 6;
    const int j = idx[(size_t)g * KK + k];
    float v;
    if (d < 3) v = posb[n * 3 + d];
    else v = posb[j * 3 + (d - 3)] - posb[n * 3 + (d - 3)];
    et[d][k] = v;
  }
  __syncthreads();

  const int c = t;
  float acc[KK];

  // layer 1: 6 -> 64
#pragma unroll
  for (int k = 0; k < KK; ++k) acc[k] = 0.f;
#pragma unroll
  for (int d = 0; d < 6; ++d) {
    const float w = w1[d * 64 + c];
#pragma unroll
    for (int q = 0; q < 5; ++q) {
      const float4 ev = *(const float4*)&et[d][q * 4];
      acc[q * 4 + 0] = fmaf(ev.x, w, acc[q * 4 + 0]);
      acc[q * 4 + 1] = fmaf(ev.y, w, acc[q * 4 + 1]);
      acc[q * 4 + 2] = fmaf(ev.z, w, acc[q * 4 + 2]);
      acc[q * 4 + 3] = fmaf(ev.w, w, acc[q * 4 + 3]);
    }
  }
  {
    const float bias = b1[c];
#pragma unroll
    for (int q = 0; q < 5; ++q) {
      float4 o;
      o.x = fmaxf(acc[q * 4 + 0] + bias, 0.f);
      o.y = fmaxf(acc[q * 4 + 1] + bias, 0.f);
      o.z = fmaxf(acc[q * 4 + 2] + bias, 0.f);
      o.w = fmaxf(acc[q * 4 + 3] + bias, 0.f);
      *(float4*)&h1t[c][q * 4] = o;
    }
  }
  __syncthreads();

  // layer 2: 64 -> 64
#pragma unroll
  for (int k = 0; k < KK; ++k) acc[k] = 0.f;
  for (int d = 0; d < 64; ++d) {
    const float w = w2[d * 64 + c];
#pragma unroll
    for (int q = 0; q < 5; ++q) {
      const float4 ev = *(const float4*)&h1t[d][q * 4];
      acc[q * 4 + 0] = fmaf(ev.x, w, acc[q * 4 + 0]);
      acc[q * 4 + 1] = fmaf(ev.y, w, acc[q * 4 + 1]);
      acc[q * 4 + 2] = fmaf(ev.z, w, acc[q * 4 + 2]);
      acc[q * 4 + 3] = fmaf(ev.w, w, acc[q * 4 + 3]);
    }
  }
  {
    const float bias = b2[c];
#pragma unroll
    for (int q = 0; q < 5; ++q) {
      float4 o;
      o.x = fmaxf(acc[q * 4 + 0] + bias, 0.f);
      o.y = fmaxf(acc[q * 4 + 1] + bias, 0.f);
      o.z = fmaxf(acc[q * 4 + 2] + bias, 0.f);
      o.w = fmaxf(acc[q * 4 + 3] + bias, 0.f);
      *(float4*)&h2t[c][q * 4] = o;
    }
  }
  __syncthreads();

  // layer 3: 64 -> 64, then max over k
#pragma unroll
  for (int k = 0; k < KK; ++k) acc[k] = 0.f;
  for (int d = 0; d < 64; ++d) {
    const float w = w3[d * 64 + c];
#pragma unroll
    for (int q = 0; q < 5; ++q) {
      const float4 ev = *(const float4*)&h2t[d][q * 4];
      acc[q * 4 + 0] = fmaf(ev.x, w, acc[q * 4 + 0]);
      acc[q * 4 + 1] = fmaf(ev.y, w, acc[q * 4 + 1]);
      acc[q * 4 + 2] = fmaf(ev.z, w, acc[q * 4 + 2]);
      acc[q * 4 + 3] = fmaf(ev.w, w, acc[q * 4 + 3]);
    }
  }
  {
    const float bias = b3[c];
    float mx = 0.f;  // relu outputs are >= 0
#pragma unroll
    for (int k = 0; k < KK; ++k) mx = fmaxf(mx, fmaxf(acc[k] + bias, 0.f));
    xout[(size_t)g * 64 + c] = mx;
  }
}

// ---------------------------------------------------------------------------
// d2 for conv2 kNN: per-cloud 128x128 tiles, 8x8 per thread, D=64 staged in
// LDS transposed. Self-dot computed with the identical fma chain as the dot
// accumulation -> diagonal is exactly 0 (matching reference self-distance).
// ---------------------------------------------------------------------------
__global__ __launch_bounds__(256) void d2_kernel(const float* __restrict__ x1,
                                                 float* __restrict__ d2) {
  __shared__ float At[64][132];
  __shared__ float Bt[64][132];
  __shared__ float sA[128], sB[128];
  const int bid = blockIdx.x;
  const int b = bid >> 8;
  const int tile = bid & 255;
  const int ti = tile >> 4, tj = tile & 15;
  const int i0 = ti * 128, j0 = tj * 128;
  const float* xb = x1 + (size_t)b * NN * 64;
  const int t = threadIdx.x;
  for (int item = t; item < 8192; item += 256) {
    const int r = item >> 6, d = item & 63;
    At[d][r] = xb[(size_t)(i0 + r) * 64 + d];
    Bt[d][r] = xb[(size_t)(j0 + r) * 64 + d];
  }
  __syncthreads();
  if (t < 128) {
    float s = 0.f;
    for (int k = 0; k < 64; ++k) s = fmaf(At[k][t], At[k][t], s);
    sA[t] = s;
  } else {
    const int r = t - 128;
    float s = 0.f;
    for (int k = 0; k < 64; ++k) s = fmaf(Bt[k][r], Bt[k][r], s);
    sB[r] = s;
  }
  __syncthreads();
  const int tx = t & 15, ty = t >> 4;
  float acc[8][8];
#pragma unroll
  for (int u = 0; u < 8; ++u)
#pragma unroll
    for (int v = 0; v < 8; ++v) acc[u][v] = 0.f;
  for (int k = 0; k < 64; ++k) {
    float a[8], bb[8];
#pragma unroll
    for (int u = 0; u < 8; ++u) a[u] = At[k][ty * 8 + u];
#pragma unroll
    for (int v = 0; v < 8; ++v) bb[v] = Bt[k][tx * 8 + v];
#pragma unroll
    for (int u = 0; u < 8; ++u)
#pragma unroll
      for (int v = 0; v < 8; ++v) acc[u][v] = fmaf(a[u], bb[v], acc[u][v]);
  }
  float* dout = d2 + (size_t)b * NN * NN;
#pragma unroll
  for (int u = 0; u < 8; ++u) {
    const int i = ty * 8 + u;
    const float si = sA[i];
    float4 o0, o1;
    o0.x = si + sB[tx * 8 + 0] - 2.f * acc[u][0];
    o0.y = si + sB[tx * 8 + 1] - 2.f * acc[u][1];
    o0.z = si + sB[tx * 8 + 2] - 2.f * acc[u][2];
    o0.w = si + sB[tx * 8 + 3] - 2.f * acc[u][3];
    o1.x = si + sB[tx * 8 + 4] - 2.f * acc[u][4];
    o1.y = si + sB[tx * 8 + 5] - 2.f * acc[u][5];
    o1.z = si + sB[tx * 8 + 6] - 2.f * acc[u][6];
    o1.w = si + sB[tx * 8 + 7] - 2.f * acc[u][7];
    float* wp = &dout[(size_t)(i0 + i) * NN + j0 + tx * 8];
    *(float4*)wp = o0;
    *(float4*)(wp + 4) = o1;
  }
}

// ---------------------------------------------------------------------------
// selection for conv2: d2 is symmetric, so thread n scans COLUMN n (coalesced
// across consecutive threads) keeping the top-20 smallest.
// ---------------------------------------------------------------------------
__global__ __launch_bounds__(256) void select2_kernel(const float* __restrict__ d2,
                                                      int* __restrict__ idx2) {
  const int gid = blockIdx.x * 256 + threadIdx.x;
  const int b = gid >> 11, n = gid & 2047;
  const float* col = d2 + (size_t)b * NN * NN + n;
  float bd[KK]; int bi[KK];
#pragma unroll
  for (int j = 0; j < KK; ++j) { bd[j] = INFINITY; bi[j] = 0; }
  float worst = INFINITY;
  int wslot = 0;
  for (int m = 0; m < NN; m += 8) {
    float dv[8];
#pragma unroll
    for (int u = 0; u < 8; ++u) dv[u] = col[(size_t)(m + u) * NN];
#pragma unroll
    for (int u = 0; u < 8; ++u) topk_insert(dv[u], m + u, bd, bi, worst, wslot);
  }
  int* op = idx2 + (size_t)gid * KK;
#pragma unroll
  for (int j = 0; j < KK; ++j) op[j] = bi[j];
}

// ---------------------------------------------------------------------------
// conv2 fused EdgeConv: one 256-thread block per point. 128-wide layers split
// the d-range across two thread-halves (combined in LDS); layer 3 (256-wide)
// is one thread per channel. Weights stream from global (L2-resident, reused
// by all 20 edges via acc[20] register blocking).
// ---------------------------------------------------------------------------
__global__ __launch_bounds__(256) void conv2_kernel(
    const float* __restrict__ x1, const int* __restrict__ idx,
    const float* __restrict__ w1, const float* __restrict__ b1,
    const float* __restrict__ w2, const float* __restrict__ b2,
    const float* __restrict__ w3, const float* __restrict__ b3,
    float* __restrict__ xout) {
  __shared__ float et[128][24];   // edge features, then reused as h2
  __shared__ float h1t[128][24];
  const int g = blockIdx.x;
  const int b = g >> 11, n = g & 2047;
  const float* xb = x1 + (size_t)b * NN * 64;
  const int t = threadIdx.x;

  for (int item = t; item < 128 * KK; item += 256) {
    const int k = item >> 7, d = item & 127;
    const int j = idx[(size_t)g * KK + k];
    float v;
    if (d < 64) v = xb[n * 64 + d];
    else v = xb[j * 64 + (d - 64)] - xb[n * 64 + (d - 64)];
    et[d][k] = v;
  }
  __syncthreads();

  const int c = t & 127;
  const int half = t >> 7;
  float acc[KK];

  // ---- layer 1: 128 -> 128 (et -> h1t)
#pragma unroll
  for (int k = 0; k < KK; ++k) acc[k] = 0.f;
  for (int d = half * 64; d < half * 64 + 64; ++d) {
    const float w = w1[d * 128 + c];
#pragma unroll
    for (int q = 0; q < 5; ++q) {
      const float4 ev = *(const float4*)&et[d][q * 4];
      acc[q * 4 + 0] = fmaf(ev.x, w, acc[q * 4 + 0]);
      acc[q * 4 + 1] = fmaf(ev.y, w, acc[q * 4 + 1]);
      acc[q * 4 + 2] = fmaf(ev.z, w, acc[q * 4 + 2]);
      acc[q * 4 + 3] = fmaf(ev.w, w, acc[q * 4 + 3]);
    }
  }
  if (half == 1) {
#pragma unroll
    for (int q = 0; q < 5; ++q)
      *(float4*)&h1t[c][q * 4] =
          make_float4(acc[q * 4 + 0], acc[q * 4 + 1], acc[q * 4 + 2], acc[q * 4 + 3]);
  }
  __syncthreads();
  if (half == 0) {
    const float bias = b1[c];
#pragma unroll
    for (int q = 0; q < 5; ++q) {
      float4 p = *(const float4*)&h1t[c][q * 4];
      p.x = fmaxf(acc[q * 4 + 0] + p.x + bias, 0.f);
      p.y = fmaxf(acc[q * 4 + 1] + p.y + bias, 0.f);
      p.z = fmaxf(acc[q * 4 + 2] + p.z + bias, 0.f);
      p.w = fmaxf(acc[q * 4 + 3] + p.w + bias, 0.f);
      *(float4*)&h1t[c][q * 4] = p;
    }
  }
  __syncthreads();

  // ---- layer 2: 128 -> 128 (h1t -> et)
#pragma unroll
  for (int k = 0; k < KK; ++k) acc[k] = 0.f;
  for (int d = half * 64; d < half * 64 + 64; ++d) {
    const float w = w2[d * 128 + c];
#pragma unroll
    for (int q = 0; q < 5; ++q) {
      const float4 ev = *(const float4*)&h1t[d][q * 4];
      acc[q * 4 + 0] = fmaf(ev.x, w, acc[q * 4 + 0]);
      acc[q * 4 + 1] = fmaf(ev.y, w, acc[q * 4 + 1]);
      acc[q * 4 + 2] = fmaf(ev.z, w, acc[q * 4 + 2]);
      acc[q * 4 + 3] = fmaf(ev.w, w, acc[q * 4 + 3]);
    }
  }
  if (half == 1) {
#pragma unroll
    for (int q = 0; q < 5; ++q)
      *(float4*)&et[c][q * 4] =
          make_float4(acc[q * 4 + 0], acc[q * 4 + 1], acc[q * 4 + 2], acc[q * 4 + 3]);
  }
  __syncthreads();
  if (half == 0) {
    const float bias = b2[c];
#pragma unroll
    for (int q = 0; q < 5; ++q) {
      float4 p = *(const float4*)&et[c][q * 4];
      p.x = fmaxf(acc[q * 4 + 0] + p.x + bias, 0.f);
      p.y = fmaxf(acc[q * 4 + 1] + p.y + bias, 0.f);
      p.z = fmaxf(acc[q * 4 + 2] + p.z + bias, 0.f);
      p.w = fmaxf(acc[q * 4 + 3] + p.w + bias, 0.f);
      *(float4*)&et[c][q * 4] = p;
    }
  }
  __syncthreads();

  // ---- layer 3: 128 -> 256 (et -> out), max over k
#pragma unroll
  for (int k = 0; k < KK; ++k) acc[k] = 0.f;
  for (int d = 0; d < 128; ++d) {
    const float w = w3[d * 256 + t];
#pragma unroll
    for (int q = 0; q < 5; ++q) {
      const float4 ev = *(const float4*)&et[d][q * 4];
      acc[q * 4 + 0] = fmaf(ev.x, w, acc[q * 4 + 0]);
      acc[q * 4 + 1] = fmaf(ev.y, w, acc[q * 4 + 1]);
      acc[q * 4 + 2] = fmaf(ev.z, w, acc[q * 4 + 2]);
      acc[q * 4 + 3] = fmaf(ev.w, w, acc[q * 4 + 3]);
    }
  }
  {
    const float bias = b3[t];
    float mx = 0.f;
#pragma unroll
    for (int k = 0; k < KK; ++k) mx = fmaxf(mx, fmaxf(acc[k] + bias, 0.f));
    xout[(size_t)g * 256 + t] = mx;
  }
}

// ---------------------------------------------------------------------------
// l0 GEMM + relu + partial global-max-pool.
// Grid: b(8) x cchunk(8, 64 channels each) x pchunk(16, 128 points each).
// ---------------------------------------------------------------------------
__global__ __launch_bounds__(256) void l0_kernel(const float* __restrict__ x2,
                                                 const float* __restrict__ w,
                                                 const float* __restrict__ bias,
                                                 float* __restrict__ gp) {
  __shared__ float wl[256][64];
  __shared__ float red[256];
  const int bid = blockIdx.x;
  const int pchunk = bid & 15;
  const int cchunk = (bid >> 4) & 7;
  const int b = bid >> 7;
  const int t = threadIdx.x;
  for (int item = t; item < 256 * 64; item += 256) {
    const int d = item >> 6, cc = item & 63;
    wl[d][cc] = w[(size_t)d * 512 + cchunk * 64 + cc];
  }
  __syncthreads();
  const int c = t & 63, psub = t >> 6;
  const float bv = bias[cchunk * 64 + c];
  const float* xrow0 = x2 + ((size_t)b * NN + pchunk * 128 + psub * 32) * 256;
  float mx = 0.f;
  for (int p = 0; p < 32; ++p) {
    const float* row = xrow0 + (size_t)p * 256;
    float acc = 0.f;
#pragma unroll 8
    for (int d = 0; d < 256; d += 4) {
      const float4 xv = *(const float4*)&row[d];
      acc = fmaf(xv.x, wl[d][c], acc);
      acc = fmaf(xv.y, wl[d + 1][c], acc);
      acc = fmaf(xv.z, wl[d + 2][c], acc);
      acc = fmaf(xv.w, wl[d + 3][c], acc);
    }
    mx = fmaxf(mx, fmaxf(acc + bv, 0.f));
  }
  red[t] = mx;
  __syncthreads();
  if (t < 64) {
    const float m = fmaxf(fmaxf(red[t], red[t + 64]), fmaxf(red[t + 128], red[t + 192]));
    gp[(size_t)(b * 16 + pchunk) * 512 + cchunk * 64 + t] = m;
  }
}

// ---------------------------------------------------------------------------
// final pool-reduce + classifier head + log_softmax. One block per cloud.
// ---------------------------------------------------------------------------
__global__ __launch_bounds__(256) void head_kernel(
    const float* __restrict__ gp,
    const float* __restrict__ l1w, const float* __restrict__ l1b,
    const float* __restrict__ l2w, const float* __restrict__ l2b,
    const float* __restrict__ l3w, const float* __restrict__ l3b,
    float* __restrict__ out) {
  __shared__ float g[512];
  __shared__ float h1[256];
  __shared__ float h2[256];
  __shared__ float logits[40];
  __shared__ float lse_s;
  const int b = blockIdx.x;
  const int t = threadIdx.x;
  for (int cidx = t; cidx < 512; cidx += 256) {
    float m = gp[(size_t)(b * 16) * 512 + cidx];
    for (int ch = 1; ch < 16; ++ch) m = fmaxf(m, gp[(size_t)(b * 16 + ch) * 512 + cidx]);
    g[cidx] = m;
  }
  __syncthreads();
  {
    float acc = 0.f;
    for (int d = 0; d < 512; d += 4) {
      const float4 gv = *(const float4*)&g[d];
      acc = fmaf(gv.x, l1w[(size_t)d * 256 + t], acc);
      acc = fmaf(gv.y, l1w[(size_t)(d + 1) * 256 + t], acc);
      acc = fmaf(gv.z, l1w[(size_t)(d + 2) * 256 + t], acc);
      acc = fmaf(gv.w, l1w[(size_t)(d + 3) * 256 + t], acc);
    }
    h1[t] = fmaxf(acc + l1b[t], 0.f);
  }
  __syncthreads();
  {
    float acc = 0.f;
    for (int d = 0; d < 256; d += 4) {
      const float4 hv = *(const float4*)&h1[d];
      acc = fmaf(hv.x, l2w[(size_t)d * 256 + t], acc);
      acc = fmaf(hv.y, l2w[(size_t)(d + 1) * 256 + t], acc);
      acc = fmaf(hv.z, l2w[(size_t)(d + 2) * 256 + t], acc);
      acc = fmaf(hv.w, l2w[(size_t)(d + 3) * 256 + t], acc);
    }
    h2[t] = fmaxf(acc + l2b[t], 0.f);
  }
  __syncthreads();
  if (t < 40) {
    float acc = 0.f;
    for (int d = 0; d < 256; ++d) acc = fmaf(h2[d], l3w[(size_t)d * 40 + t], acc);
    logits[t] = acc + l3b[t];
  }
  __syncthreads();
  if (t == 0) {
    float M = -INFINITY;
    for (int j = 0; j < 40; ++j) M = fmaxf(M, logits[j]);
    float ssum = 0.f;
    for (int j = 0; j < 40; ++j) ssum += expf(logits[j] - M);
    lse_s = M + logf(ssum);
  }
  __syncthreads();
  if (t < 40) out[(size_t)b * 40 + t] = logits[t] - lse_s;
}

// ---------------------------------------------------------------------------
extern "C" void kernel_launch(void* const* d_in, const int* in_sizes, int n_in,
                              void* d_out, int out_size, void* d_ws, size_t ws_size,
                              hipStream_t stream) {
  const float* pos  = (const float*)d_in[0];
  // d_in[1] = batch (unused: contiguous equal partition)
  const float* c1w1 = (const float*)d_in[2];
  const float* c1b1 = (const float*)d_in[3];
  const float* c1w2 = (const float*)d_in[4];
  const float* c1b2 = (const float*)d_in[5];
  const float* c1w3 = (const float*)d_in[6];
  const float* c1b3 = (const float*)d_in[7];
  const float* c2w1 = (const float*)d_in[8];
  const float* c2b1 = (const float*)d_in[9];
  const float* c2w2 = (const float*)d_in[10];
  const float* c2b2 = (const float*)d_in[11];
  const float* c2w3 = (const float*)d_in[12];
  const float* c2b3 = (const float*)d_in[13];
  const float* l0w  = (const float*)d_in[14];
  const float* l0b  = (const float*)d_in[15];
  const float* l1w  = (const float*)d_in[16];
  const float* l1b  = (const float*)d_in[17];
  const float* l2w  = (const float*)d_in[18];
  const float* l2b  = (const float*)d_in[19];
  const float* l3w  = (const float*)d_in[20];
  const float* l3b  = (const float*)d_in[21];
  float* out = (float*)d_out;

  char* ws = (char*)d_ws;
  float* x1   = (float*)(ws + 0);                         // 4 MB   [8,2048,64]
  float* x2   = (float*)(ws + ((size_t)4 << 20));         // 16 MB  [8,2048,256]
  int*   idx1 = (int*)  (ws + ((size_t)20 << 20));        // 1.3 MB [8,2048,20]
  int*   idx2 = (int*)  (ws + ((size_t)22 << 20));        // 1.3 MB
  float* gp   = (float*)(ws + ((size_t)24 << 20));        // 256 KB [8,16,512]
  float* d2b  = (float*)(ws + ((size_t)25 << 20));        // 128 MB [8,2048,2048]

  knn1_kernel<<<BB * 8, 256, 0, stream>>>(pos, idx1);
  conv1_kernel<<<BB * NN, 64, 0, stream>>>(pos, idx1, c1w1, c1b1, c1w2, c1b2, c1w3, c1b3, x1);
  d2_kernel<<<BB * 256, 256, 0, stream>>>(x1, d2b);
  select2_kernel<<<BB * NN / 256, 256, 0, stream>>>(d2b, idx2);
  conv2_kernel<<<BB * NN, 256, 0, stream>>>(x1, idx2, c2w1, c2b1, c2w2, c2b2, c2w3, c2b3, x2);
  l0_kernel<<<BB * 8 * 16, 256, 0, stream>>>(x2, l0w, l0b, gp);
  head_kernel<<<BB, 256, 0, stream>>>(gp, l1w, l1b, l2w, l2b, l3w, l3b, out);
}

// Round 2
// 1570.832 us; speedup vs baseline: 1.5946x; 1.5946x over previous
//
#include <hip/hip_runtime.h>
#include <hip/hip_bf16.h>
#include <math.h>

#define BB 8
#define NN 2048
#define KK 20

// ---------------------------------------------------------------------------
// top-K (K=20) smallest-value tracker, fully register-resident.
// Strict < keeps the earliest-seen on ties.
// ---------------------------------------------------------------------------
__device__ __forceinline__ void topk_insert(float d, int m, float (&bd)[KK], int (&bi)[KK],
                                            float& worst, int& wslot) {
  if (d < worst) {
#pragma unroll
    for (int j = 0; j < KK; ++j) {
      if (j == wslot) { bd[j] = d; bi[j] = m; }
    }
    float w = -INFINITY;
    int s = 0;
#pragma unroll
    for (int j = 0; j < KK; ++j) {
      if (bd[j] > w) { w = bd[j]; s = j; }
    }
    worst = w;
    wslot = s;
  }
}

// ---------------------------------------------------------------------------
// kNN pass 1 for conv1 (D=3), m-chunked: grid = 8 clouds x 8 nchunk x 8 mchunk.
// Each thread owns point n, scans 256 m-candidates staged in LDS, writes its
// local top-20 to the chunk candidate buffer (transposed for coalescing).
// ---------------------------------------------------------------------------
__global__ __launch_bounds__(256) void knn1_part(const float* __restrict__ pos,
                                                 float* __restrict__ candd,
                                                 int* __restrict__ candi) {
  __shared__ float xs0[256], xs1[256], xs2[256], ss[256];
  const int bid = blockIdx.x;
  const int b = bid >> 6;
  const int nc = (bid >> 3) & 7;
  const int mc = bid & 7;
  const int t = threadIdx.x;
  const float* posb = pos + (size_t)b * NN * 3;
  {
    const int m = mc * 256 + t;
    const float a0 = posb[m * 3 + 0];
    const float a1 = posb[m * 3 + 1];
    const float a2 = posb[m * 3 + 2];
    xs0[t] = a0; xs1[t] = a1; xs2[t] = a2;
    ss[t] = a0 * a0 + a1 * a1 + a2 * a2;
  }
  __syncthreads();
  const int n = nc * 256 + t;
  const float xn0 = posb[n * 3 + 0];
  const float xn1 = posb[n * 3 + 1];
  const float xn2 = posb[n * 3 + 2];
  const float sn = xn0 * xn0 + xn1 * xn1 + xn2 * xn2;  // same expr as ss -> self-dist exact 0
  float bd[KK]; int bi[KK];
#pragma unroll
  for (int j = 0; j < KK; ++j) { bd[j] = INFINITY; bi[j] = 0; }
  float worst = INFINITY;
  int wslot = 0;
  for (int lm = 0; lm < 256; lm += 8) {
    float dv[8];
#pragma unroll
    for (int u = 0; u < 8; ++u) {
      const int q = lm + u;
      dv[u] = sn + ss[q] - 2.f * (xn0 * xs0[q] + xn1 * xs1[q] + xn2 * xs2[q]);
    }
#pragma unroll
    for (int u = 0; u < 8; ++u) topk_insert(dv[u], mc * 256 + lm + u, bd, bi, worst, wslot);
  }
#pragma unroll
  for (int j = 0; j < KK; ++j) {
    const size_t o = ((size_t)(b * 8 + mc) * KK + j) * 2048 + n;
    candd[o] = bd[j];
    candi[o] = bi[j];
  }
}

// ---------------------------------------------------------------------------
// merge nch chunk-candidate-lists (20 each) per point -> final top-20 indices.
// Candidate layout [b][chunk][j][n] -> loads coalesced across threads.
// ---------------------------------------------------------------------------
__global__ __launch_bounds__(128) void merge_topk(const float* __restrict__ candd,
                                                  const int* __restrict__ candi,
                                                  int* __restrict__ idx_out, int nch) {
  const int gid = blockIdx.x * 128 + threadIdx.x;
  const int b = gid >> 11, n = gid & 2047;
  float bd[KK]; int bi[KK];
#pragma unroll
  for (int j = 0; j < KK; ++j) { bd[j] = INFINITY; bi[j] = 0; }
  float worst = INFINITY;
  int wslot = 0;
  for (int c = 0; c < nch; ++c) {
    const size_t base = ((size_t)(b * nch + c) * KK) * 2048 + n;
#pragma unroll
    for (int j = 0; j < KK; ++j) {
      const float d = candd[base + (size_t)j * 2048];
      const int m = candi[base + (size_t)j * 2048];
      topk_insert(d, m, bd, bi, worst, wslot);
    }
  }
  int* op = idx_out + (size_t)gid * KK;
#pragma unroll
  for (int j = 0; j < KK; ++j) op[j] = bi[j];
}

// ---------------------------------------------------------------------------
// conv1 fused EdgeConv (6->64->64->64, max over 20 edges), 8 points/block.
// 160 edge-rows; threads = 32 rowgrps (5 rows) x 8 colgrps (8 ch).
// Each float4 LDS read feeds 8 fma (register blocking) -> VALU-bound.
// ---------------------------------------------------------------------------
__global__ __launch_bounds__(256) void conv1_kernel(
    const float* __restrict__ pos, const int* __restrict__ idx,
    const float* __restrict__ w1, const float* __restrict__ b1,
    const float* __restrict__ w2, const float* __restrict__ b2,
    const float* __restrict__ w3, const float* __restrict__ b3,
    float* __restrict__ xout) {
  __shared__ float E[160][8];
  __shared__ float H[160][68];
  __shared__ float pm[8][4][64];
  const int bid = blockIdx.x;
  const int b = bid >> 8;               // 256 blocks per cloud
  const int pbase = (bid & 255) * 8;
  const float* posb = pos + (size_t)b * NN * 3;
  const int t = threadIdx.x;
  const int ty = t >> 3, tx = t & 7;
  const int r0 = ty * 5, c0 = tx * 8;

  for (int it = t; it < 960; it += 256) {
    const int r = it / 6, d = it - (it / 6) * 6;
    const int p = r / 20, k = r - (r / 20) * 20;
    const int n = pbase + p;
    const int j = idx[((size_t)b * NN + n) * KK + k];
    float v;
    if (d < 3) v = posb[n * 3 + d];
    else v = posb[j * 3 + (d - 3)] - posb[n * 3 + (d - 3)];
    E[r][d] = v;
  }
  __syncthreads();

  float acc[5][8];
  // ---- layer 1: 6 -> 64
#pragma unroll
  for (int u = 0; u < 5; ++u)
#pragma unroll
    for (int i = 0; i < 8; ++i) acc[u][i] = 0.f;
#pragma unroll
  for (int d0 = 0; d0 < 6; d0 += 2) {
    float2 a2[5];
#pragma unroll
    for (int u = 0; u < 5; ++u) a2[u] = *(const float2*)&E[r0 + u][d0];
#pragma unroll
    for (int dd = 0; dd < 2; ++dd) {
      const float4 wA = *(const float4*)&w1[(size_t)(d0 + dd) * 64 + c0];
      const float4 wB = *(const float4*)&w1[(size_t)(d0 + dd) * 64 + c0 + 4];
#pragma unroll
      for (int u = 0; u < 5; ++u) {
        const float av = dd ? a2[u].y : a2[u].x;
        acc[u][0] = fmaf(av, wA.x, acc[u][0]);
        acc[u][1] = fmaf(av, wA.y, acc[u][1]);
        acc[u][2] = fmaf(av, wA.z, acc[u][2]);
        acc[u][3] = fmaf(av, wA.w, acc[u][3]);
        acc[u][4] = fmaf(av, wB.x, acc[u][4]);
        acc[u][5] = fmaf(av, wB.y, acc[u][5]);
        acc[u][6] = fmaf(av, wB.z, acc[u][6]);
        acc[u][7] = fmaf(av, wB.w, acc[u][7]);
      }
    }
  }
  {
    const float4 bA = *(const float4*)&b1[c0];
    const float4 bB = *(const float4*)&b1[c0 + 4];
#pragma unroll
    for (int u = 0; u < 5; ++u) {
      float4 oA, oB;
      oA.x = fmaxf(acc[u][0] + bA.x, 0.f); oA.y = fmaxf(acc[u][1] + bA.y, 0.f);
      oA.z = fmaxf(acc[u][2] + bA.z, 0.f); oA.w = fmaxf(acc[u][3] + bA.w, 0.f);
      oB.x = fmaxf(acc[u][4] + bB.x, 0.f); oB.y = fmaxf(acc[u][5] + bB.y, 0.f);
      oB.z = fmaxf(acc[u][6] + bB.z, 0.f); oB.w = fmaxf(acc[u][7] + bB.w, 0.f);
      *(float4*)&H[r0 + u][c0] = oA;
      *(float4*)&H[r0 + u][c0 + 4] = oB;
    }
  }
  __syncthreads();

  // ---- layer 2: 64 -> 64 (in-place H)
#pragma unroll
  for (int u = 0; u < 5; ++u)
#pragma unroll
    for (int i = 0; i < 8; ++i) acc[u][i] = 0.f;
  for (int d0 = 0; d0 < 64; d0 += 4) {
    float4 a[5];
#pragma unroll
    for (int u = 0; u < 5; ++u) a[u] = *(const float4*)&H[r0 + u][d0];
#pragma unroll
    for (int dd = 0; dd < 4; ++dd) {
      const float4 wA = *(const float4*)&w2[(size_t)(d0 + dd) * 64 + c0];
      const float4 wB = *(const float4*)&w2[(size_t)(d0 + dd) * 64 + c0 + 4];
#pragma unroll
      for (int u = 0; u < 5; ++u) {
        const float av = (dd == 0) ? a[u].x : (dd == 1) ? a[u].y : (dd == 2) ? a[u].z : a[u].w;
        acc[u][0] = fmaf(av, wA.x, acc[u][0]);
        acc[u][1] = fmaf(av, wA.y, acc[u][1]);
        acc[u][2] = fmaf(av, wA.z, acc[u][2]);
        acc[u][3] = fmaf(av, wA.w, acc[u][3]);
        acc[u][4] = fmaf(av, wB.x, acc[u][4]);
        acc[u][5] = fmaf(av, wB.y, acc[u][5]);
        acc[u][6] = fmaf(av, wB.z, acc[u][6]);
        acc[u][7] = fmaf(av, wB.w, acc[u][7]);
      }
    }
  }
  __syncthreads();
  {
    const float4 bA = *(const float4*)&b2[c0];
    const float4 bB = *(const float4*)&b2[c0 + 4];
#pragma unroll
    for (int u = 0; u < 5; ++u) {
      float4 oA, oB;
      oA.x = fmaxf(acc[u][0] + bA.x, 0.f); oA.y = fmaxf(acc[u][1] + bA.y, 0.f);
      oA.z = fmaxf(acc[u][2] + bA.z, 0.f); oA.w = fmaxf(acc[u][3] + bA.w, 0.f);
      oB.x = fmaxf(acc[u][4] + bB.x, 0.f); oB.y = fmaxf(acc[u][5] + bB.y, 0.f);
      oB.z = fmaxf(acc[u][6] + bB.z, 0.f); oB.w = fmaxf(acc[u][7] + bB.w, 0.f);
      *(float4*)&H[r0 + u][c0] = oA;
      *(float4*)&H[r0 + u][c0 + 4] = oB;
    }
  }
  __syncthreads();

  // ---- layer 3: 64 -> 64, then max over k
#pragma unroll
  for (int u = 0; u < 5; ++u)
#pragma unroll
    for (int i = 0; i < 8; ++i) acc[u][i] = 0.f;
  for (int d0 = 0; d0 < 64; d0 += 4) {
    float4 a[5];
#pragma unroll
    for (int u = 0; u < 5; ++u) a[u] = *(const float4*)&H[r0 + u][d0];
#pragma unroll
    for (int dd = 0; dd < 4; ++dd) {
      const float4 wA = *(const float4*)&w3[(size_t)(d0 + dd) * 64 + c0];
      const float4 wB = *(const float4*)&w3[(size_t)(d0 + dd) * 64 + c0 + 4];
#pragma unroll
      for (int u = 0; u < 5; ++u) {
        const float av = (dd == 0) ? a[u].x : (dd == 1) ? a[u].y : (dd == 2) ? a[u].z : a[u].w;
        acc[u][0] = fmaf(av, wA.x, acc[u][0]);
        acc[u][1] = fmaf(av, wA.y, acc[u][1]);
        acc[u][2] = fmaf(av, wA.z, acc[u][2]);
        acc[u][3] = fmaf(av, wA.w, acc[u][3]);
        acc[u][4] = fmaf(av, wB.x, acc[u][4]);
        acc[u][5] = fmaf(av, wB.y, acc[u][5]);
        acc[u][6] = fmaf(av, wB.z, acc[u][6]);
        acc[u][7] = fmaf(av, wB.w, acc[u][7]);
      }
    }
  }
  {
    const int p = ty >> 2, sub = ty & 3;
    float4 m0, m1;
    m0.x = fmaxf(fmaxf(fmaxf(acc[0][0], acc[1][0]), fmaxf(acc[2][0], acc[3][0])), acc[4][0]);
    m0.y = fmaxf(fmaxf(fmaxf(acc[0][1], acc[1][1]), fmaxf(acc[2][1], acc[3][1])), acc[4][1]);
    m0.z = fmaxf(fmaxf(fmaxf(acc[0][2], acc[1][2]), fmaxf(acc[2][2], acc[3][2])), acc[4][2]);
    m0.w = fmaxf(fmaxf(fmaxf(acc[0][3], acc[1][3]), fmaxf(acc[2][3], acc[3][3])), acc[4][3]);
    m1.x = fmaxf(fmaxf(fmaxf(acc[0][4], acc[1][4]), fmaxf(acc[2][4], acc[3][4])), acc[4][4]);
    m1.y = fmaxf(fmaxf(fmaxf(acc[0][5], acc[1][5]), fmaxf(acc[2][5], acc[3][5])), acc[4][5]);
    m1.z = fmaxf(fmaxf(fmaxf(acc[0][6], acc[1][6]), fmaxf(acc[2][6], acc[3][6])), acc[4][6]);
    m1.w = fmaxf(fmaxf(fmaxf(acc[0][7], acc[1][7]), fmaxf(acc[2][7], acc[3][7])), acc[4][7]);
    *(float4*)&pm[p][sub][c0] = m0;
    *(float4*)&pm[p][sub][c0 + 4] = m1;
  }
  __syncthreads();
  {
    const int pp = t >> 5;
    const int cc = (t & 31) * 2;
    float m0 = fmaxf(fmaxf(pm[pp][0][cc], pm[pp][1][cc]), fmaxf(pm[pp][2][cc], pm[pp][3][cc]));
    float m1 = fmaxf(fmaxf(pm[pp][0][cc + 1], pm[pp][1][cc + 1]),
                     fmaxf(pm[pp][2][cc + 1], pm[pp][3][cc + 1]));
    float2 o;
    o.x = fmaxf(m0 + b3[cc], 0.f);
    o.y = fmaxf(m1 + b3[cc + 1], 0.f);
    *(float2*)&xout[((size_t)b * NN + pbase + pp) * 64 + cc] = o;
  }
}

// ---------------------------------------------------------------------------
// d2 + fused partial selection for conv2 kNN. Per 128x128 tile: GEMM in regs,
// d-values into LDS tile T, then per-column top-20 over the tile's 128 rows
// (2 threads/column, pair-merged via shfl_xor). No d2 matrix materialized.
// ---------------------------------------------------------------------------
__global__ __launch_bounds__(256) void d2sel_kernel(const float* __restrict__ x1,
                                                    float* __restrict__ candd,
                                                    int* __restrict__ candi) {
  __shared__ __align__(16) float U[16896];   // At[64][132]+Bt[64][132]  |  T[128][131]
  float (*At)[132] = (float(*)[132])U;
  float (*Bt)[132] = (float(*)[132])(U + 64 * 132);
  float (*T)[131] = (float(*)[131])U;
  __shared__ float sA[128], sB[128];
  const int bid = blockIdx.x;
  const int b = bid >> 8;
  const int tile = bid & 255;
  const int ti = tile >> 4, tj = tile & 15;
  const int i0 = ti * 128, j0 = tj * 128;
  const float* xb = x1 + (size_t)b * NN * 64;
  const int t = threadIdx.x;
  for (int item = t; item < 8192; item += 256) {
    const int r = item >> 6, d = item & 63;
    At[d][r] = xb[(size_t)(i0 + r) * 64 + d];
    Bt[d][r] = xb[(size_t)(j0 + r) * 64 + d];
  }
  __syncthreads();
  if (t < 128) {
    float s = 0.f;
    for (int k = 0; k < 64; ++k) s = fmaf(At[k][t], At[k][t], s);
    sA[t] = s;
  } else {
    const int r = t - 128;
    float s = 0.f;
    for (int k = 0; k < 64; ++k) s = fmaf(Bt[k][r], Bt[k][r], s);
    sB[r] = s;
  }
  __syncthreads();
  const int tx = t & 15, ty = t >> 4;
  float acc[8][8];
#pragma unroll
  for (int u = 0; u < 8; ++u)
#pragma unroll
    for (int v = 0; v < 8; ++v) acc[u][v] = 0.f;
  for (int k = 0; k < 64; ++k) {
    const float4 a0 = *(const float4*)&At[k][ty * 8];
    const float4 a1 = *(const float4*)&At[k][ty * 8 + 4];
    const float4 b0 = *(const float4*)&Bt[k][tx * 8];
    const float4 b1 = *(const float4*)&Bt[k][tx * 8 + 4];
    const float av[8] = {a0.x, a0.y, a0.z, a0.w, a1.x, a1.y, a1.z, a1.w};
    const float bv[8] = {b0.x, b0.y, b0.z, b0.w, b1.x, b1.y, b1.z, b1.w};
#pragma unroll
    for (int u = 0; u < 8; ++u)
#pragma unroll
      for (int v = 0; v < 8; ++v) acc[u][v] = fmaf(av[u], bv[v], acc[u][v]);
  }
  __syncthreads();   // all At/Bt reads done before T overwrites the union
  {
#pragma unroll
    for (int u = 0; u < 8; ++u) {
      const int i = ty * 8 + u;
      const float si = sA[i];
#pragma unroll
      for (int v = 0; v < 8; ++v) {
        T[i][tx * 8 + v] = si + sB[tx * 8 + v] - 2.f * acc[u][v];
      }
    }
  }
  __syncthreads();
  // selection: column j = t>>1, half h = t&1 scans 64 rows
  const int j = t >> 1, h = t & 1;
  float bd[KK]; int bi[KK];
#pragma unroll
  for (int q = 0; q < KK; ++q) { bd[q] = INFINITY; bi[q] = 0; }
  float worst = INFINITY;
  int wslot = 0;
  const int mbase = i0 + h * 64;
  for (int r = 0; r < 64; ++r) {
    topk_insert(T[h * 64 + r][j], mbase + r, bd, bi, worst, wslot);
  }
  // pair-merge: h=0 absorbs h=1's list (higher m inserted later -> tie pref ok)
  float od[KK]; int oi[KK];
#pragma unroll
  for (int q = 0; q < KK; ++q) {
    od[q] = __shfl_xor(bd[q], 1);
    oi[q] = __shfl_xor(bi[q], 1);
  }
#pragma unroll
  for (int q = 0; q < KK; ++q) topk_insert(od[q], oi[q], bd, bi, worst, wslot);
  if (h == 0) {
#pragma unroll
    for (int q = 0; q < KK; ++q) {
      const size_t o = ((size_t)(b * 16 + ti) * KK + q) * 2048 + (j0 + j);
      candd[o] = bd[q];
      candi[o] = bi[q];
    }
  }
}

// ---------------------------------------------------------------------------
// conv2 fused EdgeConv (128->128->128->256, max over 20 edges), 4 points/blk.
// 80 edge-rows; threads = 16 rowgrps (5 rows) x 16 colgrps (8/16 ch).
// ---------------------------------------------------------------------------
__global__ __launch_bounds__(256) void conv2_kernel(
    const float* __restrict__ x1, const int* __restrict__ idx,
    const float* __restrict__ w1, const float* __restrict__ b1,
    const float* __restrict__ w2, const float* __restrict__ b2,
    const float* __restrict__ w3, const float* __restrict__ b3,
    float* __restrict__ xout) {
  __shared__ float A[80][132];
  __shared__ float pm[4][4][256];
  const int bid = blockIdx.x;
  const int b = bid >> 9;               // 512 blocks per cloud
  const int pbase = (bid & 511) * 4;
  const float* xb = x1 + (size_t)b * NN * 64;
  const int t = threadIdx.x;
  const int ty = t >> 4, tx = t & 15;
  const int r0 = ty * 5, c0 = tx * 8;

  for (int it = t; it < 2560; it += 256) {
    const int r = it >> 5, q = it & 31;
    const int p = r / 20, k = r - (r / 20) * 20;
    const int n = pbase + p;
    const int j = idx[((size_t)b * NN + n) * KK + k];
    float4 v;
    if (q < 16) {
      v = *(const float4*)&xb[(size_t)n * 64 + q * 4];
    } else {
      const int d0 = (q - 16) * 4;
      const float4 aa = *(const float4*)&xb[(size_t)j * 64 + d0];
      const float4 cc = *(const float4*)&xb[(size_t)n * 64 + d0];
      v = make_float4(aa.x - cc.x, aa.y - cc.y, aa.z - cc.z, aa.w - cc.w);
    }
    *(float4*)&A[r][q * 4] = v;
  }
  __syncthreads();

  // ---- layers 1 & 2 (128 -> 128, in-place A)
  for (int layer = 0; layer < 2; ++layer) {
    const float* W = layer ? w2 : w1;
    const float* Bv = layer ? b2 : b1;
    float acc[5][8];
#pragma unroll
    for (int u = 0; u < 5; ++u)
#pragma unroll
      for (int i = 0; i < 8; ++i) acc[u][i] = 0.f;
    for (int d0 = 0; d0 < 128; d0 += 4) {
      float4 a[5];
#pragma unroll
      for (int u = 0; u < 5; ++u) a[u] = *(const float4*)&A[r0 + u][d0];
#pragma unroll
      for (int dd = 0; dd < 4; ++dd) {
        const float4 wA = *(const float4*)&W[(size_t)(d0 + dd) * 128 + c0];
        const float4 wB = *(const float4*)&W[(size_t)(d0 + dd) * 128 + c0 + 4];
#pragma unroll
        for (int u = 0; u < 5; ++u) {
          const float av = (dd == 0) ? a[u].x : (dd == 1) ? a[u].y : (dd == 2) ? a[u].z : a[u].w;
          acc[u][0] = fmaf(av, wA.x, acc[u][0]);
          acc[u][1] = fmaf(av, wA.y, acc[u][1]);
          acc[u][2] = fmaf(av, wA.z, acc[u][2]);
          acc[u][3] = fmaf(av, wA.w, acc[u][3]);
          acc[u][4] = fmaf(av, wB.x, acc[u][4]);
          acc[u][5] = fmaf(av, wB.y, acc[u][5]);
          acc[u][6] = fmaf(av, wB.z, acc[u][6]);
          acc[u][7] = fmaf(av, wB.w, acc[u][7]);
        }
      }
    }
    __syncthreads();
    {
      const float4 bA = *(const float4*)&Bv[c0];
      const float4 bB = *(const float4*)&Bv[c0 + 4];
#pragma unroll
      for (int u = 0; u < 5; ++u) {
        float4 oA, oB;
        oA.x = fmaxf(acc[u][0] + bA.x, 0.f); oA.y = fmaxf(acc[u][1] + bA.y, 0.f);
        oA.z = fmaxf(acc[u][2] + bA.z, 0.f); oA.w = fmaxf(acc[u][3] + bA.w, 0.f);
        oB.x = fmaxf(acc[u][4] + bB.x, 0.f); oB.y = fmaxf(acc[u][5] + bB.y, 0.f);
        oB.z = fmaxf(acc[u][6] + bB.z, 0.f); oB.w = fmaxf(acc[u][7] + bB.w, 0.f);
        *(float4*)&A[r0 + u][c0] = oA;
        *(float4*)&A[r0 + u][c0 + 4] = oB;
      }
    }
    __syncthreads();
  }

  // ---- layer 3: 128 -> 256, then max over k
  {
    float acc3[5][16];
#pragma unroll
    for (int u = 0; u < 5; ++u)
#pragma unroll
      for (int i = 0; i < 16; ++i) acc3[u][i] = 0.f;
    const int c3 = tx * 16;
    for (int d0 = 0; d0 < 128; d0 += 4) {
      float4 a[5];
#pragma unroll
      for (int u = 0; u < 5; ++u) a[u] = *(const float4*)&A[r0 + u][d0];
#pragma unroll
      for (int dd = 0; dd < 4; ++dd) {
        float av[5];
#pragma unroll
        for (int u = 0; u < 5; ++u)
          av[u] = (dd == 0) ? a[u].x : (dd == 1) ? a[u].y : (dd == 2) ? a[u].z : a[u].w;
        {
          const float4 w0 = *(const float4*)&w3[(size_t)(d0 + dd) * 256 + c3];
          const float4 w1v = *(const float4*)&w3[(size_t)(d0 + dd) * 256 + c3 + 4];
#pragma unroll
          for (int u = 0; u < 5; ++u) {
            acc3[u][0] = fmaf(av[u], w0.x, acc3[u][0]);
            acc3[u][1] = fmaf(av[u], w0.y, acc3[u][1]);
            acc3[u][2] = fmaf(av[u], w0.z, acc3[u][2]);
            acc3[u][3] = fmaf(av[u], w0.w, acc3[u][3]);
            acc3[u][4] = fmaf(av[u], w1v.x, acc3[u][4]);
            acc3[u][5] = fmaf(av[u], w1v.y, acc3[u][5]);
            acc3[u][6] = fmaf(av[u], w1v.z, acc3[u][6]);
            acc3[u][7] = fmaf(av[u], w1v.w, acc3[u][7]);
          }
        }
        {
          const float4 w2v = *(const float4*)&w3[(size_t)(d0 + dd) * 256 + c3 + 8];
          const float4 w3v = *(const float4*)&w3[(size_t)(d0 + dd) * 256 + c3 + 12];
#pragma unroll
          for (int u = 0; u < 5; ++u) {
            acc3[u][8]  = fmaf(av[u], w2v.x, acc3[u][8]);
            acc3[u][9]  = fmaf(av[u], w2v.y, acc3[u][9]);
            acc3[u][10] = fmaf(av[u], w2v.z, acc3[u][10]);
            acc3[u][11] = fmaf(av[u], w2v.w, acc3[u][11]);
            acc3[u][12] = fmaf(av[u], w3v.x, acc3[u][12]);
            acc3[u][13] = fmaf(av[u], w3v.y, acc3[u][13]);
            acc3[u][14] = fmaf(av[u], w3v.z, acc3[u][14]);
            acc3[u][15] = fmaf(av[u], w3v.w, acc3[u][15]);
          }
        }
      }
    }
    const int p = ty >> 2, sub = ty & 3;
#pragma unroll
    for (int i = 0; i < 16; i += 4) {
      float4 m;
      m.x = fmaxf(fmaxf(fmaxf(acc3[0][i], acc3[1][i]), fmaxf(acc3[2][i], acc3[3][i])), acc3[4][i]);
      m.y = fmaxf(fmaxf(fmaxf(acc3[0][i+1], acc3[1][i+1]), fmaxf(acc3[2][i+1], acc3[3][i+1])), acc3[4][i+1]);
      m.z = fmaxf(fmaxf(fmaxf(acc3[0][i+2], acc3[1][i+2]), fmaxf(acc3[2][i+2], acc3[3][i+2])), acc3[4][i+2]);
      m.w = fmaxf(fmaxf(fmaxf(acc3[0][i+3], acc3[1][i+3]), fmaxf(acc3[2][i+3], acc3[3][i+3])), acc3[4][i+3]);
      *(float4*)&pm[p][sub][c3 + i] = m;
    }
  }
  __syncthreads();
  {
    const int pp = t >> 6;
    const int cc = (t & 63) * 4;
    float4 m0 = *(const float4*)&pm[pp][0][cc];
    const float4 m1 = *(const float4*)&pm[pp][1][cc];
    const float4 m2 = *(const float4*)&pm[pp][2][cc];
    const float4 m3 = *(const float4*)&pm[pp][3][cc];
    m0.x = fmaxf(fmaxf(m0.x, m1.x), fmaxf(m2.x, m3.x));
    m0.y = fmaxf(fmaxf(m0.y, m1.y), fmaxf(m2.y, m3.y));
    m0.z = fmaxf(fmaxf(m0.z, m1.z), fmaxf(m2.z, m3.z));
    m0.w = fmaxf(fmaxf(m0.w, m1.w), fmaxf(m2.w, m3.w));
    const float4 bb = *(const float4*)&b3[cc];
    float4 o;
    o.x = fmaxf(m0.x + bb.x, 0.f);
    o.y = fmaxf(m0.y + bb.y, 0.f);
    o.z = fmaxf(m0.z + bb.z, 0.f);
    o.w = fmaxf(m0.w + bb.w, 0.f);
    *(float4*)&xout[((size_t)b * NN + pbase + pp) * 256 + cc] = o;
  }
}

// ---------------------------------------------------------------------------
// l0 GEMM (16384x512 @ K=256) + relu + per-64-row max partials.
// Grid: cloud(8) x mblk(32, 64 pts) x cblk(4, 128 ch). K staged in 4 chunks.
// ---------------------------------------------------------------------------
__global__ __launch_bounds__(256) void l0_kernel(const float* __restrict__ x2,
                                                 const float* __restrict__ w,
                                                 const float* __restrict__ bias,
                                                 float* __restrict__ gp) {
  __shared__ float A[64][68];
  __shared__ float red[16][128];
  const int bid = blockIdx.x;
  const int b = bid >> 7;
  const int mblk = (bid >> 2) & 31;
  const int cblk = bid & 3;
  const int t = threadIdx.x;
  const int ty = t >> 4, tx = t & 15;
  const float* xb = x2 + ((size_t)b * NN + mblk * 64) * 256;
  float acc[4][8];
#pragma unroll
  for (int u = 0; u < 4; ++u)
#pragma unroll
    for (int i = 0; i < 8; ++i) acc[u][i] = 0.f;
  for (int kc = 0; kc < 4; ++kc) {
    {
      const int r = t >> 2, seg = (t & 3) * 16;
#pragma unroll
      for (int s4 = 0; s4 < 4; ++s4) {
        *(float4*)&A[r][seg + s4 * 4] =
            *(const float4*)&xb[(size_t)r * 256 + kc * 64 + seg + s4 * 4];
      }
    }
    __syncthreads();
    for (int d0 = 0; d0 < 64; d0 += 4) {
      float4 a[4];
#pragma unroll
      for (int u = 0; u < 4; ++u) a[u] = *(const float4*)&A[ty * 4 + u][d0];
#pragma unroll
      for (int dd = 0; dd < 4; ++dd) {
        const size_t wrow = (size_t)(kc * 64 + d0 + dd) * 512 + cblk * 128 + tx * 8;
        const float4 wA = *(const float4*)&w[wrow];
        const float4 wB = *(const float4*)&w[wrow + 4];
#pragma unroll
        for (int u = 0; u < 4; ++u) {
          const float av = (dd == 0) ? a[u].x : (dd == 1) ? a[u].y : (dd == 2) ? a[u].z : a[u].w;
          acc[u][0] = fmaf(av, wA.x, acc[u][0]);
          acc[u][1] = fmaf(av, wA.y, acc[u][1]);
          acc[u][2] = fmaf(av, wA.z, acc[u][2]);
          acc[u][3] = fmaf(av, wA.w, acc[u][3]);
          acc[u][4] = fmaf(av, wB.x, acc[u][4]);
          acc[u][5] = fmaf(av, wB.y, acc[u][5]);
          acc[u][6] = fmaf(av, wB.z, acc[u][6]);
          acc[u][7] = fmaf(av, wB.w, acc[u][7]);
        }
      }
    }
    __syncthreads();
  }
  // raw max over the thread's 4 rows (bias/relu applied after final reduce)
  {
    float4 m0, m1;
    m0.x = fmaxf(fmaxf(acc[0][0], acc[1][0]), fmaxf(acc[2][0], acc[3][0]));
    m0.y = fmaxf(fmaxf(acc[0][1], acc[1][1]), fmaxf(acc[2][1], acc[3][1]));
    m0.z = fmaxf(fmaxf(acc[0][2], acc[1][2]), fmaxf(acc[2][2], acc[3][2]));
    m0.w = fmaxf(fmaxf(acc[0][3], acc[1][3]), fmaxf(acc[2][3], acc[3][3]));
    m1.x = fmaxf(fmaxf(acc[0][4], acc[1][4]), fmaxf(acc[2][4], acc[3][4]));
    m1.y = fmaxf(fmaxf(acc[0][5], acc[1][5]), fmaxf(acc[2][5], acc[3][5]));
    m1.z = fmaxf(fmaxf(acc[0][6], acc[1][6]), fmaxf(acc[2][6], acc[3][6]));
    m1.w = fmaxf(fmaxf(acc[0][7], acc[1][7]), fmaxf(acc[2][7], acc[3][7]));
    *(float4*)&red[ty][tx * 8] = m0;
    *(float4*)&red[ty][tx * 8 + 4] = m1;
  }
  __syncthreads();
  if (t < 128) {
    float m = red[0][t];
#pragma unroll
    for (int q = 1; q < 16; ++q) m = fmaxf(m, red[q][t]);
    m = fmaxf(m + bias[cblk * 128 + t], 0.f);
    gp[((size_t)b * 32 + mblk) * 512 + cblk * 128 + t] = m;
  }
}

// ---------------------------------------------------------------------------
// final pool-reduce (32 partials) + classifier head + log_softmax.
// ---------------------------------------------------------------------------
__global__ __launch_bounds__(256) void head_kernel(
    const float* __restrict__ gp,
    const float* __restrict__ l1w, const float* __restrict__ l1b,
    const float* __restrict__ l2w, const float* __restrict__ l2b,
    const float* __restrict__ l3w, const float* __restrict__ l3b,
    float* __restrict__ out) {
  __shared__ float g[512];
  __shared__ float h1[256];
  __shared__ float h2[256];
  __shared__ float logits[40];
  __shared__ float lse_s;
  const int b = blockIdx.x;
  const int t = threadIdx.x;
  for (int cidx = t; cidx < 512; cidx += 256) {
    float m = gp[(size_t)(b * 32) * 512 + cidx];
    for (int ch = 1; ch < 32; ++ch) m = fmaxf(m, gp[(size_t)(b * 32 + ch) * 512 + cidx]);
    g[cidx] = m;
  }
  __syncthreads();
  {
    float acc = 0.f;
    for (int d = 0; d < 512; d += 4) {
      const float4 gv = *(const float4*)&g[d];
      acc = fmaf(gv.x, l1w[(size_t)d * 256 + t], acc);
      acc = fmaf(gv.y, l1w[(size_t)(d + 1) * 256 + t], acc);
      acc = fmaf(gv.z, l1w[(size_t)(d + 2) * 256 + t], acc);
      acc = fmaf(gv.w, l1w[(size_t)(d + 3) * 256 + t], acc);
    }
    h1[t] = fmaxf(acc + l1b[t], 0.f);
  }
  __syncthreads();
  {
    float acc = 0.f;
    for (int d = 0; d < 256; d += 4) {
      const float4 hv = *(const float4*)&h1[d];
      acc = fmaf(hv.x, l2w[(size_t)d * 256 + t], acc);
      acc = fmaf(hv.y, l2w[(size_t)(d + 1) * 256 + t], acc);
      acc = fmaf(hv.z, l2w[(size_t)(d + 2) * 256 + t], acc);
      acc = fmaf(hv.w, l2w[(size_t)(d + 3) * 256 + t], acc);
    }
    h2[t] = fmaxf(acc + l2b[t], 0.f);
  }
  __syncthreads();
  if (t < 40) {
    float acc = 0.f;
    for (int d = 0; d < 256; ++d) acc = fmaf(h2[d], l3w[(size_t)d * 40 + t], acc);
    logits[t] = acc + l3b[t];
  }
  __syncthreads();
  if (t == 0) {
    float M = -INFINITY;
    for (int j = 0; j < 40; ++j) M = fmaxf(M, logits[j]);
    float ssum = 0.f;
    for (int j = 0; j < 40; ++j) ssum += expf(logits[j] - M);
    lse_s = M + logf(ssum);
  }
  __syncthreads();
  if (t < 40) out[(size_t)b * 40 + t] = logits[t] - lse_s;
}

// ---------------------------------------------------------------------------
extern "C" void kernel_launch(void* const* d_in, const int* in_sizes, int n_in,
                              void* d_out, int out_size, void* d_ws, size_t ws_size,
                              hipStream_t stream) {
  const float* pos  = (const float*)d_in[0];
  const float* c1w1 = (const float*)d_in[2];
  const float* c1b1 = (const float*)d_in[3];
  const float* c1w2 = (const float*)d_in[4];
  const float* c1b2 = (const float*)d_in[5];
  const float* c1w3 = (const float*)d_in[6];
  const float* c1b3 = (const float*)d_in[7];
  const float* c2w1 = (const float*)d_in[8];
  const float* c2b1 = (const float*)d_in[9];
  const float* c2w2 = (const float*)d_in[10];
  const float* c2b2 = (const float*)d_in[11];
  const float* c2w3 = (const float*)d_in[12];
  const float* c2b3 = (const float*)d_in[13];
  const float* l0w  = (const float*)d_in[14];
  const float* l0b  = (const float*)d_in[15];
  const float* l1w  = (const float*)d_in[16];
  const float* l1b  = (const float*)d_in[17];
  const float* l2w  = (const float*)d_in[18];
  const float* l2b  = (const float*)d_in[19];
  const float* l3w  = (const float*)d_in[20];
  const float* l3b  = (const float*)d_in[21];
  float* out = (float*)d_out;

  char* ws = (char*)d_ws;
  float* x1    = (float*)(ws + 0);                      // 4 MB    [8,2048,64]
  float* x2    = (float*)(ws + ((size_t)4 << 20));      // 16 MB   [8,2048,256]
  int*   idx1  = (int*)  (ws + ((size_t)20 << 20));     // 1.31 MB [16384,20]
  int*   idx2  = (int*)  (ws + ((size_t)22 << 20));     // 1.31 MB
  float* gp    = (float*)(ws + ((size_t)24 << 20));     // 512 KB  [8,32,512]
  float* candd = (float*)(ws + ((size_t)25 << 20));     // 21 MB   [8,16,20,2048]
  int*   candi = (int*)  (ws + ((size_t)46 << 20));     // 21 MB

  knn1_part<<<512, 256, 0, stream>>>(pos, candd, candi);
  merge_topk<<<128, 128, 0, stream>>>(candd, candi, idx1, 8);
  conv1_kernel<<<2048, 256, 0, stream>>>(pos, idx1, c1w1, c1b1, c1w2, c1b2, c1w3, c1b3, x1);
  d2sel_kernel<<<2048, 256, 0, stream>>>(x1, candd, candi);
  merge_topk<<<128, 128, 0, stream>>>(candd, candi, idx2, 16);
  conv2_kernel<<<4096, 256, 0, stream>>>(x1, idx2, c2w1, c2b1, c2w2, c2b2, c2w3, c2b3, x2);
  l0_kernel<<<1024, 256, 0, stream>>>(x2, l0w, l0b, gp);
  head_kernel<<<8, 256, 0, stream>>>(gp, l1w, l1b, l2w, l2b, l3w, l3b, out);
}

// Round 3
// 1477.074 us; speedup vs baseline: 1.6958x; 1.0635x over previous
//
#include <hip/hip_runtime.h>
#include <hip/hip_bf16.h>
#include <math.h>

#define BB 8
#define NN 2048
#define KK 20

// ---------------------------------------------------------------------------
// top-K (K=20) smallest-value tracker, fully register-resident.
// Strict < keeps the earliest-seen on ties.
// ---------------------------------------------------------------------------
__device__ __forceinline__ void topk_insert(float d, int m, float (&bd)[KK], int (&bi)[KK],
                                            float& worst, int& wslot) {
  if (d < worst) {
#pragma unroll
    for (int j = 0; j < KK; ++j) {
      if (j == wslot) { bd[j] = d; bi[j] = m; }
    }
    float w = -INFINITY;
    int s = 0;
#pragma unroll
    for (int j = 0; j < KK; ++j) {
      if (bd[j] > w) { w = bd[j]; s = j; }
    }
    worst = w;
    wslot = s;
  }
}

// ---------------------------------------------------------------------------
// kNN pass 1 for conv1 (D=3), m-chunked: grid = 8 clouds x 8 nchunk x 8 mchunk.
// ---------------------------------------------------------------------------
__global__ __launch_bounds__(256) void knn1_part(const float* __restrict__ pos,
                                                 float* __restrict__ candd,
                                                 int* __restrict__ candi) {
  __shared__ float xs0[256], xs1[256], xs2[256], ss[256];
  const int bid = blockIdx.x;
  const int b = bid >> 6;
  const int nc = (bid >> 3) & 7;
  const int mc = bid & 7;
  const int t = threadIdx.x;
  const float* posb = pos + (size_t)b * NN * 3;
  {
    const int m = mc * 256 + t;
    const float a0 = posb[m * 3 + 0];
    const float a1 = posb[m * 3 + 1];
    const float a2 = posb[m * 3 + 2];
    xs0[t] = a0; xs1[t] = a1; xs2[t] = a2;
    ss[t] = a0 * a0 + a1 * a1 + a2 * a2;
  }
  __syncthreads();
  const int n = nc * 256 + t;
  const float xn0 = posb[n * 3 + 0];
  const float xn1 = posb[n * 3 + 1];
  const float xn2 = posb[n * 3 + 2];
  const float sn = xn0 * xn0 + xn1 * xn1 + xn2 * xn2;  // same expr as ss -> self-dist exact 0
  float bd[KK]; int bi[KK];
#pragma unroll
  for (int j = 0; j < KK; ++j) { bd[j] = INFINITY; bi[j] = 0; }
  float worst = INFINITY;
  int wslot = 0;
  for (int lm = 0; lm < 256; lm += 8) {
    float dv[8];
#pragma unroll
    for (int u = 0; u < 8; ++u) {
      const int q = lm + u;
      dv[u] = sn + ss[q] - 2.f * (xn0 * xs0[q] + xn1 * xs1[q] + xn2 * xs2[q]);
    }
#pragma unroll
    for (int u = 0; u < 8; ++u) topk_insert(dv[u], mc * 256 + lm + u, bd, bi, worst, wslot);
  }
#pragma unroll
  for (int j = 0; j < KK; ++j) {
    const size_t o = ((size_t)(b * 8 + mc) * KK + j) * 2048 + n;
    candd[o] = bd[j];
    candi[o] = bi[j];
  }
}

// ---------------------------------------------------------------------------
// merge nch chunk-candidate-lists (20 each) per point -> final top-20 indices.
// ---------------------------------------------------------------------------
__global__ __launch_bounds__(128) void merge_topk(const float* __restrict__ candd,
                                                  const int* __restrict__ candi,
                                                  int* __restrict__ idx_out, int nch) {
  const int gid = blockIdx.x * 128 + threadIdx.x;
  const int b = gid >> 11, n = gid & 2047;
  float bd[KK]; int bi[KK];
#pragma unroll
  for (int j = 0; j < KK; ++j) { bd[j] = INFINITY; bi[j] = 0; }
  float worst = INFINITY;
  int wslot = 0;
  for (int c = 0; c < nch; ++c) {
    const size_t base = ((size_t)(b * nch + c) * KK) * 2048 + n;
#pragma unroll
    for (int j = 0; j < KK; ++j) {
      const float d = candd[base + (size_t)j * 2048];
      const int m = candi[base + (size_t)j * 2048];
      topk_insert(d, m, bd, bi, worst, wslot);
    }
  }
  int* op = idx_out + (size_t)gid * KK;
#pragma unroll
  for (int j = 0; j < KK; ++j) op[j] = bi[j];
}

// ---------------------------------------------------------------------------
// pre1: per-point factorized conv1 layer-1.
//   U1[n][c] = sum_d pos[n][d]*(w[d][c]-w[3+d][c]) + b1[c]
//   V1[n][c] = sum_d pos[n][d]*w[3+d][c]
// One thread per (n, c): grid 4096 x 256.
// ---------------------------------------------------------------------------
__global__ __launch_bounds__(256) void pre1_kernel(const float* __restrict__ pos,
                                                   const float* __restrict__ w1,
                                                   const float* __restrict__ b1,
                                                   float* __restrict__ U1,
                                                   float* __restrict__ V1) {
  const int t = threadIdx.x;
  const int c = t & 63;
  const int n = blockIdx.x * 4 + (t >> 6);
  const float p0 = pos[(size_t)n * 3 + 0];
  const float p1 = pos[(size_t)n * 3 + 1];
  const float p2 = pos[(size_t)n * 3 + 2];
  const float wt0 = w1[0 * 64 + c], wt1 = w1[1 * 64 + c], wt2 = w1[2 * 64 + c];
  const float wb0 = w1[3 * 64 + c], wb1 = w1[4 * 64 + c], wb2 = w1[5 * 64 + c];
  float v = p0 * wb0 + p1 * wb1 + p2 * wb2;
  float u = p0 * (wt0 - wb0) + p1 * (wt1 - wb1) + p2 * (wt2 - wb2) + b1[c];
  U1[(size_t)n * 64 + c] = u;
  V1[(size_t)n * 64 + c] = v;
}

// ---------------------------------------------------------------------------
// pre2: per-point factorized conv2 layer-1 (GEMM 16384x128 @ K=64, x2 halves).
//   accT = x1 @ W1[0:64], accB = x1 @ W1[64:128]
//   U = accT - accB + b1 ; V = accB
// Block: 64 points x 128 cols; threads 16 rowgrp(4) x 16 colgrp(8).
// ---------------------------------------------------------------------------
__global__ __launch_bounds__(256) void pre2_kernel(const float* __restrict__ x1,
                                                   const float* __restrict__ w1,
                                                   const float* __restrict__ b1,
                                                   float* __restrict__ U,
                                                   float* __restrict__ V) {
  __shared__ float X[64][68];
  const int nbase = blockIdx.x * 64;
  const int t = threadIdx.x;
  for (int it = t; it < 1024; it += 256) {
    const int r = it >> 4, q = it & 15;
    *(float4*)&X[r][q * 4] = *(const float4*)&x1[(size_t)(nbase + r) * 64 + q * 4];
  }
  __syncthreads();
  const int ty = t >> 4, tx = t & 15;
  const int c0 = tx * 8;
  float accT[4][8], accB[4][8];
#pragma unroll
  for (int u = 0; u < 4; ++u)
#pragma unroll
    for (int i = 0; i < 8; ++i) { accT[u][i] = 0.f; accB[u][i] = 0.f; }
  for (int d0 = 0; d0 < 64; d0 += 4) {
    float4 a[4];
#pragma unroll
    for (int u = 0; u < 4; ++u) a[u] = *(const float4*)&X[ty * 4 + u][d0];
#pragma unroll
    for (int dd = 0; dd < 4; ++dd) {
      const float4 t0 = *(const float4*)&w1[(size_t)(d0 + dd) * 128 + c0];
      const float4 t1 = *(const float4*)&w1[(size_t)(d0 + dd) * 128 + c0 + 4];
      const float4 bb0 = *(const float4*)&w1[(size_t)(64 + d0 + dd) * 128 + c0];
      const float4 bb1 = *(const float4*)&w1[(size_t)(64 + d0 + dd) * 128 + c0 + 4];
#pragma unroll
      for (int u = 0; u < 4; ++u) {
        const float av = (dd == 0) ? a[u].x : (dd == 1) ? a[u].y : (dd == 2) ? a[u].z : a[u].w;
        accT[u][0] = fmaf(av, t0.x, accT[u][0]);
        accT[u][1] = fmaf(av, t0.y, accT[u][1]);
        accT[u][2] = fmaf(av, t0.z, accT[u][2]);
        accT[u][3] = fmaf(av, t0.w, accT[u][3]);
        accT[u][4] = fmaf(av, t1.x, accT[u][4]);
        accT[u][5] = fmaf(av, t1.y, accT[u][5]);
        accT[u][6] = fmaf(av, t1.z, accT[u][6]);
        accT[u][7] = fmaf(av, t1.w, accT[u][7]);
        accB[u][0] = fmaf(av, bb0.x, accB[u][0]);
        accB[u][1] = fmaf(av, bb0.y, accB[u][1]);
        accB[u][2] = fmaf(av, bb0.z, accB[u][2]);
        accB[u][3] = fmaf(av, bb0.w, accB[u][3]);
        accB[u][4] = fmaf(av, bb1.x, accB[u][4]);
        accB[u][5] = fmaf(av, bb1.y, accB[u][5]);
        accB[u][6] = fmaf(av, bb1.z, accB[u][6]);
        accB[u][7] = fmaf(av, bb1.w, accB[u][7]);
      }
    }
  }
  const float4 bA = *(const float4*)&b1[c0];
  const float4 bB = *(const float4*)&b1[c0 + 4];
#pragma unroll
  for (int u = 0; u < 4; ++u) {
    const size_t row = (size_t)(nbase + ty * 4 + u) * 128 + c0;
    float4 u0, u1, v0, v1;
    v0 = make_float4(accB[u][0], accB[u][1], accB[u][2], accB[u][3]);
    v1 = make_float4(accB[u][4], accB[u][5], accB[u][6], accB[u][7]);
    u0.x = accT[u][0] - accB[u][0] + bA.x;
    u0.y = accT[u][1] - accB[u][1] + bA.y;
    u0.z = accT[u][2] - accB[u][2] + bA.z;
    u0.w = accT[u][3] - accB[u][3] + bA.w;
    u1.x = accT[u][4] - accB[u][4] + bB.x;
    u1.y = accT[u][5] - accB[u][5] + bB.y;
    u1.z = accT[u][6] - accB[u][6] + bB.z;
    u1.w = accT[u][7] - accB[u][7] + bB.w;
    *(float4*)&U[row] = u0;
    *(float4*)&U[row + 4] = u1;
    *(float4*)&V[row] = v0;
    *(float4*)&V[row + 4] = v1;
  }
}

// ---------------------------------------------------------------------------
// conv1 EdgeConv layers 2,3 (64->64->64, max over 20 edges), 8 points/block.
// Layer-1 output gathered as relu(U1[i]+V1[j]) during staging.
// ---------------------------------------------------------------------------
__global__ __launch_bounds__(256) void conv1_kernel(
    const float* __restrict__ U1, const float* __restrict__ V1,
    const int* __restrict__ idx,
    const float* __restrict__ w2, const float* __restrict__ b2,
    const float* __restrict__ w3, const float* __restrict__ b3,
    float* __restrict__ xout) {
  __shared__ float H[160][68];
  __shared__ float pm[8][4][64];
  const int bid = blockIdx.x;
  const int b = bid >> 8;               // 256 blocks per cloud
  const int pbase = (bid & 255) * 8;
  const int t = threadIdx.x;
  const int ty = t >> 3, tx = t & 7;
  const int r0 = ty * 5, c0 = tx * 8;

  for (int it = t; it < 2560; it += 256) {
    const int r = it >> 4, q = it & 15;
    const int p = r / 20, k = r - (r / 20) * 20;
    const int n = b * NN + pbase + p;
    const int j = b * NN + idx[(size_t)n * KK + k];
    const float4 uv = *(const float4*)&U1[(size_t)n * 64 + q * 4];
    const float4 vv = *(const float4*)&V1[(size_t)j * 64 + q * 4];
    float4 h;
    h.x = fmaxf(uv.x + vv.x, 0.f);
    h.y = fmaxf(uv.y + vv.y, 0.f);
    h.z = fmaxf(uv.z + vv.z, 0.f);
    h.w = fmaxf(uv.w + vv.w, 0.f);
    *(float4*)&H[r][q * 4] = h;
  }
  __syncthreads();

  float acc[5][8];
  // ---- layer 2: 64 -> 64 (in-place H)
#pragma unroll
  for (int u = 0; u < 5; ++u)
#pragma unroll
    for (int i = 0; i < 8; ++i) acc[u][i] = 0.f;
  for (int d0 = 0; d0 < 64; d0 += 4) {
    float4 a[5];
#pragma unroll
    for (int u = 0; u < 5; ++u) a[u] = *(const float4*)&H[r0 + u][d0];
#pragma unroll
    for (int dd = 0; dd < 4; ++dd) {
      const float4 wA = *(const float4*)&w2[(size_t)(d0 + dd) * 64 + c0];
      const float4 wB = *(const float4*)&w2[(size_t)(d0 + dd) * 64 + c0 + 4];
#pragma unroll
      for (int u = 0; u < 5; ++u) {
        const float av = (dd == 0) ? a[u].x : (dd == 1) ? a[u].y : (dd == 2) ? a[u].z : a[u].w;
        acc[u][0] = fmaf(av, wA.x, acc[u][0]);
        acc[u][1] = fmaf(av, wA.y, acc[u][1]);
        acc[u][2] = fmaf(av, wA.z, acc[u][2]);
        acc[u][3] = fmaf(av, wA.w, acc[u][3]);
        acc[u][4] = fmaf(av, wB.x, acc[u][4]);
        acc[u][5] = fmaf(av, wB.y, acc[u][5]);
        acc[u][6] = fmaf(av, wB.z, acc[u][6]);
        acc[u][7] = fmaf(av, wB.w, acc[u][7]);
      }
    }
  }
  __syncthreads();
  {
    const float4 bA = *(const float4*)&b2[c0];
    const float4 bB = *(const float4*)&b2[c0 + 4];
#pragma unroll
    for (int u = 0; u < 5; ++u) {
      float4 oA, oB;
      oA.x = fmaxf(acc[u][0] + bA.x, 0.f); oA.y = fmaxf(acc[u][1] + bA.y, 0.f);
      oA.z = fmaxf(acc[u][2] + bA.z, 0.f); oA.w = fmaxf(acc[u][3] + bA.w, 0.f);
      oB.x = fmaxf(acc[u][4] + bB.x, 0.f); oB.y = fmaxf(acc[u][5] + bB.y, 0.f);
      oB.z = fmaxf(acc[u][6] + bB.z, 0.f); oB.w = fmaxf(acc[u][7] + bB.w, 0.f);
      *(float4*)&H[r0 + u][c0] = oA;
      *(float4*)&H[r0 + u][c0 + 4] = oB;
    }
  }
  __syncthreads();

  // ---- layer 3: 64 -> 64, then max over k
#pragma unroll
  for (int u = 0; u < 5; ++u)
#pragma unroll
    for (int i = 0; i < 8; ++i) acc[u][i] = 0.f;
  for (int d0 = 0; d0 < 64; d0 += 4) {
    float4 a[5];
#pragma unroll
    for (int u = 0; u < 5; ++u) a[u] = *(const float4*)&H[r0 + u][d0];
#pragma unroll
    for (int dd = 0; dd < 4; ++dd) {
      const float4 wA = *(const float4*)&w3[(size_t)(d0 + dd) * 64 + c0];
      const float4 wB = *(const float4*)&w3[(size_t)(d0 + dd) * 64 + c0 + 4];
#pragma unroll
      for (int u = 0; u < 5; ++u) {
        const float av = (dd == 0) ? a[u].x : (dd == 1) ? a[u].y : (dd == 2) ? a[u].z : a[u].w;
        acc[u][0] = fmaf(av, wA.x, acc[u][0]);
        acc[u][1] = fmaf(av, wA.y, acc[u][1]);
        acc[u][2] = fmaf(av, wA.z, acc[u][2]);
        acc[u][3] = fmaf(av, wA.w, acc[u][3]);
        acc[u][4] = fmaf(av, wB.x, acc[u][4]);
        acc[u][5] = fmaf(av, wB.y, acc[u][5]);
        acc[u][6] = fmaf(av, wB.z, acc[u][6]);
        acc[u][7] = fmaf(av, wB.w, acc[u][7]);
      }
    }
  }
  {
    const int p = ty >> 2, sub = ty & 3;
    float4 m0, m1;
    m0.x = fmaxf(fmaxf(fmaxf(acc[0][0], acc[1][0]), fmaxf(acc[2][0], acc[3][0])), acc[4][0]);
    m0.y = fmaxf(fmaxf(fmaxf(acc[0][1], acc[1][1]), fmaxf(acc[2][1], acc[3][1])), acc[4][1]);
    m0.z = fmaxf(fmaxf(fmaxf(acc[0][2], acc[1][2]), fmaxf(acc[2][2], acc[3][2])), acc[4][2]);
    m0.w = fmaxf(fmaxf(fmaxf(acc[0][3], acc[1][3]), fmaxf(acc[2][3], acc[3][3])), acc[4][3]);
    m1.x = fmaxf(fmaxf(fmaxf(acc[0][4], acc[1][4]), fmaxf(acc[2][4], acc[3][4])), acc[4][4]);
    m1.y = fmaxf(fmaxf(fmaxf(acc[0][5], acc[1][5]), fmaxf(acc[2][5], acc[3][5])), acc[4][5]);
    m1.z = fmaxf(fmaxf(fmaxf(acc[0][6], acc[1][6]), fmaxf(acc[2][6], acc[3][6])), acc[4][6]);
    m1.w = fmaxf(fmaxf(fmaxf(acc[0][7], acc[1][7]), fmaxf(acc[2][7], acc[3][7])), acc[4][7]);
    *(float4*)&pm[p][sub][c0] = m0;
    *(float4*)&pm[p][sub][c0 + 4] = m1;
  }
  __syncthreads();
  {
    const int pp = t >> 5;
    const int cc = (t & 31) * 2;
    float m0 = fmaxf(fmaxf(pm[pp][0][cc], pm[pp][1][cc]), fmaxf(pm[pp][2][cc], pm[pp][3][cc]));
    float m1 = fmaxf(fmaxf(pm[pp][0][cc + 1], pm[pp][1][cc + 1]),
                     fmaxf(pm[pp][2][cc + 1], pm[pp][3][cc + 1]));
    float2 o;
    o.x = fmaxf(m0 + b3[cc], 0.f);
    o.y = fmaxf(m1 + b3[cc + 1], 0.f);
    *(float2*)&xout[((size_t)bid) * 8 * 64 + (size_t)pp * 64 + cc] = o;
  }
}

// ---------------------------------------------------------------------------
// d2 + fused partial selection for conv2 kNN (unchanged from round 2).
// ---------------------------------------------------------------------------
__global__ __launch_bounds__(256) void d2sel_kernel(const float* __restrict__ x1,
                                                    float* __restrict__ candd,
                                                    int* __restrict__ candi) {
  __shared__ __align__(16) float Ubuf[16896];   // At[64][132]+Bt[64][132] | T[128][131]
  float (*At)[132] = (float(*)[132])Ubuf;
  float (*Bt)[132] = (float(*)[132])(Ubuf + 64 * 132);
  float (*T)[131] = (float(*)[131])Ubuf;
  __shared__ float sA[128], sB[128];
  const int bid = blockIdx.x;
  const int b = bid >> 8;
  const int tile = bid & 255;
  const int ti = tile >> 4, tj = tile & 15;
  const int i0 = ti * 128, j0 = tj * 128;
  const float* xb = x1 + (size_t)b * NN * 64;
  const int t = threadIdx.x;
  for (int item = t; item < 8192; item += 256) {
    const int r = item >> 6, d = item & 63;
    At[d][r] = xb[(size_t)(i0 + r) * 64 + d];
    Bt[d][r] = xb[(size_t)(j0 + r) * 64 + d];
  }
  __syncthreads();
  if (t < 128) {
    float s = 0.f;
    for (int k = 0; k < 64; ++k) s = fmaf(At[k][t], At[k][t], s);
    sA[t] = s;
  } else {
    const int r = t - 128;
    float s = 0.f;
    for (int k = 0; k < 64; ++k) s = fmaf(Bt[k][r], Bt[k][r], s);
    sB[r] = s;
  }
  __syncthreads();
  const int tx = t & 15, ty = t >> 4;
  float acc[8][8];
#pragma unroll
  for (int u = 0; u < 8; ++u)
#pragma unroll
    for (int v = 0; v < 8; ++v) acc[u][v] = 0.f;
  for (int k = 0; k < 64; ++k) {
    const float4 a0 = *(const float4*)&At[k][ty * 8];
    const float4 a1 = *(const float4*)&At[k][ty * 8 + 4];
    const float4 b0 = *(const float4*)&Bt[k][tx * 8];
    const float4 b1 = *(const float4*)&Bt[k][tx * 8 + 4];
    const float av[8] = {a0.x, a0.y, a0.z, a0.w, a1.x, a1.y, a1.z, a1.w};
    const float bv[8] = {b0.x, b0.y, b0.z, b0.w, b1.x, b1.y, b1.z, b1.w};
#pragma unroll
    for (int u = 0; u < 8; ++u)
#pragma unroll
      for (int v = 0; v < 8; ++v) acc[u][v] = fmaf(av[u], bv[v], acc[u][v]);
  }
  __syncthreads();   // all At/Bt reads done before T overwrites the union
  {
#pragma unroll
    for (int u = 0; u < 8; ++u) {
      const int i = ty * 8 + u;
      const float si = sA[i];
#pragma unroll
      for (int v = 0; v < 8; ++v) {
        T[i][tx * 8 + v] = si + sB[tx * 8 + v] - 2.f * acc[u][v];
      }
    }
  }
  __syncthreads();
  const int j = t >> 1, h = t & 1;
  float bd[KK]; int bi[KK];
#pragma unroll
  for (int q = 0; q < KK; ++q) { bd[q] = INFINITY; bi[q] = 0; }
  float worst = INFINITY;
  int wslot = 0;
  const int mbase = i0 + h * 64;
  for (int r = 0; r < 64; ++r) {
    topk_insert(T[h * 64 + r][j], mbase + r, bd, bi, worst, wslot);
  }
  float od[KK]; int oi[KK];
#pragma unroll
  for (int q = 0; q < KK; ++q) {
    od[q] = __shfl_xor(bd[q], 1);
    oi[q] = __shfl_xor(bi[q], 1);
  }
#pragma unroll
  for (int q = 0; q < KK; ++q) topk_insert(od[q], oi[q], bd, bi, worst, wslot);
  if (h == 0) {
#pragma unroll
    for (int q = 0; q < KK; ++q) {
      const size_t o = ((size_t)(b * 16 + ti) * KK + q) * 2048 + (j0 + j);
      candd[o] = bd[q];
      candi[o] = bi[q];
    }
  }
}

// ---------------------------------------------------------------------------
// conv2 EdgeConv layers 2,3 (128->128->256, max over 20 edges), 4 points/blk.
// Layer-1 output gathered as relu(U[i]+V[j]) during staging. Max-pool
// partials overlay the H buffer (union) -> 42.2 KB LDS -> 3 blocks/CU.
// ---------------------------------------------------------------------------
__global__ __launch_bounds__(256) void conv2_kernel(
    const float* __restrict__ U, const float* __restrict__ V,
    const int* __restrict__ idx,
    const float* __restrict__ w2, const float* __restrict__ b2,
    const float* __restrict__ w3, const float* __restrict__ b3,
    float* __restrict__ xout) {
  __shared__ float A[80][132];
  float* pmf = &A[0][0];                 // overlay: pm[4][4][256] after layer 3
  const int bid = blockIdx.x;
  const int b = bid >> 9;               // 512 blocks per cloud
  const int pbase = (bid & 511) * 4;
  const int t = threadIdx.x;
  const int ty = t >> 4, tx = t & 15;
  const int r0 = ty * 5, c0 = tx * 8;

  for (int it = t; it < 2560; it += 256) {
    const int r = it >> 5, q = it & 31;
    const int p = r / 20, k = r - (r / 20) * 20;
    const int n = b * NN + pbase + p;
    const int j = b * NN + idx[(size_t)n * KK + k];
    const float4 uv = *(const float4*)&U[(size_t)n * 128 + q * 4];
    const float4 vv = *(const float4*)&V[(size_t)j * 128 + q * 4];
    float4 h;
    h.x = fmaxf(uv.x + vv.x, 0.f);
    h.y = fmaxf(uv.y + vv.y, 0.f);
    h.z = fmaxf(uv.z + vv.z, 0.f);
    h.w = fmaxf(uv.w + vv.w, 0.f);
    *(float4*)&A[r][q * 4] = h;
  }
  __syncthreads();

  // ---- layer 2: 128 -> 128 (in-place A)
  {
    float acc[5][8];
#pragma unroll
    for (int u = 0; u < 5; ++u)
#pragma unroll
      for (int i = 0; i < 8; ++i) acc[u][i] = 0.f;
    for (int d0 = 0; d0 < 128; d0 += 4) {
      float4 a[5];
#pragma unroll
      for (int u = 0; u < 5; ++u) a[u] = *(const float4*)&A[r0 + u][d0];
#pragma unroll
      for (int dd = 0; dd < 4; ++dd) {
        const float4 wA = *(const float4*)&w2[(size_t)(d0 + dd) * 128 + c0];
        const float4 wB = *(const float4*)&w2[(size_t)(d0 + dd) * 128 + c0 + 4];
#pragma unroll
        for (int u = 0; u < 5; ++u) {
          const float av = (dd == 0) ? a[u].x : (dd == 1) ? a[u].y : (dd == 2) ? a[u].z : a[u].w;
          acc[u][0] = fmaf(av, wA.x, acc[u][0]);
          acc[u][1] = fmaf(av, wA.y, acc[u][1]);
          acc[u][2] = fmaf(av, wA.z, acc[u][2]);
          acc[u][3] = fmaf(av, wA.w, acc[u][3]);
          acc[u][4] = fmaf(av, wB.x, acc[u][4]);
          acc[u][5] = fmaf(av, wB.y, acc[u][5]);
          acc[u][6] = fmaf(av, wB.z, acc[u][6]);
          acc[u][7] = fmaf(av, wB.w, acc[u][7]);
        }
      }
    }
    __syncthreads();
    {
      const float4 bA = *(const float4*)&b2[c0];
      const float4 bB = *(const float4*)&b2[c0 + 4];
#pragma unroll
      for (int u = 0; u < 5; ++u) {
        float4 oA, oB;
        oA.x = fmaxf(acc[u][0] + bA.x, 0.f); oA.y = fmaxf(acc[u][1] + bA.y, 0.f);
        oA.z = fmaxf(acc[u][2] + bA.z, 0.f); oA.w = fmaxf(acc[u][3] + bA.w, 0.f);
        oB.x = fmaxf(acc[u][4] + bB.x, 0.f); oB.y = fmaxf(acc[u][5] + bB.y, 0.f);
        oB.z = fmaxf(acc[u][6] + bB.z, 0.f); oB.w = fmaxf(acc[u][7] + bB.w, 0.f);
        *(float4*)&A[r0 + u][c0] = oA;
        *(float4*)&A[r0 + u][c0 + 4] = oB;
      }
    }
    __syncthreads();
  }

  // ---- layer 3: 128 -> 256, then max over k
  {
    float acc3[5][16];
#pragma unroll
    for (int u = 0; u < 5; ++u)
#pragma unroll
      for (int i = 0; i < 16; ++i) acc3[u][i] = 0.f;
    const int c3 = tx * 16;
    for (int d0 = 0; d0 < 128; d0 += 4) {
      float4 a[5];
#pragma unroll
      for (int u = 0; u < 5; ++u) a[u] = *(const float4*)&A[r0 + u][d0];
#pragma unroll
      for (int dd = 0; dd < 4; ++dd) {
        float av[5];
#pragma unroll
        for (int u = 0; u < 5; ++u)
          av[u] = (dd == 0) ? a[u].x : (dd == 1) ? a[u].y : (dd == 2) ? a[u].z : a[u].w;
        {
          const float4 w0 = *(const float4*)&w3[(size_t)(d0 + dd) * 256 + c3];
          const float4 w1v = *(const float4*)&w3[(size_t)(d0 + dd) * 256 + c3 + 4];
#pragma unroll
          for (int u = 0; u < 5; ++u) {
            acc3[u][0] = fmaf(av[u], w0.x, acc3[u][0]);
            acc3[u][1] = fmaf(av[u], w0.y, acc3[u][1]);
            acc3[u][2] = fmaf(av[u], w0.z, acc3[u][2]);
            acc3[u][3] = fmaf(av[u], w0.w, acc3[u][3]);
            acc3[u][4] = fmaf(av[u], w1v.x, acc3[u][4]);
            acc3[u][5] = fmaf(av[u], w1v.y, acc3[u][5]);
            acc3[u][6] = fmaf(av[u], w1v.z, acc3[u][6]);
            acc3[u][7] = fmaf(av[u], w1v.w, acc3[u][7]);
          }
        }
        {
          const float4 w2v = *(const float4*)&w3[(size_t)(d0 + dd) * 256 + c3 + 8];
          const float4 w3v = *(const float4*)&w3[(size_t)(d0 + dd) * 256 + c3 + 12];
#pragma unroll
          for (int u = 0; u < 5; ++u) {
            acc3[u][8]  = fmaf(av[u], w2v.x, acc3[u][8]);
            acc3[u][9]  = fmaf(av[u], w2v.y, acc3[u][9]);
            acc3[u][10] = fmaf(av[u], w2v.z, acc3[u][10]);
            acc3[u][11] = fmaf(av[u], w2v.w, acc3[u][11]);
            acc3[u][12] = fmaf(av[u], w3v.x, acc3[u][12]);
            acc3[u][13] = fmaf(av[u], w3v.y, acc3[u][13]);
            acc3[u][14] = fmaf(av[u], w3v.z, acc3[u][14]);
            acc3[u][15] = fmaf(av[u], w3v.w, acc3[u][15]);
          }
        }
      }
    }
    __syncthreads();   // all A reads done before pm overlays the buffer
    const int p = ty >> 2, sub = ty & 3;
#pragma unroll
    for (int i = 0; i < 16; i += 4) {
      float4 m;
      m.x = fmaxf(fmaxf(fmaxf(acc3[0][i], acc3[1][i]), fmaxf(acc3[2][i], acc3[3][i])), acc3[4][i]);
      m.y = fmaxf(fmaxf(fmaxf(acc3[0][i+1], acc3[1][i+1]), fmaxf(acc3[2][i+1], acc3[3][i+1])), acc3[4][i+1]);
      m.z = fmaxf(fmaxf(fmaxf(acc3[0][i+2], acc3[1][i+2]), fmaxf(acc3[2][i+2], acc3[3][i+2])), acc3[4][i+2]);
      m.w = fmaxf(fmaxf(fmaxf(acc3[0][i+3], acc3[1][i+3]), fmaxf(acc3[2][i+3], acc3[3][i+3])), acc3[4][i+3]);
      *(float4*)&pmf[((size_t)(p * 4 + sub)) * 256 + c3 + i] = m;
    }
  }
  __syncthreads();
  {
    const int pp = t >> 6;
    const int cc = (t & 63) * 4;
    float4 m0 = *(const float4*)&pmf[((size_t)(pp * 4 + 0)) * 256 + cc];
    const float4 m1 = *(const float4*)&pmf[((size_t)(pp * 4 + 1)) * 256 + cc];
    const float4 m2 = *(const float4*)&pmf[((size_t)(pp * 4 + 2)) * 256 + cc];
    const float4 m3 = *(const float4*)&pmf[((size_t)(pp * 4 + 3)) * 256 + cc];
    m0.x = fmaxf(fmaxf(m0.x, m1.x), fmaxf(m2.x, m3.x));
    m0.y = fmaxf(fmaxf(m0.y, m1.y), fmaxf(m2.y, m3.y));
    m0.z = fmaxf(fmaxf(m0.z, m1.z), fmaxf(m2.z, m3.z));
    m0.w = fmaxf(fmaxf(m0.w, m1.w), fmaxf(m2.w, m3.w));
    const float4 bb = *(const float4*)&b3[cc];
    float4 o;
    o.x = fmaxf(m0.x + bb.x, 0.f);
    o.y = fmaxf(m0.y + bb.y, 0.f);
    o.z = fmaxf(m0.z + bb.z, 0.f);
    o.w = fmaxf(m0.w + bb.w, 0.f);
    *(float4*)&xout[((size_t)b * NN + pbase + pp) * 256 + cc] = o;
  }
}

// ---------------------------------------------------------------------------
// l0 GEMM (16384x512 @ K=256) + relu + per-64-row max partials (unchanged).
// ---------------------------------------------------------------------------
__global__ __launch_bounds__(256) void l0_kernel(const float* __restrict__ x2,
                                                 const float* __restrict__ w,
                                                 const float* __restrict__ bias,
                                                 float* __restrict__ gp) {
  __shared__ float A[64][68];
  __shared__ float red[16][128];
  const int bid = blockIdx.x;
  const int b = bid >> 7;
  const int mblk = (bid >> 2) & 31;
  const int cblk = bid & 3;
  const int t = threadIdx.x;
  const int ty = t >> 4, tx = t & 15;
  const float* xb = x2 + ((size_t)b * NN + mblk * 64) * 256;
  float acc[4][8];
#pragma unroll
  for (int u = 0; u < 4; ++u)
#pragma unroll
    for (int i = 0; i < 8; ++i) acc[u][i] = 0.f;
  for (int kc = 0; kc < 4; ++kc) {
    {
      const int r = t >> 2, seg = (t & 3) * 16;
#pragma unroll
      for (int s4 = 0; s4 < 4; ++s4) {
        *(float4*)&A[r][seg + s4 * 4] =
            *(const float4*)&xb[(size_t)r * 256 + kc * 64 + seg + s4 * 4];
      }
    }
    __syncthreads();
    for (int d0 = 0; d0 < 64; d0 += 4) {
      float4 a[4];
#pragma unroll
      for (int u = 0; u < 4; ++u) a[u] = *(const float4*)&A[ty * 4 + u][d0];
#pragma unroll
      for (int dd = 0; dd < 4; ++dd) {
        const size_t wrow = (size_t)(kc * 64 + d0 + dd) * 512 + cblk * 128 + tx * 8;
        const float4 wA = *(const float4*)&w[wrow];
        const float4 wB = *(const float4*)&w[wrow + 4];
#pragma unroll
        for (int u = 0; u < 4; ++u) {
          const float av = (dd == 0) ? a[u].x : (dd == 1) ? a[u].y : (dd == 2) ? a[u].z : a[u].w;
          acc[u][0] = fmaf(av, wA.x, acc[u][0]);
          acc[u][1] = fmaf(av, wA.y, acc[u][1]);
          acc[u][2] = fmaf(av, wA.z, acc[u][2]);
          acc[u][3] = fmaf(av, wA.w, acc[u][3]);
          acc[u][4] = fmaf(av, wB.x, acc[u][4]);
          acc[u][5] = fmaf(av, wB.y, acc[u][5]);
          acc[u][6] = fmaf(av, wB.z, acc[u][6]);
          acc[u][7] = fmaf(av, wB.w, acc[u][7]);
        }
      }
    }
    __syncthreads();
  }
  {
    float4 m0, m1;
    m0.x = fmaxf(fmaxf(acc[0][0], acc[1][0]), fmaxf(acc[2][0], acc[3][0]));
    m0.y = fmaxf(fmaxf(acc[0][1], acc[1][1]), fmaxf(acc[2][1], acc[3][1]));
    m0.z = fmaxf(fmaxf(acc[0][2], acc[1][2]), fmaxf(acc[2][2], acc[3][2]));
    m0.w = fmaxf(fmaxf(acc[0][3], acc[1][3]), fmaxf(acc[2][3], acc[3][3]));
    m1.x = fmaxf(fmaxf(acc[0][4], acc[1][4]), fmaxf(acc[2][4], acc[3][4]));
    m1.y = fmaxf(fmaxf(acc[0][5], acc[1][5]), fmaxf(acc[2][5], acc[3][5]));
    m1.z = fmaxf(fmaxf(acc[0][6], acc[1][6]), fmaxf(acc[2][6], acc[3][6]));
    m1.w = fmaxf(fmaxf(acc[0][7], acc[1][7]), fmaxf(acc[2][7], acc[3][7]));
    *(float4*)&red[ty][tx * 8] = m0;
    *(float4*)&red[ty][tx * 8 + 4] = m1;
  }
  __syncthreads();
  if (t < 128) {
    float m = red[0][t];
#pragma unroll
    for (int q = 1; q < 16; ++q) m = fmaxf(m, red[q][t]);
    m = fmaxf(m + bias[cblk * 128 + t], 0.f);
    gp[((size_t)b * 32 + mblk) * 512 + cblk * 128 + t] = m;
  }
}

// ---------------------------------------------------------------------------
// final pool-reduce (32 partials) + classifier head + log_softmax (unchanged).
// ---------------------------------------------------------------------------
__global__ __launch_bounds__(256) void head_kernel(
    const float* __restrict__ gp,
    const float* __restrict__ l1w, const float* __restrict__ l1b,
    const float* __restrict__ l2w, const float* __restrict__ l2b,
    const float* __restrict__ l3w, const float* __restrict__ l3b,
    float* __restrict__ out) {
  __shared__ float g[512];
  __shared__ float h1[256];
  __shared__ float h2[256];
  __shared__ float logits[40];
  __shared__ float lse_s;
  const int b = blockIdx.x;
  const int t = threadIdx.x;
  for (int cidx = t; cidx < 512; cidx += 256) {
    float m = gp[(size_t)(b * 32) * 512 + cidx];
    for (int ch = 1; ch < 32; ++ch) m = fmaxf(m, gp[(size_t)(b * 32 + ch) * 512 + cidx]);
    g[cidx] = m;
  }
  __syncthreads();
  {
    float acc = 0.f;
    for (int d = 0; d < 512; d += 4) {
      const float4 gv = *(const float4*)&g[d];
      acc = fmaf(gv.x, l1w[(size_t)d * 256 + t], acc);
      acc = fmaf(gv.y, l1w[(size_t)(d + 1) * 256 + t], acc);
      acc = fmaf(gv.z, l1w[(size_t)(d + 2) * 256 + t], acc);
      acc = fmaf(gv.w, l1w[(size_t)(d + 3) * 256 + t], acc);
    }
    h1[t] = fmaxf(acc + l1b[t], 0.f);
  }
  __syncthreads();
  {
    float acc = 0.f;
    for (int d = 0; d < 256; d += 4) {
      const float4 hv = *(const float4*)&h1[d];
      acc = fmaf(hv.x, l2w[(size_t)d * 256 + t], acc);
      acc = fmaf(hv.y, l2w[(size_t)(d + 1) * 256 + t], acc);
      acc = fmaf(hv.z, l2w[(size_t)(d + 2) * 256 + t], acc);
      acc = fmaf(hv.w, l2w[(size_t)(d + 3) * 256 + t], acc);
    }
    h2[t] = fmaxf(acc + l2b[t], 0.f);
  }
  __syncthreads();
  if (t < 40) {
    float acc = 0.f;
    for (int d = 0; d < 256; ++d) acc = fmaf(h2[d], l3w[(size_t)d * 40 + t], acc);
    logits[t] = acc + l3b[t];
  }
  __syncthreads();
  if (t == 0) {
    float M = -INFINITY;
    for (int j = 0; j < 40; ++j) M = fmaxf(M, logits[j]);
    float ssum = 0.f;
    for (int j = 0; j < 40; ++j) ssum += expf(logits[j] - M);
    lse_s = M + logf(ssum);
  }
  __syncthreads();
  if (t < 40) out[(size_t)b * 40 + t] = logits[t] - lse_s;
}

// ---------------------------------------------------------------------------
extern "C" void kernel_launch(void* const* d_in, const int* in_sizes, int n_in,
                              void* d_out, int out_size, void* d_ws, size_t ws_size,
                              hipStream_t stream) {
  const float* pos  = (const float*)d_in[0];
  const float* c1w1 = (const float*)d_in[2];
  const float* c1b1 = (const float*)d_in[3];
  const float* c1w2 = (const float*)d_in[4];
  const float* c1b2 = (const float*)d_in[5];
  const float* c1w3 = (const float*)d_in[6];
  const float* c1b3 = (const float*)d_in[7];
  const float* c2w1 = (const float*)d_in[8];
  const float* c2b1 = (const float*)d_in[9];
  const float* c2w2 = (const float*)d_in[10];
  const float* c2b2 = (const float*)d_in[11];
  const float* c2w3 = (const float*)d_in[12];
  const float* c2b3 = (const float*)d_in[13];
  const float* l0w  = (const float*)d_in[14];
  const float* l0b  = (const float*)d_in[15];
  const float* l1w  = (const float*)d_in[16];
  const float* l1b  = (const float*)d_in[17];
  const float* l2w  = (const float*)d_in[18];
  const float* l2b  = (const float*)d_in[19];
  const float* l3w  = (const float*)d_in[20];
  const float* l3b  = (const float*)d_in[21];
  float* out = (float*)d_out;

  char* ws = (char*)d_ws;
  float* x1    = (float*)(ws + 0);                      // 4 MB    [8,2048,64]
  float* x2    = (float*)(ws + ((size_t)4 << 20));      // 16 MB   [8,2048,256]
  int*   idx1  = (int*)  (ws + ((size_t)20 << 20));     // 1.31 MB [16384,20]
  int*   idx2  = (int*)  (ws + ((size_t)22 << 20));     // 1.31 MB
  float* gp    = (float*)(ws + ((size_t)24 << 20));     // 512 KB  [8,32,512]
  float* candd = (float*)(ws + ((size_t)25 << 20));     // 21 MB   [8,16,20,2048]
  int*   candi = (int*)  (ws + ((size_t)46 << 20));     // 21 MB
  // Overlays (regions dead at time of use -- see launch order):
  float* U1 = (float*)(ws + ((size_t)25 << 20));        // 4 MB over candd (dead after merge1)
  float* V1 = (float*)(ws + ((size_t)29 << 20));        // 4 MB
  float* U  = (float*)(ws + ((size_t)46 << 20));        // 8 MB over candi (dead after merge2)
  float* Vv = (float*)(ws + ((size_t)54 << 20));        // 8 MB

  knn1_part<<<512, 256, 0, stream>>>(pos, candd, candi);
  merge_topk<<<128, 128, 0, stream>>>(candd, candi, idx1, 8);
  pre1_kernel<<<4096, 256, 0, stream>>>(pos, c1w1, c1b1, U1, V1);      // overwrites candd region
  conv1_kernel<<<2048, 256, 0, stream>>>(U1, V1, idx1, c1w2, c1b2, c1w3, c1b3, x1);
  d2sel_kernel<<<2048, 256, 0, stream>>>(x1, candd, candi);            // U1/V1 dead now
  merge_topk<<<128, 128, 0, stream>>>(candd, candi, idx2, 16);
  pre2_kernel<<<256, 256, 0, stream>>>(x1, c2w1, c2b1, U, Vv);         // overwrites candi region
  conv2_kernel<<<4096, 256, 0, stream>>>(U, Vv, idx2, c2w2, c2b2, c2w3, c2b3, x2);
  l0_kernel<<<1024, 256, 0, stream>>>(x2, l0w, l0b, gp);
  head_kernel<<<8, 256, 0, stream>>>(gp, l1w, l1b, l2w, l2b, l3w, l3b, out);
}

// Round 4
// 982.307 us; speedup vs baseline: 2.5500x; 1.5037x over previous
//
#include <hip/hip_runtime.h>
#include <hip/hip_bf16.h>
#include <math.h>

#define BB 8
#define NN 2048
#define KK 20

typedef short bf16x8 __attribute__((ext_vector_type(8)));
typedef float f32x4 __attribute__((ext_vector_type(4)));

// fp32 -> bf16 (round-to-nearest-even), finite inputs only
__device__ __forceinline__ unsigned short f2bf(float f) {
  unsigned u = __float_as_uint(f);
  u += 0x7FFFu + ((u >> 16) & 1u);
  return (unsigned short)(u >> 16);
}

// ---------------------------------------------------------------------------
// top-K (K=20) smallest-value tracker, fully register-resident.
// Strict < keeps the earliest-seen on ties.
// ---------------------------------------------------------------------------
__device__ __forceinline__ void topk_insert(float d, int m, float (&bd)[KK], int (&bi)[KK],
                                            float& worst, int& wslot) {
  if (d < worst) {
#pragma unroll
    for (int j = 0; j < KK; ++j) {
      if (j == wslot) { bd[j] = d; bi[j] = m; }
    }
    float w = -INFINITY;
    int s = 0;
#pragma unroll
    for (int j = 0; j < KK; ++j) {
      if (bd[j] > w) { w = bd[j]; s = j; }
    }
    worst = w;
    wslot = s;
  }
}

// ---------------------------------------------------------------------------
// kNN pass 1 for conv1 (D=3), m-chunked: grid = 8 clouds x 8 nchunk x 8 mchunk.
// ---------------------------------------------------------------------------
__global__ __launch_bounds__(256) void knn1_part(const float* __restrict__ pos,
                                                 float* __restrict__ candd,
                                                 int* __restrict__ candi) {
  __shared__ float xs0[256], xs1[256], xs2[256], ss[256];
  const int bid = blockIdx.x;
  const int b = bid >> 6;
  const int nc = (bid >> 3) & 7;
  const int mc = bid & 7;
  const int t = threadIdx.x;
  const float* posb = pos + (size_t)b * NN * 3;
  {
    const int m = mc * 256 + t;
    const float a0 = posb[m * 3 + 0];
    const float a1 = posb[m * 3 + 1];
    const float a2 = posb[m * 3 + 2];
    xs0[t] = a0; xs1[t] = a1; xs2[t] = a2;
    ss[t] = a0 * a0 + a1 * a1 + a2 * a2;
  }
  __syncthreads();
  const int n = nc * 256 + t;
  const float xn0 = posb[n * 3 + 0];
  const float xn1 = posb[n * 3 + 1];
  const float xn2 = posb[n * 3 + 2];
  const float sn = xn0 * xn0 + xn1 * xn1 + xn2 * xn2;  // same expr as ss -> self-dist exact 0
  float bd[KK]; int bi[KK];
#pragma unroll
  for (int j = 0; j < KK; ++j) { bd[j] = INFINITY; bi[j] = 0; }
  float worst = INFINITY;
  int wslot = 0;
  for (int lm = 0; lm < 256; lm += 8) {
    float dv[8];
#pragma unroll
    for (int u = 0; u < 8; ++u) {
      const int q = lm + u;
      dv[u] = sn + ss[q] - 2.f * (xn0 * xs0[q] + xn1 * xs1[q] + xn2 * xs2[q]);
    }
#pragma unroll
    for (int u = 0; u < 8; ++u) topk_insert(dv[u], mc * 256 + lm + u, bd, bi, worst, wslot);
  }
#pragma unroll
  for (int j = 0; j < KK; ++j) {
    const size_t o = ((size_t)(b * 8 + mc) * KK + j) * 2048 + n;
    candd[o] = bd[j];
    candi[o] = bi[j];
  }
}

// ---------------------------------------------------------------------------
// merge nch chunk-candidate-lists (20 each) per point -> final top-20 indices.
// ---------------------------------------------------------------------------
__global__ __launch_bounds__(128) void merge_topk(const float* __restrict__ candd,
                                                  const int* __restrict__ candi,
                                                  int* __restrict__ idx_out, int nch) {
  const int gid = blockIdx.x * 128 + threadIdx.x;
  const int b = gid >> 11, n = gid & 2047;
  float bd[KK]; int bi[KK];
#pragma unroll
  for (int j = 0; j < KK; ++j) { bd[j] = INFINITY; bi[j] = 0; }
  float worst = INFINITY;
  int wslot = 0;
  for (int c = 0; c < nch; ++c) {
    const size_t base = ((size_t)(b * nch + c) * KK) * 2048 + n;
#pragma unroll
    for (int j = 0; j < KK; ++j) {
      const float d = candd[base + (size_t)j * 2048];
      const int m = candi[base + (size_t)j * 2048];
      topk_insert(d, m, bd, bi, worst, wslot);
    }
  }
  int* op = idx_out + (size_t)gid * KK;
#pragma unroll
  for (int j = 0; j < KK; ++j) op[j] = bi[j];
}

// ---------------------------------------------------------------------------
// pre1: per-point factorized conv1 layer-1.
// ---------------------------------------------------------------------------
__global__ __launch_bounds__(256) void pre1_kernel(const float* __restrict__ pos,
                                                   const float* __restrict__ w1,
                                                   const float* __restrict__ b1,
                                                   float* __restrict__ U1,
                                                   float* __restrict__ V1) {
  const int t = threadIdx.x;
  const int c = t & 63;
  const int n = blockIdx.x * 4 + (t >> 6);
  const float p0 = pos[(size_t)n * 3 + 0];
  const float p1 = pos[(size_t)n * 3 + 1];
  const float p2 = pos[(size_t)n * 3 + 2];
  const float wt0 = w1[0 * 64 + c], wt1 = w1[1 * 64 + c], wt2 = w1[2 * 64 + c];
  const float wb0 = w1[3 * 64 + c], wb1 = w1[4 * 64 + c], wb2 = w1[5 * 64 + c];
  float v = p0 * wb0 + p1 * wb1 + p2 * wb2;
  float u = p0 * (wt0 - wb0) + p1 * (wt1 - wb1) + p2 * (wt2 - wb2) + b1[c];
  U1[(size_t)n * 64 + c] = u;
  V1[(size_t)n * 64 + c] = v;
}

// ---------------------------------------------------------------------------
// pre2: per-point factorized conv2 layer-1 (GEMM 16384x128 @ K=64, x2 halves).
// ---------------------------------------------------------------------------
__global__ __launch_bounds__(256) void pre2_kernel(const float* __restrict__ x1,
                                                   const float* __restrict__ w1,
                                                   const float* __restrict__ b1,
                                                   float* __restrict__ U,
                                                   float* __restrict__ V) {
  __shared__ float X[64][68];
  const int nbase = blockIdx.x * 64;
  const int t = threadIdx.x;
  for (int it = t; it < 1024; it += 256) {
    const int r = it >> 4, q = it & 15;
    *(float4*)&X[r][q * 4] = *(const float4*)&x1[(size_t)(nbase + r) * 64 + q * 4];
  }
  __syncthreads();
  const int ty = t >> 4, tx = t & 15;
  const int c0 = tx * 8;
  float accT[4][8], accB[4][8];
#pragma unroll
  for (int u = 0; u < 4; ++u)
#pragma unroll
    for (int i = 0; i < 8; ++i) { accT[u][i] = 0.f; accB[u][i] = 0.f; }
  for (int d0 = 0; d0 < 64; d0 += 4) {
    float4 a[4];
#pragma unroll
    for (int u = 0; u < 4; ++u) a[u] = *(const float4*)&X[ty * 4 + u][d0];
#pragma unroll
    for (int dd = 0; dd < 4; ++dd) {
      const float4 t0 = *(const float4*)&w1[(size_t)(d0 + dd) * 128 + c0];
      const float4 t1 = *(const float4*)&w1[(size_t)(d0 + dd) * 128 + c0 + 4];
      const float4 bb0 = *(const float4*)&w1[(size_t)(64 + d0 + dd) * 128 + c0];
      const float4 bb1 = *(const float4*)&w1[(size_t)(64 + d0 + dd) * 128 + c0 + 4];
#pragma unroll
      for (int u = 0; u < 4; ++u) {
        const float av = (dd == 0) ? a[u].x : (dd == 1) ? a[u].y : (dd == 2) ? a[u].z : a[u].w;
        accT[u][0] = fmaf(av, t0.x, accT[u][0]);
        accT[u][1] = fmaf(av, t0.y, accT[u][1]);
        accT[u][2] = fmaf(av, t0.z, accT[u][2]);
        accT[u][3] = fmaf(av, t0.w, accT[u][3]);
        accT[u][4] = fmaf(av, t1.x, accT[u][4]);
        accT[u][5] = fmaf(av, t1.y, accT[u][5]);
        accT[u][6] = fmaf(av, t1.z, accT[u][6]);
        accT[u][7] = fmaf(av, t1.w, accT[u][7]);
        accB[u][0] = fmaf(av, bb0.x, accB[u][0]);
        accB[u][1] = fmaf(av, bb0.y, accB[u][1]);
        accB[u][2] = fmaf(av, bb0.z, accB[u][2]);
        accB[u][3] = fmaf(av, bb0.w, accB[u][3]);
        accB[u][4] = fmaf(av, bb1.x, accB[u][4]);
        accB[u][5] = fmaf(av, bb1.y, accB[u][5]);
        accB[u][6] = fmaf(av, bb1.z, accB[u][6]);
        accB[u][7] = fmaf(av, bb1.w, accB[u][7]);
      }
    }
  }
  const float4 bA = *(const float4*)&b1[c0];
  const float4 bB = *(const float4*)&b1[c0 + 4];
#pragma unroll
  for (int u = 0; u < 4; ++u) {
    const size_t row = (size_t)(nbase + ty * 4 + u) * 128 + c0;
    float4 u0, u1, v0, v1;
    v0 = make_float4(accB[u][0], accB[u][1], accB[u][2], accB[u][3]);
    v1 = make_float4(accB[u][4], accB[u][5], accB[u][6], accB[u][7]);
    u0.x = accT[u][0] - accB[u][0] + bA.x;
    u0.y = accT[u][1] - accB[u][1] + bA.y;
    u0.z = accT[u][2] - accB[u][2] + bA.z;
    u0.w = accT[u][3] - accB[u][3] + bA.w;
    u1.x = accT[u][4] - accB[u][4] + bB.x;
    u1.y = accT[u][5] - accB[u][5] + bB.y;
    u1.z = accT[u][6] - accB[u][6] + bB.z;
    u1.w = accT[u][7] - accB[u][7] + bB.w;
    *(float4*)&U[row] = u0;
    *(float4*)&U[row + 4] = u1;
    *(float4*)&V[row] = v0;
    *(float4*)&V[row + 4] = v1;
  }
}

// ---------------------------------------------------------------------------
// conv1 EdgeConv layers 2,3 (64->64->64, max over 20 edges), 8 points/block.
// ---------------------------------------------------------------------------
__global__ __launch_bounds__(256) void conv1_kernel(
    const float* __restrict__ U1, const float* __restrict__ V1,
    const int* __restrict__ idx,
    const float* __restrict__ w2, const float* __restrict__ b2,
    const float* __restrict__ w3, const float* __restrict__ b3,
    float* __restrict__ xout) {
  __shared__ float H[160][68];
  __shared__ float pm[8][4][64];
  const int bid = blockIdx.x;
  const int b = bid >> 8;               // 256 blocks per cloud
  const int pbase = (bid & 255) * 8;
  const int t = threadIdx.x;
  const int ty = t >> 3, tx = t & 7;
  const int r0 = ty * 5, c0 = tx * 8;

  for (int it = t; it < 2560; it += 256) {
    const int r = it >> 4, q = it & 15;
    const int p = r / 20, k = r - (r / 20) * 20;
    const int n = b * NN + pbase + p;
    const int j = b * NN + idx[(size_t)n * KK + k];
    const float4 uv = *(const float4*)&U1[(size_t)n * 64 + q * 4];
    const float4 vv = *(const float4*)&V1[(size_t)j * 64 + q * 4];
    float4 h;
    h.x = fmaxf(uv.x + vv.x, 0.f);
    h.y = fmaxf(uv.y + vv.y, 0.f);
    h.z = fmaxf(uv.z + vv.z, 0.f);
    h.w = fmaxf(uv.w + vv.w, 0.f);
    *(float4*)&H[r][q * 4] = h;
  }
  __syncthreads();

  float acc[5][8];
  // ---- layer 2: 64 -> 64 (in-place H)
#pragma unroll
  for (int u = 0; u < 5; ++u)
#pragma unroll
    for (int i = 0; i < 8; ++i) acc[u][i] = 0.f;
  for (int d0 = 0; d0 < 64; d0 += 4) {
    float4 a[5];
#pragma unroll
    for (int u = 0; u < 5; ++u) a[u] = *(const float4*)&H[r0 + u][d0];
#pragma unroll
    for (int dd = 0; dd < 4; ++dd) {
      const float4 wA = *(const float4*)&w2[(size_t)(d0 + dd) * 64 + c0];
      const float4 wB = *(const float4*)&w2[(size_t)(d0 + dd) * 64 + c0 + 4];
#pragma unroll
      for (int u = 0; u < 5; ++u) {
        const float av = (dd == 0) ? a[u].x : (dd == 1) ? a[u].y : (dd == 2) ? a[u].z : a[u].w;
        acc[u][0] = fmaf(av, wA.x, acc[u][0]);
        acc[u][1] = fmaf(av, wA.y, acc[u][1]);
        acc[u][2] = fmaf(av, wA.z, acc[u][2]);
        acc[u][3] = fmaf(av, wA.w, acc[u][3]);
        acc[u][4] = fmaf(av, wB.x, acc[u][4]);
        acc[u][5] = fmaf(av, wB.y, acc[u][5]);
        acc[u][6] = fmaf(av, wB.z, acc[u][6]);
        acc[u][7] = fmaf(av, wB.w, acc[u][7]);
      }
    }
  }
  __syncthreads();
  {
    const float4 bA = *(const float4*)&b2[c0];
    const float4 bB = *(const float4*)&b2[c0 + 4];
#pragma unroll
    for (int u = 0; u < 5; ++u) {
      float4 oA, oB;
      oA.x = fmaxf(acc[u][0] + bA.x, 0.f); oA.y = fmaxf(acc[u][1] + bA.y, 0.f);
      oA.z = fmaxf(acc[u][2] + bA.z, 0.f); oA.w = fmaxf(acc[u][3] + bA.w, 0.f);
      oB.x = fmaxf(acc[u][4] + bB.x, 0.f); oB.y = fmaxf(acc[u][5] + bB.y, 0.f);
      oB.z = fmaxf(acc[u][6] + bB.z, 0.f); oB.w = fmaxf(acc[u][7] + bB.w, 0.f);
      *(float4*)&H[r0 + u][c0] = oA;
      *(float4*)&H[r0 + u][c0 + 4] = oB;
    }
  }
  __syncthreads();

  // ---- layer 3: 64 -> 64, then max over k
#pragma unroll
  for (int u = 0; u < 5; ++u)
#pragma unroll
    for (int i = 0; i < 8; ++i) acc[u][i] = 0.f;
  for (int d0 = 0; d0 < 64; d0 += 4) {
    float4 a[5];
#pragma unroll
    for (int u = 0; u < 5; ++u) a[u] = *(const float4*)&H[r0 + u][d0];
#pragma unroll
    for (int dd = 0; dd < 4; ++dd) {
      const float4 wA = *(const float4*)&w3[(size_t)(d0 + dd) * 64 + c0];
      const float4 wB = *(const float4*)&w3[(size_t)(d0 + dd) * 64 + c0 + 4];
#pragma unroll
      for (int u = 0; u < 5; ++u) {
        const float av = (dd == 0) ? a[u].x : (dd == 1) ? a[u].y : (dd == 2) ? a[u].z : a[u].w;
        acc[u][0] = fmaf(av, wA.x, acc[u][0]);
        acc[u][1] = fmaf(av, wA.y, acc[u][1]);
        acc[u][2] = fmaf(av, wA.z, acc[u][2]);
        acc[u][3] = fmaf(av, wA.w, acc[u][3]);
        acc[u][4] = fmaf(av, wB.x, acc[u][4]);
        acc[u][5] = fmaf(av, wB.y, acc[u][5]);
        acc[u][6] = fmaf(av, wB.z, acc[u][6]);
        acc[u][7] = fmaf(av, wB.w, acc[u][7]);
      }
    }
  }
  {
    const int p = ty >> 2, sub = ty & 3;
    float4 m0, m1;
    m0.x = fmaxf(fmaxf(fmaxf(acc[0][0], acc[1][0]), fmaxf(acc[2][0], acc[3][0])), acc[4][0]);
    m0.y = fmaxf(fmaxf(fmaxf(acc[0][1], acc[1][1]), fmaxf(acc[2][1], acc[3][1])), acc[4][1]);
    m0.z = fmaxf(fmaxf(fmaxf(acc[0][2], acc[1][2]), fmaxf(acc[2][2], acc[3][2])), acc[4][2]);
    m0.w = fmaxf(fmaxf(fmaxf(acc[0][3], acc[1][3]), fmaxf(acc[2][3], acc[3][3])), acc[4][3]);
    m1.x = fmaxf(fmaxf(fmaxf(acc[0][4], acc[1][4]), fmaxf(acc[2][4], acc[3][4])), acc[4][4]);
    m1.y = fmaxf(fmaxf(fmaxf(acc[0][5], acc[1][5]), fmaxf(acc[2][5], acc[3][5])), acc[4][5]);
    m1.z = fmaxf(fmaxf(fmaxf(acc[0][6], acc[1][6]), fmaxf(acc[2][6], acc[3][6])), acc[4][6]);
    m1.w = fmaxf(fmaxf(fmaxf(acc[0][7], acc[1][7]), fmaxf(acc[2][7], acc[3][7])), acc[4][7]);
    *(float4*)&pm[p][sub][c0] = m0;
    *(float4*)&pm[p][sub][c0 + 4] = m1;
  }
  __syncthreads();
  {
    const int pp = t >> 5;
    const int cc = (t & 31) * 2;
    float m0 = fmaxf(fmaxf(pm[pp][0][cc], pm[pp][1][cc]), fmaxf(pm[pp][2][cc], pm[pp][3][cc]));
    float m1 = fmaxf(fmaxf(pm[pp][0][cc + 1], pm[pp][1][cc + 1]),
                     fmaxf(pm[pp][2][cc + 1], pm[pp][3][cc + 1]));
    float2 o;
    o.x = fmaxf(m0 + b3[cc], 0.f);
    o.y = fmaxf(m1 + b3[cc + 1], 0.f);
    *(float2*)&xout[((size_t)bid) * 8 * 64 + (size_t)pp * 64 + cc] = o;
  }
}

// ---------------------------------------------------------------------------
// d2 + fused partial selection for conv2 kNN (unchanged).
// ---------------------------------------------------------------------------
__global__ __launch_bounds__(256) void d2sel_kernel(const float* __restrict__ x1,
                                                    float* __restrict__ candd,
                                                    int* __restrict__ candi) {
  __shared__ __align__(16) float Ubuf[16896];   // At[64][132]+Bt[64][132] | T[128][131]
  float (*At)[132] = (float(*)[132])Ubuf;
  float (*Bt)[132] = (float(*)[132])(Ubuf + 64 * 132);
  float (*T)[131] = (float(*)[131])Ubuf;
  __shared__ float sA[128], sB[128];
  const int bid = blockIdx.x;
  const int b = bid >> 8;
  const int tile = bid & 255;
  const int ti = tile >> 4, tj = tile & 15;
  const int i0 = ti * 128, j0 = tj * 128;
  const float* xb = x1 + (size_t)b * NN * 64;
  const int t = threadIdx.x;
  for (int item = t; item < 8192; item += 256) {
    const int r = item >> 6, d = item & 63;
    At[d][r] = xb[(size_t)(i0 + r) * 64 + d];
    Bt[d][r] = xb[(size_t)(j0 + r) * 64 + d];
  }
  __syncthreads();
  if (t < 128) {
    float s = 0.f;
    for (int k = 0; k < 64; ++k) s = fmaf(At[k][t], At[k][t], s);
    sA[t] = s;
  } else {
    const int r = t - 128;
    float s = 0.f;
    for (int k = 0; k < 64; ++k) s = fmaf(Bt[k][r], Bt[k][r], s);
    sB[r] = s;
  }
  __syncthreads();
  const int tx = t & 15, ty = t >> 4;
  float acc[8][8];
#pragma unroll
  for (int u = 0; u < 8; ++u)
#pragma unroll
    for (int v = 0; v < 8; ++v) acc[u][v] = 0.f;
  for (int k = 0; k < 64; ++k) {
    const float4 a0 = *(const float4*)&At[k][ty * 8];
    const float4 a1 = *(const float4*)&At[k][ty * 8 + 4];
    const float4 b0 = *(const float4*)&Bt[k][tx * 8];
    const float4 b1 = *(const float4*)&Bt[k][tx * 8 + 4];
    const float av[8] = {a0.x, a0.y, a0.z, a0.w, a1.x, a1.y, a1.z, a1.w};
    const float bv[8] = {b0.x, b0.y, b0.z, b0.w, b1.x, b1.y, b1.z, b1.w};
#pragma unroll
    for (int u = 0; u < 8; ++u)
#pragma unroll
      for (int v = 0; v < 8; ++v) acc[u][v] = fmaf(av[u], bv[v], acc[u][v]);
  }
  __syncthreads();   // all At/Bt reads done before T overwrites the union
  {
#pragma unroll
    for (int u = 0; u < 8; ++u) {
      const int i = ty * 8 + u;
      const float si = sA[i];
#pragma unroll
      for (int v = 0; v < 8; ++v) {
        T[i][tx * 8 + v] = si + sB[tx * 8 + v] - 2.f * acc[u][v];
      }
    }
  }
  __syncthreads();
  const int j = t >> 1, h = t & 1;
  float bd[KK]; int bi[KK];
#pragma unroll
  for (int q = 0; q < KK; ++q) { bd[q] = INFINITY; bi[q] = 0; }
  float worst = INFINITY;
  int wslot = 0;
  const int mbase = i0 + h * 64;
  for (int r = 0; r < 64; ++r) {
    topk_insert(T[h * 64 + r][j], mbase + r, bd, bi, worst, wslot);
  }
  float od[KK]; int oi[KK];
#pragma unroll
  for (int q = 0; q < KK; ++q) {
    od[q] = __shfl_xor(bd[q], 1);
    oi[q] = __shfl_xor(bi[q], 1);
  }
#pragma unroll
  for (int q = 0; q < KK; ++q) topk_insert(od[q], oi[q], bd, bi, worst, wslot);
  if (h == 0) {
#pragma unroll
    for (int q = 0; q < KK; ++q) {
      const size_t o = ((size_t)(b * 16 + ti) * KK + q) * 2048 + (j0 + j);
      candd[o] = bd[q];
      candi[o] = bi[q];
    }
  }
}

// ---------------------------------------------------------------------------
// wprep: transpose+convert conv2 weights to bf16 [N][K] for MFMA B-fragments.
//   w2t[c][d] = bf16(w2[d][c])  (128x128)
//   w3t[c][d] = bf16(w3[d][c])  (256x128)
// ---------------------------------------------------------------------------
__global__ __launch_bounds__(256) void wprep_kernel(const float* __restrict__ w2,
                                                    const float* __restrict__ w3,
                                                    unsigned short* __restrict__ w2t,
                                                    unsigned short* __restrict__ w3t) {
  const int i = blockIdx.x * 256 + threadIdx.x;
  if (i < 16384) {
    const int d = i >> 7, c = i & 127;
    w2t[c * 128 + d] = f2bf(w2[i]);
  } else {
    const int j = i - 16384;           // j < 32768
    const int d = j >> 8, c = j & 255;
    w3t[c * 128 + d] = f2bf(w3[j]);
  }
}

// ---------------------------------------------------------------------------
// conv2 EdgeConv layers 2,3 via bf16 MFMA (16x16x32), 4 points/block.
// E[80][136] bf16 edge features = relu(U[i]+V[j]); per wave: layer2 owns
// 2 N-tiles (w-frags in VGPRs), layer3 owns 4 N-tiles. Max over edges via
// LDS atomicMax on non-negative float bit patterns (exact, deterministic).
// ---------------------------------------------------------------------------
__global__ __launch_bounds__(256) void conv2_kernel(
    const float* __restrict__ U, const float* __restrict__ V,
    const int* __restrict__ idx,
    const unsigned short* __restrict__ w2t, const float* __restrict__ b2,
    const unsigned short* __restrict__ w3t, const float* __restrict__ b3,
    float* __restrict__ xout) {
  __shared__ __align__(16) unsigned short E[80][136];
  __shared__ __align__(16) unsigned short E2[80][136];
  __shared__ unsigned int pm[4][256];
  const int bid = blockIdx.x;
  const int b = bid >> 9;               // 512 blocks per cloud
  const int pbase = (bid & 511) * 4;
  const int t = threadIdx.x;
  const int wave = t >> 6, lane = t & 63;
  const int lrow = lane & 15;           // A/B fragment row (M or N index)
  const int lk8 = (lane >> 4) * 8;      // k-offset of the 8-element fragment

  // ---- stage edge features (bf16) + init pm
  for (int it = t; it < 2560; it += 256) {
    const int r = it >> 5, q = it & 31;
    const int p = r / 20, k = r - (r / 20) * 20;
    const int n = b * NN + pbase + p;
    const int j = b * NN + idx[(size_t)n * KK + k];
    const float4 uv = *(const float4*)&U[(size_t)n * 128 + q * 4];
    const float4 vv = *(const float4*)&V[(size_t)j * 128 + q * 4];
    ushort4 h;
    h.x = f2bf(fmaxf(uv.x + vv.x, 0.f));
    h.y = f2bf(fmaxf(uv.y + vv.y, 0.f));
    h.z = f2bf(fmaxf(uv.z + vv.z, 0.f));
    h.w = f2bf(fmaxf(uv.w + vv.w, 0.f));
    *(ushort4*)&E[r][q * 4] = h;
  }
  for (int i = t; i < 1024; i += 256) ((unsigned int*)pm)[i] = 0u;
  __syncthreads();

  // ---- layer 2: [80x128] @ [128x128] -> E2 (bf16, relu+bias)
  {
    bf16x8 wf[2][4];
#pragma unroll
    for (int nt2 = 0; nt2 < 2; ++nt2) {
      const int ntg = wave * 2 + nt2;
#pragma unroll
      for (int ks = 0; ks < 4; ++ks)
        wf[nt2][ks] = *(const bf16x8*)&w2t[(size_t)(ntg * 16 + lrow) * 128 + ks * 32 + lk8];
    }
    const float bias0 = b2[wave * 32 + lrow];
    const float bias1 = b2[wave * 32 + 16 + lrow];
#pragma unroll
    for (int mt = 0; mt < 5; ++mt) {
      bf16x8 af[4];
#pragma unroll
      for (int ks = 0; ks < 4; ++ks)
        af[ks] = *(const bf16x8*)&E[mt * 16 + lrow][ks * 32 + lk8];
      f32x4 acc0 = {0.f, 0.f, 0.f, 0.f};
      f32x4 acc1 = {0.f, 0.f, 0.f, 0.f};
#pragma unroll
      for (int ks = 0; ks < 4; ++ks) {
        acc0 = __builtin_amdgcn_mfma_f32_16x16x32_bf16(af[ks], wf[0][ks], acc0, 0, 0, 0);
        acc1 = __builtin_amdgcn_mfma_f32_16x16x32_bf16(af[ks], wf[1][ks], acc1, 0, 0, 0);
      }
      const int r0 = mt * 16 + ((lane >> 4) << 2);
      const int c0 = wave * 32 + lrow;
#pragma unroll
      for (int reg = 0; reg < 4; ++reg) {
        E2[r0 + reg][c0]      = f2bf(fmaxf(acc0[reg] + bias0, 0.f));
        E2[r0 + reg][c0 + 16] = f2bf(fmaxf(acc1[reg] + bias1, 0.f));
      }
    }
  }
  __syncthreads();

  // ---- layer 3: [80x128] @ [128x256], relu+bias, max over edges into pm
  {
    bf16x8 wf[4][4];
#pragma unroll
    for (int nt4 = 0; nt4 < 4; ++nt4) {
      const int ntg = wave * 4 + nt4;
#pragma unroll
      for (int ks = 0; ks < 4; ++ks)
        wf[nt4][ks] = *(const bf16x8*)&w3t[(size_t)(ntg * 16 + lrow) * 128 + ks * 32 + lk8];
    }
#pragma unroll
    for (int mt = 0; mt < 5; ++mt) {
      bf16x8 af[4];
#pragma unroll
      for (int ks = 0; ks < 4; ++ks)
        af[ks] = *(const bf16x8*)&E2[mt * 16 + lrow][ks * 32 + lk8];
      f32x4 acc[4];
#pragma unroll
      for (int nt4 = 0; nt4 < 4; ++nt4) acc[nt4] = (f32x4){0.f, 0.f, 0.f, 0.f};
#pragma unroll
      for (int ks = 0; ks < 4; ++ks) {
#pragma unroll
        for (int nt4 = 0; nt4 < 4; ++nt4)
          acc[nt4] = __builtin_amdgcn_mfma_f32_16x16x32_bf16(af[ks], wf[nt4][ks], acc[nt4], 0, 0, 0);
      }
      const int r0 = mt * 16 + ((lane >> 4) << 2);
      const int pa = r0 / 20;
      const int pb = (r0 + 3) / 20;
#pragma unroll
      for (int nt4 = 0; nt4 < 4; ++nt4) {
        const int c = wave * 64 + nt4 * 16 + lrow;
        const float bias = b3[c];
        float v0 = fmaxf(acc[nt4][0] + bias, 0.f);
        float v1 = fmaxf(acc[nt4][1] + bias, 0.f);
        float v2 = fmaxf(acc[nt4][2] + bias, 0.f);
        float v3 = fmaxf(acc[nt4][3] + bias, 0.f);
        if (pa == pb) {
          atomicMax(&pm[pa][c], __float_as_uint(fmaxf(fmaxf(v0, v1), fmaxf(v2, v3))));
        } else {
          atomicMax(&pm[(r0 + 0) / 20][c], __float_as_uint(v0));
          atomicMax(&pm[(r0 + 1) / 20][c], __float_as_uint(v1));
          atomicMax(&pm[(r0 + 2) / 20][c], __float_as_uint(v2));
          atomicMax(&pm[(r0 + 3) / 20][c], __float_as_uint(v3));
        }
      }
    }
  }
  __syncthreads();

  // ---- write out: pm bit patterns are the (>=0) float results
  {
    const int p = t >> 6;
    const int c0 = (t & 63) * 4;
    const float4 o = *(const float4*)&pm[p][c0];
    *(float4*)&xout[((size_t)b * NN + pbase + p) * 256 + c0] = o;
  }
}

// ---------------------------------------------------------------------------
// l0 GEMM (16384x512 @ K=256) + relu + per-64-row max partials (unchanged).
// ---------------------------------------------------------------------------
__global__ __launch_bounds__(256) void l0_kernel(const float* __restrict__ x2,
                                                 const float* __restrict__ w,
                                                 const float* __restrict__ bias,
                                                 float* __restrict__ gp) {
  __shared__ float A[64][68];
  __shared__ float red[16][128];
  const int bid = blockIdx.x;
  const int b = bid >> 7;
  const int mblk = (bid >> 2) & 31;
  const int cblk = bid & 3;
  const int t = threadIdx.x;
  const int ty = t >> 4, tx = t & 15;
  const float* xb = x2 + ((size_t)b * NN + mblk * 64) * 256;
  float acc[4][8];
#pragma unroll
  for (int u = 0; u < 4; ++u)
#pragma unroll
    for (int i = 0; i < 8; ++i) acc[u][i] = 0.f;
  for (int kc = 0; kc < 4; ++kc) {
    {
      const int r = t >> 2, seg = (t & 3) * 16;
#pragma unroll
      for (int s4 = 0; s4 < 4; ++s4) {
        *(float4*)&A[r][seg + s4 * 4] =
            *(const float4*)&xb[(size_t)r * 256 + kc * 64 + seg + s4 * 4];
      }
    }
    __syncthreads();
    for (int d0 = 0; d0 < 64; d0 += 4) {
      float4 a[4];
#pragma unroll
      for (int u = 0; u < 4; ++u) a[u] = *(const float4*)&A[ty * 4 + u][d0];
#pragma unroll
      for (int dd = 0; dd < 4; ++dd) {
        const size_t wrow = (size_t)(kc * 64 + d0 + dd) * 512 + cblk * 128 + tx * 8;
        const float4 wA = *(const float4*)&w[wrow];
        const float4 wB = *(const float4*)&w[wrow + 4];
#pragma unroll
        for (int u = 0; u < 4; ++u) {
          const float av = (dd == 0) ? a[u].x : (dd == 1) ? a[u].y : (dd == 2) ? a[u].z : a[u].w;
          acc[u][0] = fmaf(av, wA.x, acc[u][0]);
          acc[u][1] = fmaf(av, wA.y, acc[u][1]);
          acc[u][2] = fmaf(av, wA.z, acc[u][2]);
          acc[u][3] = fmaf(av, wA.w, acc[u][3]);
          acc[u][4] = fmaf(av, wB.x, acc[u][4]);
          acc[u][5] = fmaf(av, wB.y, acc[u][5]);
          acc[u][6] = fmaf(av, wB.z, acc[u][6]);
          acc[u][7] = fmaf(av, wB.w, acc[u][7]);
        }
      }
    }
    __syncthreads();
  }
  {
    float4 m0, m1;
    m0.x = fmaxf(fmaxf(acc[0][0], acc[1][0]), fmaxf(acc[2][0], acc[3][0]));
    m0.y = fmaxf(fmaxf(acc[0][1], acc[1][1]), fmaxf(acc[2][1], acc[3][1]));
    m0.z = fmaxf(fmaxf(acc[0][2], acc[1][2]), fmaxf(acc[2][2], acc[3][2]));
    m0.w = fmaxf(fmaxf(acc[0][3], acc[1][3]), fmaxf(acc[2][3], acc[3][3]));
    m1.x = fmaxf(fmaxf(acc[0][4], acc[1][4]), fmaxf(acc[2][4], acc[3][4]));
    m1.y = fmaxf(fmaxf(acc[0][5], acc[1][5]), fmaxf(acc[2][5], acc[3][5]));
    m1.z = fmaxf(fmaxf(acc[0][6], acc[1][6]), fmaxf(acc[2][6], acc[3][6]));
    m1.w = fmaxf(fmaxf(acc[0][7], acc[1][7]), fmaxf(acc[2][7], acc[3][7]));
    *(float4*)&red[ty][tx * 8] = m0;
    *(float4*)&red[ty][tx * 8 + 4] = m1;
  }
  __syncthreads();
  if (t < 128) {
    float m = red[0][t];
#pragma unroll
    for (int q = 1; q < 16; ++q) m = fmaxf(m, red[q][t]);
    m = fmaxf(m + bias[cblk * 128 + t], 0.f);
    gp[((size_t)b * 32 + mblk) * 512 + cblk * 128 + t] = m;
  }
}

// ---------------------------------------------------------------------------
// final pool-reduce (32 partials) + classifier head + log_softmax (unchanged).
// ---------------------------------------------------------------------------
__global__ __launch_bounds__(256) void head_kernel(
    const float* __restrict__ gp,
    const float* __restrict__ l1w, const float* __restrict__ l1b,
    const float* __restrict__ l2w, const float* __restrict__ l2b,
    const float* __restrict__ l3w, const float* __restrict__ l3b,
    float* __restrict__ out) {
  __shared__ float g[512];
  __shared__ float h1[256];
  __shared__ float h2[256];
  __shared__ float logits[40];
  __shared__ float lse_s;
  const int b = blockIdx.x;
  const int t = threadIdx.x;
  for (int cidx = t; cidx < 512; cidx += 256) {
    float m = gp[(size_t)(b * 32) * 512 + cidx];
    for (int ch = 1; ch < 32; ++ch) m = fmaxf(m, gp[(size_t)(b * 32 + ch) * 512 + cidx]);
    g[cidx] = m;
  }
  __syncthreads();
  {
    float acc = 0.f;
    for (int d = 0; d < 512; d += 4) {
      const float4 gv = *(const float4*)&g[d];
      acc = fmaf(gv.x, l1w[(size_t)d * 256 + t], acc);
      acc = fmaf(gv.y, l1w[(size_t)(d + 1) * 256 + t], acc);
      acc = fmaf(gv.z, l1w[(size_t)(d + 2) * 256 + t], acc);
      acc = fmaf(gv.w, l1w[(size_t)(d + 3) * 256 + t], acc);
    }
    h1[t] = fmaxf(acc + l1b[t], 0.f);
  }
  __syncthreads();
  {
    float acc = 0.f;
    for (int d = 0; d < 256; d += 4) {
      const float4 hv = *(const float4*)&h1[d];
      acc = fmaf(hv.x, l2w[(size_t)d * 256 + t], acc);
      acc = fmaf(hv.y, l2w[(size_t)(d + 1) * 256 + t], acc);
      acc = fmaf(hv.z, l2w[(size_t)(d + 2) * 256 + t], acc);
      acc = fmaf(hv.w, l2w[(size_t)(d + 3) * 256 + t], acc);
    }
    h2[t] = fmaxf(acc + l2b[t], 0.f);
  }
  __syncthreads();
  if (t < 40) {
    float acc = 0.f;
    for (int d = 0; d < 256; ++d) acc = fmaf(h2[d], l3w[(size_t)d * 40 + t], acc);
    logits[t] = acc + l3b[t];
  }
  __syncthreads();
  if (t == 0) {
    float M = -INFINITY;
    for (int j = 0; j < 40; ++j) M = fmaxf(M, logits[j]);
    float ssum = 0.f;
    for (int j = 0; j < 40; ++j) ssum += expf(logits[j] - M);
    lse_s = M + logf(ssum);
  }
  __syncthreads();
  if (t < 40) out[(size_t)b * 40 + t] = logits[t] - lse_s;
}

// ---------------------------------------------------------------------------
extern "C" void kernel_launch(void* const* d_in, const int* in_sizes, int n_in,
                              void* d_out, int out_size, void* d_ws, size_t ws_size,
                              hipStream_t stream) {
  const float* pos  = (const float*)d_in[0];
  const float* c1w1 = (const float*)d_in[2];
  const float* c1b1 = (const float*)d_in[3];
  const float* c1w2 = (const float*)d_in[4];
  const float* c1b2 = (const float*)d_in[5];
  const float* c1w3 = (const float*)d_in[6];
  const float* c1b3 = (const float*)d_in[7];
  const float* c2w1 = (const float*)d_in[8];
  const float* c2b1 = (const float*)d_in[9];
  const float* c2w2 = (const float*)d_in[10];
  const float* c2b2 = (const float*)d_in[11];
  const float* c2w3 = (const float*)d_in[12];
  const float* c2b3 = (const float*)d_in[13];
  const float* l0w  = (const float*)d_in[14];
  const float* l0b  = (const float*)d_in[15];
  const float* l1w  = (const float*)d_in[16];
  const float* l1b  = (const float*)d_in[17];
  const float* l2w  = (const float*)d_in[18];
  const float* l2b  = (const float*)d_in[19];
  const float* l3w  = (const float*)d_in[20];
  const float* l3b  = (const float*)d_in[21];
  float* out = (float*)d_out;

  char* ws = (char*)d_ws;
  float* x1    = (float*)(ws + 0);                      // 4 MB    [8,2048,64]
  float* x2    = (float*)(ws + ((size_t)4 << 20));      // 16 MB   [8,2048,256]
  int*   idx1  = (int*)  (ws + ((size_t)20 << 20));     // 1.31 MB [16384,20]
  int*   idx2  = (int*)  (ws + ((size_t)22 << 20));     // 1.31 MB
  float* gp    = (float*)(ws + ((size_t)24 << 20));     // 512 KB  [8,32,512]
  unsigned short* w2t = (unsigned short*)(ws + ((size_t)24 << 20) + (512 << 10)); // 32 KB
  unsigned short* w3t = (unsigned short*)(ws + ((size_t)24 << 20) + (544 << 10)); // 64 KB
  float* candd = (float*)(ws + ((size_t)25 << 20));     // 21 MB   [8,16,20,2048]
  int*   candi = (int*)  (ws + ((size_t)46 << 20));     // 21 MB
  // Overlays (regions dead at time of use -- see launch order):
  float* U1 = (float*)(ws + ((size_t)25 << 20));        // 4 MB over candd (dead after merge1)
  float* V1 = (float*)(ws + ((size_t)29 << 20));        // 4 MB
  float* U  = (float*)(ws + ((size_t)46 << 20));        // 8 MB over candi (dead after merge2)
  float* Vv = (float*)(ws + ((size_t)54 << 20));        // 8 MB

  knn1_part<<<512, 256, 0, stream>>>(pos, candd, candi);
  merge_topk<<<128, 128, 0, stream>>>(candd, candi, idx1, 8);
  pre1_kernel<<<4096, 256, 0, stream>>>(pos, c1w1, c1b1, U1, V1);      // overwrites candd region
  conv1_kernel<<<2048, 256, 0, stream>>>(U1, V1, idx1, c1w2, c1b2, c1w3, c1b3, x1);
  d2sel_kernel<<<2048, 256, 0, stream>>>(x1, candd, candi);            // U1/V1 dead now
  merge_topk<<<128, 128, 0, stream>>>(candd, candi, idx2, 16);
  pre2_kernel<<<256, 256, 0, stream>>>(x1, c2w1, c2b1, U, Vv);         // overwrites candi region
  wprep_kernel<<<192, 256, 0, stream>>>(c2w2, c2w3, w2t, w3t);
  conv2_kernel<<<4096, 256, 0, stream>>>(U, Vv, idx2, w2t, c2b2, w3t, c2b3, x2);
  l0_kernel<<<1024, 256, 0, stream>>>(x2, l0w, l0b, gp);
  head_kernel<<<8, 256, 0, stream>>>(gp, l1w, l1b, l2w, l2b, l3w, l3b, out);
}

// Round 5
// 713.641 us; speedup vs baseline: 3.5100x; 1.3765x over previous
//
#include <hip/hip_runtime.h>
#include <hip/hip_bf16.h>
#include <math.h>

#define BB 8
#define NN 2048
#define KK 20

typedef short bf16x8 __attribute__((ext_vector_type(8)));
typedef float f32x4 __attribute__((ext_vector_type(4)));

// fp32 -> bf16 (round-to-nearest-even), finite inputs only
__device__ __forceinline__ unsigned short f2bf(float f) {
  unsigned u = __float_as_uint(f);
  u += 0x7FFFu + ((u >> 16) & 1u);
  return (unsigned short)(u >> 16);
}

// ---------------------------------------------------------------------------
// top-K (K=20) smallest-value tracker, fully register-resident.
// Strict < keeps the earliest-seen on ties.
// ---------------------------------------------------------------------------
__device__ __forceinline__ void topk_insert(float d, int m, float (&bd)[KK], int (&bi)[KK],
                                            float& worst, int& wslot) {
  if (d < worst) {
#pragma unroll
    for (int j = 0; j < KK; ++j) {
      if (j == wslot) { bd[j] = d; bi[j] = m; }
    }
    float w = -INFINITY;
    int s = 0;
#pragma unroll
    for (int j = 0; j < KK; ++j) {
      if (bd[j] > w) { w = bd[j]; s = j; }
    }
    worst = w;
    wslot = s;
  }
}

// ---------------------------------------------------------------------------
// kNN pass 1 for conv1 (D=3), m-chunked: grid = 8 clouds x 8 nchunk x 8 mchunk.
// ---------------------------------------------------------------------------
__global__ __launch_bounds__(256) void knn1_part(const float* __restrict__ pos,
                                                 float* __restrict__ candd,
                                                 int* __restrict__ candi) {
  __shared__ float xs0[256], xs1[256], xs2[256], ss[256];
  const int bid = blockIdx.x;
  const int b = bid >> 6;
  const int nc = (bid >> 3) & 7;
  const int mc = bid & 7;
  const int t = threadIdx.x;
  const float* posb = pos + (size_t)b * NN * 3;
  {
    const int m = mc * 256 + t;
    const float a0 = posb[m * 3 + 0];
    const float a1 = posb[m * 3 + 1];
    const float a2 = posb[m * 3 + 2];
    xs0[t] = a0; xs1[t] = a1; xs2[t] = a2;
    ss[t] = a0 * a0 + a1 * a1 + a2 * a2;
  }
  __syncthreads();
  const int n = nc * 256 + t;
  const float xn0 = posb[n * 3 + 0];
  const float xn1 = posb[n * 3 + 1];
  const float xn2 = posb[n * 3 + 2];
  const float sn = xn0 * xn0 + xn1 * xn1 + xn2 * xn2;  // same expr as ss -> self-dist exact 0
  float bd[KK]; int bi[KK];
#pragma unroll
  for (int j = 0; j < KK; ++j) { bd[j] = INFINITY; bi[j] = 0; }
  float worst = INFINITY;
  int wslot = 0;
  for (int lm = 0; lm < 256; lm += 8) {
    float dv[8];
#pragma unroll
    for (int u = 0; u < 8; ++u) {
      const int q = lm + u;
      dv[u] = sn + ss[q] - 2.f * (xn0 * xs0[q] + xn1 * xs1[q] + xn2 * xs2[q]);
    }
#pragma unroll
    for (int u = 0; u < 8; ++u) topk_insert(dv[u], mc * 256 + lm + u, bd, bi, worst, wslot);
  }
#pragma unroll
  for (int j = 0; j < KK; ++j) {
    const size_t o = ((size_t)(b * 8 + mc) * KK + j) * 2048 + n;
    candd[o] = bd[j];
    candi[o] = bi[j];
  }
}

// ---------------------------------------------------------------------------
// merge v2: G threads per point; each merges NCH/G chunks (batched loads),
// then a shfl_xor tree combines the G partial lists. Blocked chunk
// assignment keeps increasing-m order on the surviving merge path (ties ->
// lowest m, matching top_k).
// ---------------------------------------------------------------------------
template <int NCH, int G>
__global__ __launch_bounds__(256) void merge_topk2(const float* __restrict__ candd,
                                                   const int* __restrict__ candi,
                                                   int* __restrict__ idx_out) {
  const int gid = blockIdx.x * 256 + threadIdx.x;
  const int pt = gid / G;
  const int sub = gid % G;
  const int b = pt >> 11, n = pt & 2047;
  constexpr int CPT = NCH / G;
  float bd[KK]; int bi[KK];
#pragma unroll
  for (int j = 0; j < KK; ++j) { bd[j] = INFINITY; bi[j] = 0; }
  float worst = INFINITY;
  int wslot = 0;
#pragma unroll
  for (int cc = 0; cc < CPT; ++cc) {
    const int c = sub * CPT + cc;
    const size_t base = ((size_t)(b * NCH + c) * KK) * 2048 + n;
    float dv[KK]; int iv[KK];
#pragma unroll
    for (int j = 0; j < KK; ++j) dv[j] = candd[base + (size_t)j * 2048];
#pragma unroll
    for (int j = 0; j < KK; ++j) iv[j] = candi[base + (size_t)j * 2048];
#pragma unroll
    for (int j = 0; j < KK; ++j) topk_insert(dv[j], iv[j], bd, bi, worst, wslot);
  }
#pragma unroll
  for (int stride = 1; stride < G; stride <<= 1) {
    float od[KK]; int oi[KK];
#pragma unroll
    for (int q = 0; q < KK; ++q) {
      od[q] = __shfl_xor(bd[q], stride);
      oi[q] = __shfl_xor(bi[q], stride);
    }
#pragma unroll
    for (int q = 0; q < KK; ++q) topk_insert(od[q], oi[q], bd, bi, worst, wslot);
  }
  if (sub == 0) {
    int* op = idx_out + (size_t)pt * KK;
#pragma unroll
    for (int j = 0; j < KK; ++j) op[j] = bi[j];
  }
}

// ---------------------------------------------------------------------------
// pre1: per-point factorized conv1 layer-1.
// ---------------------------------------------------------------------------
__global__ __launch_bounds__(256) void pre1_kernel(const float* __restrict__ pos,
                                                   const float* __restrict__ w1,
                                                   const float* __restrict__ b1,
                                                   float* __restrict__ U1,
                                                   float* __restrict__ V1) {
  const int t = threadIdx.x;
  const int c = t & 63;
  const int n = blockIdx.x * 4 + (t >> 6);
  const float p0 = pos[(size_t)n * 3 + 0];
  const float p1 = pos[(size_t)n * 3 + 1];
  const float p2 = pos[(size_t)n * 3 + 2];
  const float wt0 = w1[0 * 64 + c], wt1 = w1[1 * 64 + c], wt2 = w1[2 * 64 + c];
  const float wb0 = w1[3 * 64 + c], wb1 = w1[4 * 64 + c], wb2 = w1[5 * 64 + c];
  float v = p0 * wb0 + p1 * wb1 + p2 * wb2;
  float u = p0 * (wt0 - wb0) + p1 * (wt1 - wb1) + p2 * (wt2 - wb2) + b1[c];
  U1[(size_t)n * 64 + c] = u;
  V1[(size_t)n * 64 + c] = v;
}

// ---------------------------------------------------------------------------
// pre2: per-point factorized conv2 layer-1 (GEMM 16384x128 @ K=64, x2 halves).
// ---------------------------------------------------------------------------
__global__ __launch_bounds__(256) void pre2_kernel(const float* __restrict__ x1,
                                                   const float* __restrict__ w1,
                                                   const float* __restrict__ b1,
                                                   float* __restrict__ U,
                                                   float* __restrict__ V) {
  __shared__ float X[64][68];
  const int nbase = blockIdx.x * 64;
  const int t = threadIdx.x;
  for (int it = t; it < 1024; it += 256) {
    const int r = it >> 4, q = it & 15;
    *(float4*)&X[r][q * 4] = *(const float4*)&x1[(size_t)(nbase + r) * 64 + q * 4];
  }
  __syncthreads();
  const int ty = t >> 4, tx = t & 15;
  const int c0 = tx * 8;
  float accT[4][8], accB[4][8];
#pragma unroll
  for (int u = 0; u < 4; ++u)
#pragma unroll
    for (int i = 0; i < 8; ++i) { accT[u][i] = 0.f; accB[u][i] = 0.f; }
  for (int d0 = 0; d0 < 64; d0 += 4) {
    float4 a[4];
#pragma unroll
    for (int u = 0; u < 4; ++u) a[u] = *(const float4*)&X[ty * 4 + u][d0];
#pragma unroll
    for (int dd = 0; dd < 4; ++dd) {
      const float4 t0 = *(const float4*)&w1[(size_t)(d0 + dd) * 128 + c0];
      const float4 t1 = *(const float4*)&w1[(size_t)(d0 + dd) * 128 + c0 + 4];
      const float4 bb0 = *(const float4*)&w1[(size_t)(64 + d0 + dd) * 128 + c0];
      const float4 bb1 = *(const float4*)&w1[(size_t)(64 + d0 + dd) * 128 + c0 + 4];
#pragma unroll
      for (int u = 0; u < 4; ++u) {
        const float av = (dd == 0) ? a[u].x : (dd == 1) ? a[u].y : (dd == 2) ? a[u].z : a[u].w;
        accT[u][0] = fmaf(av, t0.x, accT[u][0]);
        accT[u][1] = fmaf(av, t0.y, accT[u][1]);
        accT[u][2] = fmaf(av, t0.z, accT[u][2]);
        accT[u][3] = fmaf(av, t0.w, accT[u][3]);
        accT[u][4] = fmaf(av, t1.x, accT[u][4]);
        accT[u][5] = fmaf(av, t1.y, accT[u][5]);
        accT[u][6] = fmaf(av, t1.z, accT[u][6]);
        accT[u][7] = fmaf(av, t1.w, accT[u][7]);
        accB[u][0] = fmaf(av, bb0.x, accB[u][0]);
        accB[u][1] = fmaf(av, bb0.y, accB[u][1]);
        accB[u][2] = fmaf(av, bb0.z, accB[u][2]);
        accB[u][3] = fmaf(av, bb0.w, accB[u][3]);
        accB[u][4] = fmaf(av, bb1.x, accB[u][4]);
        accB[u][5] = fmaf(av, bb1.y, accB[u][5]);
        accB[u][6] = fmaf(av, bb1.z, accB[u][6]);
        accB[u][7] = fmaf(av, bb1.w, accB[u][7]);
      }
    }
  }
  const float4 bA = *(const float4*)&b1[c0];
  const float4 bB = *(const float4*)&b1[c0 + 4];
#pragma unroll
  for (int u = 0; u < 4; ++u) {
    const size_t row = (size_t)(nbase + ty * 4 + u) * 128 + c0;
    float4 u0, u1, v0, v1;
    v0 = make_float4(accB[u][0], accB[u][1], accB[u][2], accB[u][3]);
    v1 = make_float4(accB[u][4], accB[u][5], accB[u][6], accB[u][7]);
    u0.x = accT[u][0] - accB[u][0] + bA.x;
    u0.y = accT[u][1] - accB[u][1] + bA.y;
    u0.z = accT[u][2] - accB[u][2] + bA.z;
    u0.w = accT[u][3] - accB[u][3] + bA.w;
    u1.x = accT[u][4] - accB[u][4] + bB.x;
    u1.y = accT[u][5] - accB[u][5] + bB.y;
    u1.z = accT[u][6] - accB[u][6] + bB.z;
    u1.w = accT[u][7] - accB[u][7] + bB.w;
    *(float4*)&U[row] = u0;
    *(float4*)&U[row + 4] = u1;
    *(float4*)&V[row] = v0;
    *(float4*)&V[row + 4] = v1;
  }
}

// ---------------------------------------------------------------------------
// conv1 EdgeConv layers 2,3 (64->64->64, max over 20 edges), 8 points/block.
// ---------------------------------------------------------------------------
__global__ __launch_bounds__(256) void conv1_kernel(
    const float* __restrict__ U1, const float* __restrict__ V1,
    const int* __restrict__ idx,
    const float* __restrict__ w2, const float* __restrict__ b2,
    const float* __restrict__ w3, const float* __restrict__ b3,
    float* __restrict__ xout) {
  __shared__ float H[160][68];
  __shared__ float pm[8][4][64];
  const int bid = blockIdx.x;
  const int b = bid >> 8;               // 256 blocks per cloud
  const int pbase = (bid & 255) * 8;
  const int t = threadIdx.x;
  const int ty = t >> 3, tx = t & 7;
  const int r0 = ty * 5, c0 = tx * 8;

  for (int it = t; it < 2560; it += 256) {
    const int r = it >> 4, q = it & 15;
    const int p = r / 20, k = r - (r / 20) * 20;
    const int n = b * NN + pbase + p;
    const int j = b * NN + idx[(size_t)n * KK + k];
    const float4 uv = *(const float4*)&U1[(size_t)n * 64 + q * 4];
    const float4 vv = *(const float4*)&V1[(size_t)j * 64 + q * 4];
    float4 h;
    h.x = fmaxf(uv.x + vv.x, 0.f);
    h.y = fmaxf(uv.y + vv.y, 0.f);
    h.z = fmaxf(uv.z + vv.z, 0.f);
    h.w = fmaxf(uv.w + vv.w, 0.f);
    *(float4*)&H[r][q * 4] = h;
  }
  __syncthreads();

  float acc[5][8];
  // ---- layer 2: 64 -> 64 (in-place H)
#pragma unroll
  for (int u = 0; u < 5; ++u)
#pragma unroll
    for (int i = 0; i < 8; ++i) acc[u][i] = 0.f;
  for (int d0 = 0; d0 < 64; d0 += 4) {
    float4 a[5];
#pragma unroll
    for (int u = 0; u < 5; ++u) a[u] = *(const float4*)&H[r0 + u][d0];
#pragma unroll
    for (int dd = 0; dd < 4; ++dd) {
      const float4 wA = *(const float4*)&w2[(size_t)(d0 + dd) * 64 + c0];
      const float4 wB = *(const float4*)&w2[(size_t)(d0 + dd) * 64 + c0 + 4];
#pragma unroll
      for (int u = 0; u < 5; ++u) {
        const float av = (dd == 0) ? a[u].x : (dd == 1) ? a[u].y : (dd == 2) ? a[u].z : a[u].w;
        acc[u][0] = fmaf(av, wA.x, acc[u][0]);
        acc[u][1] = fmaf(av, wA.y, acc[u][1]);
        acc[u][2] = fmaf(av, wA.z, acc[u][2]);
        acc[u][3] = fmaf(av, wA.w, acc[u][3]);
        acc[u][4] = fmaf(av, wB.x, acc[u][4]);
        acc[u][5] = fmaf(av, wB.y, acc[u][5]);
        acc[u][6] = fmaf(av, wB.z, acc[u][6]);
        acc[u][7] = fmaf(av, wB.w, acc[u][7]);
      }
    }
  }
  __syncthreads();
  {
    const float4 bA = *(const float4*)&b2[c0];
    const float4 bB = *(const float4*)&b2[c0 + 4];
#pragma unroll
    for (int u = 0; u < 5; ++u) {
      float4 oA, oB;
      oA.x = fmaxf(acc[u][0] + bA.x, 0.f); oA.y = fmaxf(acc[u][1] + bA.y, 0.f);
      oA.z = fmaxf(acc[u][2] + bA.z, 0.f); oA.w = fmaxf(acc[u][3] + bA.w, 0.f);
      oB.x = fmaxf(acc[u][4] + bB.x, 0.f); oB.y = fmaxf(acc[u][5] + bB.y, 0.f);
      oB.z = fmaxf(acc[u][6] + bB.z, 0.f); oB.w = fmaxf(acc[u][7] + bB.w, 0.f);
      *(float4*)&H[r0 + u][c0] = oA;
      *(float4*)&H[r0 + u][c0 + 4] = oB;
    }
  }
  __syncthreads();

  // ---- layer 3: 64 -> 64, then max over k
#pragma unroll
  for (int u = 0; u < 5; ++u)
#pragma unroll
    for (int i = 0; i < 8; ++i) acc[u][i] = 0.f;
  for (int d0 = 0; d0 < 64; d0 += 4) {
    float4 a[5];
#pragma unroll
    for (int u = 0; u < 5; ++u) a[u] = *(const float4*)&H[r0 + u][d0];
#pragma unroll
    for (int dd = 0; dd < 4; ++dd) {
      const float4 wA = *(const float4*)&w3[(size_t)(d0 + dd) * 64 + c0];
      const float4 wB = *(const float4*)&w3[(size_t)(d0 + dd) * 64 + c0 + 4];
#pragma unroll
      for (int u = 0; u < 5; ++u) {
        const float av = (dd == 0) ? a[u].x : (dd == 1) ? a[u].y : (dd == 2) ? a[u].z : a[u].w;
        acc[u][0] = fmaf(av, wA.x, acc[u][0]);
        acc[u][1] = fmaf(av, wA.y, acc[u][1]);
        acc[u][2] = fmaf(av, wA.z, acc[u][2]);
        acc[u][3] = fmaf(av, wA.w, acc[u][3]);
        acc[u][4] = fmaf(av, wB.x, acc[u][4]);
        acc[u][5] = fmaf(av, wB.y, acc[u][5]);
        acc[u][6] = fmaf(av, wB.z, acc[u][6]);
        acc[u][7] = fmaf(av, wB.w, acc[u][7]);
      }
    }
  }
  {
    const int p = ty >> 2, sub = ty & 3;
    float4 m0, m1;
    m0.x = fmaxf(fmaxf(fmaxf(acc[0][0], acc[1][0]), fmaxf(acc[2][0], acc[3][0])), acc[4][0]);
    m0.y = fmaxf(fmaxf(fmaxf(acc[0][1], acc[1][1]), fmaxf(acc[2][1], acc[3][1])), acc[4][1]);
    m0.z = fmaxf(fmaxf(fmaxf(acc[0][2], acc[1][2]), fmaxf(acc[2][2], acc[3][2])), acc[4][2]);
    m0.w = fmaxf(fmaxf(fmaxf(acc[0][3], acc[1][3]), fmaxf(acc[2][3], acc[3][3])), acc[4][3]);
    m1.x = fmaxf(fmaxf(fmaxf(acc[0][4], acc[1][4]), fmaxf(acc[2][4], acc[3][4])), acc[4][4]);
    m1.y = fmaxf(fmaxf(fmaxf(acc[0][5], acc[1][5]), fmaxf(acc[2][5], acc[3][5])), acc[4][5]);
    m1.z = fmaxf(fmaxf(fmaxf(acc[0][6], acc[1][6]), fmaxf(acc[2][6], acc[3][6])), acc[4][6]);
    m1.w = fmaxf(fmaxf(fmaxf(acc[0][7], acc[1][7]), fmaxf(acc[2][7], acc[3][7])), acc[4][7]);
    *(float4*)&pm[p][sub][c0] = m0;
    *(float4*)&pm[p][sub][c0 + 4] = m1;
  }
  __syncthreads();
  {
    const int pp = t >> 5;
    const int cc = (t & 31) * 2;
    float m0 = fmaxf(fmaxf(pm[pp][0][cc], pm[pp][1][cc]), fmaxf(pm[pp][2][cc], pm[pp][3][cc]));
    float m1 = fmaxf(fmaxf(pm[pp][0][cc + 1], pm[pp][1][cc + 1]),
                     fmaxf(pm[pp][2][cc + 1], pm[pp][3][cc + 1]));
    float2 o;
    o.x = fmaxf(m0 + b3[cc], 0.f);
    o.y = fmaxf(m1 + b3[cc + 1], 0.f);
    *(float2*)&xout[((size_t)bid) * 8 * 64 + (size_t)pp * 64 + cc] = o;
  }
}

// ---------------------------------------------------------------------------
// d2 + fused partial selection for conv2 kNN (unchanged).
// ---------------------------------------------------------------------------
__global__ __launch_bounds__(256) void d2sel_kernel(const float* __restrict__ x1,
                                                    float* __restrict__ candd,
                                                    int* __restrict__ candi) {
  __shared__ __align__(16) float Ubuf[16896];   // At[64][132]+Bt[64][132] | T[128][131]
  float (*At)[132] = (float(*)[132])Ubuf;
  float (*Bt)[132] = (float(*)[132])(Ubuf + 64 * 132);
  float (*T)[131] = (float(*)[131])Ubuf;
  __shared__ float sA[128], sB[128];
  const int bid = blockIdx.x;
  const int b = bid >> 8;
  const int tile = bid & 255;
  const int ti = tile >> 4, tj = tile & 15;
  const int i0 = ti * 128, j0 = tj * 128;
  const float* xb = x1 + (size_t)b * NN * 64;
  const int t = threadIdx.x;
  for (int item = t; item < 8192; item += 256) {
    const int r = item >> 6, d = item & 63;
    At[d][r] = xb[(size_t)(i0 + r) * 64 + d];
    Bt[d][r] = xb[(size_t)(j0 + r) * 64 + d];
  }
  __syncthreads();
  if (t < 128) {
    float s = 0.f;
    for (int k = 0; k < 64; ++k) s = fmaf(At[k][t], At[k][t], s);
    sA[t] = s;
  } else {
    const int r = t - 128;
    float s = 0.f;
    for (int k = 0; k < 64; ++k) s = fmaf(Bt[k][r], Bt[k][r], s);
    sB[r] = s;
  }
  __syncthreads();
  const int tx = t & 15, ty = t >> 4;
  float acc[8][8];
#pragma unroll
  for (int u = 0; u < 8; ++u)
#pragma unroll
    for (int v = 0; v < 8; ++v) acc[u][v] = 0.f;
  for (int k = 0; k < 64; ++k) {
    const float4 a0 = *(const float4*)&At[k][ty * 8];
    const float4 a1 = *(const float4*)&At[k][ty * 8 + 4];
    const float4 b0 = *(const float4*)&Bt[k][tx * 8];
    const float4 b1 = *(const float4*)&Bt[k][tx * 8 + 4];
    const float av[8] = {a0.x, a0.y, a0.z, a0.w, a1.x, a1.y, a1.z, a1.w};
    const float bv[8] = {b0.x, b0.y, b0.z, b0.w, b1.x, b1.y, b1.z, b1.w};
#pragma unroll
    for (int u = 0; u < 8; ++u)
#pragma unroll
      for (int v = 0; v < 8; ++v) acc[u][v] = fmaf(av[u], bv[v], acc[u][v]);
  }
  __syncthreads();   // all At/Bt reads done before T overwrites the union
  {
#pragma unroll
    for (int u = 0; u < 8; ++u) {
      const int i = ty * 8 + u;
      const float si = sA[i];
#pragma unroll
      for (int v = 0; v < 8; ++v) {
        T[i][tx * 8 + v] = si + sB[tx * 8 + v] - 2.f * acc[u][v];
      }
    }
  }
  __syncthreads();
  const int j = t >> 1, h = t & 1;
  float bd[KK]; int bi[KK];
#pragma unroll
  for (int q = 0; q < KK; ++q) { bd[q] = INFINITY; bi[q] = 0; }
  float worst = INFINITY;
  int wslot = 0;
  const int mbase = i0 + h * 64;
  for (int r = 0; r < 64; ++r) {
    topk_insert(T[h * 64 + r][j], mbase + r, bd, bi, worst, wslot);
  }
  float od[KK]; int oi[KK];
#pragma unroll
  for (int q = 0; q < KK; ++q) {
    od[q] = __shfl_xor(bd[q], 1);
    oi[q] = __shfl_xor(bi[q], 1);
  }
#pragma unroll
  for (int q = 0; q < KK; ++q) topk_insert(od[q], oi[q], bd, bi, worst, wslot);
  if (h == 0) {
#pragma unroll
    for (int q = 0; q < KK; ++q) {
      const size_t o = ((size_t)(b * 16 + ti) * KK + q) * 2048 + (j0 + j);
      candd[o] = bd[q];
      candi[o] = bi[q];
    }
  }
}

// ---------------------------------------------------------------------------
// wprep: transpose+convert conv2 weights to bf16 [N][K] for MFMA B-fragments.
// ---------------------------------------------------------------------------
__global__ __launch_bounds__(256) void wprep_kernel(const float* __restrict__ w2,
                                                    const float* __restrict__ w3,
                                                    unsigned short* __restrict__ w2t,
                                                    unsigned short* __restrict__ w3t) {
  const int i = blockIdx.x * 256 + threadIdx.x;
  if (i < 16384) {
    const int d = i >> 7, c = i & 127;
    w2t[c * 128 + d] = f2bf(w2[i]);
  } else {
    const int j = i - 16384;           // j < 32768
    const int d = j >> 8, c = j & 255;
    w3t[c * 128 + d] = f2bf(w3[j]);
  }
}

// ---------------------------------------------------------------------------
// conv2 EdgeConv layers 2,3 via bf16 MFMA (16x16x32), 4 points/block.
// ---------------------------------------------------------------------------
__global__ __launch_bounds__(256) void conv2_kernel(
    const float* __restrict__ U, const float* __restrict__ V,
    const int* __restrict__ idx,
    const unsigned short* __restrict__ w2t, const float* __restrict__ b2,
    const unsigned short* __restrict__ w3t, const float* __restrict__ b3,
    float* __restrict__ xout) {
  __shared__ __align__(16) unsigned short E[80][136];
  __shared__ __align__(16) unsigned short E2[80][136];
  __shared__ unsigned int pm[4][256];
  const int bid = blockIdx.x;
  const int b = bid >> 9;               // 512 blocks per cloud
  const int pbase = (bid & 511) * 4;
  const int t = threadIdx.x;
  const int wave = t >> 6, lane = t & 63;
  const int lrow = lane & 15;           // A/B fragment row (M or N index)
  const int lk8 = (lane >> 4) * 8;      // k-offset of the 8-element fragment

  // ---- stage edge features (bf16) + init pm
  for (int it = t; it < 2560; it += 256) {
    const int r = it >> 5, q = it & 31;
    const int p = r / 20, k = r - (r / 20) * 20;
    const int n = b * NN + pbase + p;
    const int j = b * NN + idx[(size_t)n * KK + k];
    const float4 uv = *(const float4*)&U[(size_t)n * 128 + q * 4];
    const float4 vv = *(const float4*)&V[(size_t)j * 128 + q * 4];
    ushort4 h;
    h.x = f2bf(fmaxf(uv.x + vv.x, 0.f));
    h.y = f2bf(fmaxf(uv.y + vv.y, 0.f));
    h.z = f2bf(fmaxf(uv.z + vv.z, 0.f));
    h.w = f2bf(fmaxf(uv.w + vv.w, 0.f));
    *(ushort4*)&E[r][q * 4] = h;
  }
  for (int i = t; i < 1024; i += 256) ((unsigned int*)pm)[i] = 0u;
  __syncthreads();

  // ---- layer 2: [80x128] @ [128x128] -> E2 (bf16, relu+bias)
  {
    bf16x8 wf[2][4];
#pragma unroll
    for (int nt2 = 0; nt2 < 2; ++nt2) {
      const int ntg = wave * 2 + nt2;
#pragma unroll
      for (int ks = 0; ks < 4; ++ks)
        wf[nt2][ks] = *(const bf16x8*)&w2t[(size_t)(ntg * 16 + lrow) * 128 + ks * 32 + lk8];
    }
    const float bias0 = b2[wave * 32 + lrow];
    const float bias1 = b2[wave * 32 + 16 + lrow];
#pragma unroll
    for (int mt = 0; mt < 5; ++mt) {
      bf16x8 af[4];
#pragma unroll
      for (int ks = 0; ks < 4; ++ks)
        af[ks] = *(const bf16x8*)&E[mt * 16 + lrow][ks * 32 + lk8];
      f32x4 acc0 = {0.f, 0.f, 0.f, 0.f};
      f32x4 acc1 = {0.f, 0.f, 0.f, 0.f};
#pragma unroll
      for (int ks = 0; ks < 4; ++ks) {
        acc0 = __builtin_amdgcn_mfma_f32_16x16x32_bf16(af[ks], wf[0][ks], acc0, 0, 0, 0);
        acc1 = __builtin_amdgcn_mfma_f32_16x16x32_bf16(af[ks], wf[1][ks], acc1, 0, 0, 0);
      }
      const int r0 = mt * 16 + ((lane >> 4) << 2);
      const int c0 = wave * 32 + lrow;
#pragma unroll
      for (int reg = 0; reg < 4; ++reg) {
        E2[r0 + reg][c0]      = f2bf(fmaxf(acc0[reg] + bias0, 0.f));
        E2[r0 + reg][c0 + 16] = f2bf(fmaxf(acc1[reg] + bias1, 0.f));
      }
    }
  }
  __syncthreads();

  // ---- layer 3: [80x128] @ [128x256], relu+bias, max over edges into pm
  {
    bf16x8 wf[4][4];
#pragma unroll
    for (int nt4 = 0; nt4 < 4; ++nt4) {
      const int ntg = wave * 4 + nt4;
#pragma unroll
      for (int ks = 0; ks < 4; ++ks)
        wf[nt4][ks] = *(const bf16x8*)&w3t[(size_t)(ntg * 16 + lrow) * 128 + ks * 32 + lk8];
    }
#pragma unroll
    for (int mt = 0; mt < 5; ++mt) {
      bf16x8 af[4];
#pragma unroll
      for (int ks = 0; ks < 4; ++ks)
        af[ks] = *(const bf16x8*)&E2[mt * 16 + lrow][ks * 32 + lk8];
      f32x4 acc[4];
#pragma unroll
      for (int nt4 = 0; nt4 < 4; ++nt4) acc[nt4] = (f32x4){0.f, 0.f, 0.f, 0.f};
#pragma unroll
      for (int ks = 0; ks < 4; ++ks) {
#pragma unroll
        for (int nt4 = 0; nt4 < 4; ++nt4)
          acc[nt4] = __builtin_amdgcn_mfma_f32_16x16x32_bf16(af[ks], wf[nt4][ks], acc[nt4], 0, 0, 0);
      }
      const int r0 = mt * 16 + ((lane >> 4) << 2);
      const int pa = r0 / 20;
      const int pb = (r0 + 3) / 20;
#pragma unroll
      for (int nt4 = 0; nt4 < 4; ++nt4) {
        const int c = wave * 64 + nt4 * 16 + lrow;
        const float bias = b3[c];
        float v0 = fmaxf(acc[nt4][0] + bias, 0.f);
        float v1 = fmaxf(acc[nt4][1] + bias, 0.f);
        float v2 = fmaxf(acc[nt4][2] + bias, 0.f);
        float v3 = fmaxf(acc[nt4][3] + bias, 0.f);
        if (pa == pb) {
          atomicMax(&pm[pa][c], __float_as_uint(fmaxf(fmaxf(v0, v1), fmaxf(v2, v3))));
        } else {
          atomicMax(&pm[(r0 + 0) / 20][c], __float_as_uint(v0));
          atomicMax(&pm[(r0 + 1) / 20][c], __float_as_uint(v1));
          atomicMax(&pm[(r0 + 2) / 20][c], __float_as_uint(v2));
          atomicMax(&pm[(r0 + 3) / 20][c], __float_as_uint(v3));
        }
      }
    }
  }
  __syncthreads();

  // ---- write out: pm bit patterns are the (>=0) float results
  {
    const int p = t >> 6;
    const int c0 = (t & 63) * 4;
    const float4 o = *(const float4*)&pm[p][c0];
    *(float4*)&xout[((size_t)b * NN + pbase + p) * 256 + c0] = o;
  }
}

// ---------------------------------------------------------------------------
// l0 GEMM (16384x512 @ K=256) + relu + per-64-row max partials (unchanged).
// ---------------------------------------------------------------------------
__global__ __launch_bounds__(256) void l0_kernel(const float* __restrict__ x2,
                                                 const float* __restrict__ w,
                                                 const float* __restrict__ bias,
                                                 float* __restrict__ gp) {
  __shared__ float A[64][68];
  __shared__ float red[16][128];
  const int bid = blockIdx.x;
  const int b = bid >> 7;
  const int mblk = (bid >> 2) & 31;
  const int cblk = bid & 3;
  const int t = threadIdx.x;
  const int ty = t >> 4, tx = t & 15;
  const float* xb = x2 + ((size_t)b * NN + mblk * 64) * 256;
  float acc[4][8];
#pragma unroll
  for (int u = 0; u < 4; ++u)
#pragma unroll
    for (int i = 0; i < 8; ++i) acc[u][i] = 0.f;
  for (int kc = 0; kc < 4; ++kc) {
    {
      const int r = t >> 2, seg = (t & 3) * 16;
#pragma unroll
      for (int s4 = 0; s4 < 4; ++s4) {
        *(float4*)&A[r][seg + s4 * 4] =
            *(const float4*)&xb[(size_t)r * 256 + kc * 64 + seg + s4 * 4];
      }
    }
    __syncthreads();
    for (int d0 = 0; d0 < 64; d0 += 4) {
      float4 a[4];
#pragma unroll
      for (int u = 0; u < 4; ++u) a[u] = *(const float4*)&A[ty * 4 + u][d0];
#pragma unroll
      for (int dd = 0; dd < 4; ++dd) {
        const size_t wrow = (size_t)(kc * 64 + d0 + dd) * 512 + cblk * 128 + tx * 8;
        const float4 wA = *(const float4*)&w[wrow];
        const float4 wB = *(const float4*)&w[wrow + 4];
#pragma unroll
        for (int u = 0; u < 4; ++u) {
          const float av = (dd == 0) ? a[u].x : (dd == 1) ? a[u].y : (dd == 2) ? a[u].z : a[u].w;
          acc[u][0] = fmaf(av, wA.x, acc[u][0]);
          acc[u][1] = fmaf(av, wA.y, acc[u][1]);
          acc[u][2] = fmaf(av, wA.z, acc[u][2]);
          acc[u][3] = fmaf(av, wA.w, acc[u][3]);
          acc[u][4] = fmaf(av, wB.x, acc[u][4]);
          acc[u][5] = fmaf(av, wB.y, acc[u][5]);
          acc[u][6] = fmaf(av, wB.z, acc[u][6]);
          acc[u][7] = fmaf(av, wB.w, acc[u][7]);
        }
      }
    }
    __syncthreads();
  }
  {
    float4 m0, m1;
    m0.x = fmaxf(fmaxf(acc[0][0], acc[1][0]), fmaxf(acc[2][0], acc[3][0]));
    m0.y = fmaxf(fmaxf(acc[0][1], acc[1][1]), fmaxf(acc[2][1], acc[3][1]));
    m0.z = fmaxf(fmaxf(acc[0][2], acc[1][2]), fmaxf(acc[2][2], acc[3][2]));
    m0.w = fmaxf(fmaxf(acc[0][3], acc[1][3]), fmaxf(acc[2][3], acc[3][3]));
    m1.x = fmaxf(fmaxf(acc[0][4], acc[1][4]), fmaxf(acc[2][4], acc[3][4]));
    m1.y = fmaxf(fmaxf(acc[0][5], acc[1][5]), fmaxf(acc[2][5], acc[3][5]));
    m1.z = fmaxf(fmaxf(acc[0][6], acc[1][6]), fmaxf(acc[2][6], acc[3][6]));
    m1.w = fmaxf(fmaxf(acc[0][7], acc[1][7]), fmaxf(acc[2][7], acc[3][7]));
    *(float4*)&red[ty][tx * 8] = m0;
    *(float4*)&red[ty][tx * 8 + 4] = m1;
  }
  __syncthreads();
  if (t < 128) {
    float m = red[0][t];
#pragma unroll
    for (int q = 1; q < 16; ++q) m = fmaxf(m, red[q][t]);
    m = fmaxf(m + bias[cblk * 128 + t], 0.f);
    gp[((size_t)b * 32 + mblk) * 512 + cblk * 128 + t] = m;
  }
}

// ---------------------------------------------------------------------------
// final pool-reduce (32 partials) + classifier head + log_softmax (unchanged).
// ---------------------------------------------------------------------------
__global__ __launch_bounds__(256) void head_kernel(
    const float* __restrict__ gp,
    const float* __restrict__ l1w, const float* __restrict__ l1b,
    const float* __restrict__ l2w, const float* __restrict__ l2b,
    const float* __restrict__ l3w, const float* __restrict__ l3b,
    float* __restrict__ out) {
  __shared__ float g[512];
  __shared__ float h1[256];
  __shared__ float h2[256];
  __shared__ float logits[40];
  __shared__ float lse_s;
  const int b = blockIdx.x;
  const int t = threadIdx.x;
  for (int cidx = t; cidx < 512; cidx += 256) {
    float m = gp[(size_t)(b * 32) * 512 + cidx];
    for (int ch = 1; ch < 32; ++ch) m = fmaxf(m, gp[(size_t)(b * 32 + ch) * 512 + cidx]);
    g[cidx] = m;
  }
  __syncthreads();
  {
    float acc = 0.f;
    for (int d = 0; d < 512; d += 4) {
      const float4 gv = *(const float4*)&g[d];
      acc = fmaf(gv.x, l1w[(size_t)d * 256 + t], acc);
      acc = fmaf(gv.y, l1w[(size_t)(d + 1) * 256 + t], acc);
      acc = fmaf(gv.z, l1w[(size_t)(d + 2) * 256 + t], acc);
      acc = fmaf(gv.w, l1w[(size_t)(d + 3) * 256 + t], acc);
    }
    h1[t] = fmaxf(acc + l1b[t], 0.f);
  }
  __syncthreads();
  {
    float acc = 0.f;
    for (int d = 0; d < 256; d += 4) {
      const float4 hv = *(const float4*)&h1[d];
      acc = fmaf(hv.x, l2w[(size_t)d * 256 + t], acc);
      acc = fmaf(hv.y, l2w[(size_t)(d + 1) * 256 + t], acc);
      acc = fmaf(hv.z, l2w[(size_t)(d + 2) * 256 + t], acc);
      acc = fmaf(hv.w, l2w[(size_t)(d + 3) * 256 + t], acc);
    }
    h2[t] = fmaxf(acc + l2b[t], 0.f);
  }
  __syncthreads();
  if (t < 40) {
    float acc = 0.f;
    for (int d = 0; d < 256; ++d) acc = fmaf(h2[d], l3w[(size_t)d * 40 + t], acc);
    logits[t] = acc + l3b[t];
  }
  __syncthreads();
  if (t == 0) {
    float M = -INFINITY;
    for (int j = 0; j < 40; ++j) M = fmaxf(M, logits[j]);
    float ssum = 0.f;
    for (int j = 0; j < 40; ++j) ssum += expf(logits[j] - M);
    lse_s = M + logf(ssum);
  }
  __syncthreads();
  if (t < 40) out[(size_t)b * 40 + t] = logits[t] - lse_s;
}

// ---------------------------------------------------------------------------
extern "C" void kernel_launch(void* const* d_in, const int* in_sizes, int n_in,
                              void* d_out, int out_size, void* d_ws, size_t ws_size,
                              hipStream_t stream) {
  const float* pos  = (const float*)d_in[0];
  const float* c1w1 = (const float*)d_in[2];
  const float* c1b1 = (const float*)d_in[3];
  const float* c1w2 = (const float*)d_in[4];
  const float* c1b2 = (const float*)d_in[5];
  const float* c1w3 = (const float*)d_in[6];
  const float* c1b3 = (const float*)d_in[7];
  const float* c2w1 = (const float*)d_in[8];
  const float* c2b1 = (const float*)d_in[9];
  const float* c2w2 = (const float*)d_in[10];
  const float* c2b2 = (const float*)d_in[11];
  const float* c2w3 = (const float*)d_in[12];
  const float* c2b3 = (const float*)d_in[13];
  const float* l0w  = (const float*)d_in[14];
  const float* l0b  = (const float*)d_in[15];
  const float* l1w  = (const float*)d_in[16];
  const float* l1b  = (const float*)d_in[17];
  const float* l2w  = (const float*)d_in[18];
  const float* l2b  = (const float*)d_in[19];
  const float* l3w  = (const float*)d_in[20];
  const float* l3b  = (const float*)d_in[21];
  float* out = (float*)d_out;

  char* ws = (char*)d_ws;
  float* x1    = (float*)(ws + 0);                      // 4 MB    [8,2048,64]
  float* x2    = (float*)(ws + ((size_t)4 << 20));      // 16 MB   [8,2048,256]
  int*   idx1  = (int*)  (ws + ((size_t)20 << 20));     // 1.31 MB [16384,20]
  int*   idx2  = (int*)  (ws + ((size_t)22 << 20));     // 1.31 MB
  float* gp    = (float*)(ws + ((size_t)24 << 20));     // 512 KB  [8,32,512]
  unsigned short* w2t = (unsigned short*)(ws + ((size_t)24 << 20) + (512 << 10)); // 32 KB
  unsigned short* w3t = (unsigned short*)(ws + ((size_t)24 << 20) + (544 << 10)); // 64 KB
  float* candd = (float*)(ws + ((size_t)25 << 20));     // 21 MB   [8,16,20,2048]
  int*   candi = (int*)  (ws + ((size_t)46 << 20));     // 21 MB
  // Overlays (regions dead at time of use -- see launch order):
  float* U1 = (float*)(ws + ((size_t)25 << 20));        // 4 MB over candd (dead after merge1)
  float* V1 = (float*)(ws + ((size_t)29 << 20));        // 4 MB
  float* U  = (float*)(ws + ((size_t)46 << 20));        // 8 MB over candi (dead after merge2)
  float* Vv = (float*)(ws + ((size_t)54 << 20));        // 8 MB

  knn1_part<<<512, 256, 0, stream>>>(pos, candd, candi);
  merge_topk2<8, 4><<<256, 256, 0, stream>>>(candd, candi, idx1);
  pre1_kernel<<<4096, 256, 0, stream>>>(pos, c1w1, c1b1, U1, V1);      // overwrites candd region
  conv1_kernel<<<2048, 256, 0, stream>>>(U1, V1, idx1, c1w2, c1b2, c1w3, c1b3, x1);
  d2sel_kernel<<<2048, 256, 0, stream>>>(x1, candd, candi);            // U1/V1 dead now
  merge_topk2<16, 8><<<512, 256, 0, stream>>>(candd, candi, idx2);
  pre2_kernel<<<256, 256, 0, stream>>>(x1, c2w1, c2b1, U, Vv);         // overwrites candi region
  wprep_kernel<<<192, 256, 0, stream>>>(c2w2, c2w3, w2t, w3t);
  conv2_kernel<<<4096, 256, 0, stream>>>(U, Vv, idx2, w2t, c2b2, w3t, c2b3, x2);
  l0_kernel<<<1024, 256, 0, stream>>>(x2, l0w, l0b, gp);
  head_kernel<<<8, 256, 0, stream>>>(gp, l1w, l1b, l2w, l2b, l3w, l3b, out);
}

// Round 6
// 686.860 us; speedup vs baseline: 3.6468x; 1.0390x over previous
//
#include <hip/hip_runtime.h>
#include <hip/hip_bf16.h>
#include <math.h>

#define BB 8
#define NN 2048
#define KK 20

typedef short bf16x8 __attribute__((ext_vector_type(8)));
typedef float f32x4 __attribute__((ext_vector_type(4)));

// fp32 -> bf16 (round-to-nearest-even), finite inputs only
__device__ __forceinline__ unsigned short f2bf(float f) {
  unsigned u = __float_as_uint(f);
  u += 0x7FFFu + ((u >> 16) & 1u);
  return (unsigned short)(u >> 16);
}
__device__ __forceinline__ float bf2f(unsigned short h) {
  return __uint_as_float(((unsigned)h) << 16);
}

// ---------------------------------------------------------------------------
// top-K (K=20) smallest-value tracker, fully register-resident.
// Strict < keeps the earliest-seen on ties.
// ---------------------------------------------------------------------------
__device__ __forceinline__ void topk_insert(float d, int m, float (&bd)[KK], int (&bi)[KK],
                                            float& worst, int& wslot) {
  if (d < worst) {
#pragma unroll
    for (int j = 0; j < KK; ++j) {
      if (j == wslot) { bd[j] = d; bi[j] = m; }
    }
    float w = -INFINITY;
    int s = 0;
#pragma unroll
    for (int j = 0; j < KK; ++j) {
      if (bd[j] > w) { w = bd[j]; s = j; }
    }
    worst = w;
    wslot = s;
  }
}

// ---------------------------------------------------------------------------
// kNN pass 1 for conv1 (D=3), m-chunked: grid = 8 clouds x 8 nchunk x 8 mchunk.
// ---------------------------------------------------------------------------
__global__ __launch_bounds__(256) void knn1_part(const float* __restrict__ pos,
                                                 float* __restrict__ candd,
                                                 int* __restrict__ candi) {
  __shared__ float xs0[256], xs1[256], xs2[256], ss[256];
  const int bid = blockIdx.x;
  const int b = bid >> 6;
  const int nc = (bid >> 3) & 7;
  const int mc = bid & 7;
  const int t = threadIdx.x;
  const float* posb = pos + (size_t)b * NN * 3;
  {
    const int m = mc * 256 + t;
    const float a0 = posb[m * 3 + 0];
    const float a1 = posb[m * 3 + 1];
    const float a2 = posb[m * 3 + 2];
    xs0[t] = a0; xs1[t] = a1; xs2[t] = a2;
    ss[t] = a0 * a0 + a1 * a1 + a2 * a2;
  }
  __syncthreads();
  const int n = nc * 256 + t;
  const float xn0 = posb[n * 3 + 0];
  const float xn1 = posb[n * 3 + 1];
  const float xn2 = posb[n * 3 + 2];
  const float sn = xn0 * xn0 + xn1 * xn1 + xn2 * xn2;  // same expr as ss -> self-dist exact 0
  float bd[KK]; int bi[KK];
#pragma unroll
  for (int j = 0; j < KK; ++j) { bd[j] = INFINITY; bi[j] = 0; }
  float worst = INFINITY;
  int wslot = 0;
  for (int lm = 0; lm < 256; lm += 8) {
    float dv[8];
#pragma unroll
    for (int u = 0; u < 8; ++u) {
      const int q = lm + u;
      dv[u] = sn + ss[q] - 2.f * (xn0 * xs0[q] + xn1 * xs1[q] + xn2 * xs2[q]);
    }
#pragma unroll
    for (int u = 0; u < 8; ++u) topk_insert(dv[u], mc * 256 + lm + u, bd, bi, worst, wslot);
  }
#pragma unroll
  for (int j = 0; j < KK; ++j) {
    const size_t o = ((size_t)(b * 8 + mc) * KK + j) * 2048 + n;
    candd[o] = bd[j];
    candi[o] = bi[j];
  }
}

// ---------------------------------------------------------------------------
// merge v2: G threads per point; each merges NCH/G chunks (batched loads),
// then a shfl_xor tree combines the G partial lists.
// ---------------------------------------------------------------------------
template <int NCH, int G>
__global__ __launch_bounds__(256) void merge_topk2(const float* __restrict__ candd,
                                                   const int* __restrict__ candi,
                                                   int* __restrict__ idx_out) {
  const int gid = blockIdx.x * 256 + threadIdx.x;
  const int pt = gid / G;
  const int sub = gid % G;
  const int b = pt >> 11, n = pt & 2047;
  constexpr int CPT = NCH / G;
  float bd[KK]; int bi[KK];
#pragma unroll
  for (int j = 0; j < KK; ++j) { bd[j] = INFINITY; bi[j] = 0; }
  float worst = INFINITY;
  int wslot = 0;
#pragma unroll
  for (int cc = 0; cc < CPT; ++cc) {
    const int c = sub * CPT + cc;
    const size_t base = ((size_t)(b * NCH + c) * KK) * 2048 + n;
    float dv[KK]; int iv[KK];
#pragma unroll
    for (int j = 0; j < KK; ++j) dv[j] = candd[base + (size_t)j * 2048];
#pragma unroll
    for (int j = 0; j < KK; ++j) iv[j] = candi[base + (size_t)j * 2048];
#pragma unroll
    for (int j = 0; j < KK; ++j) topk_insert(dv[j], iv[j], bd, bi, worst, wslot);
  }
#pragma unroll
  for (int stride = 1; stride < G; stride <<= 1) {
    float od[KK]; int oi[KK];
#pragma unroll
    for (int q = 0; q < KK; ++q) {
      od[q] = __shfl_xor(bd[q], stride);
      oi[q] = __shfl_xor(bi[q], stride);
    }
#pragma unroll
    for (int q = 0; q < KK; ++q) topk_insert(od[q], oi[q], bd, bi, worst, wslot);
  }
  if (sub == 0) {
    int* op = idx_out + (size_t)pt * KK;
#pragma unroll
    for (int j = 0; j < KK; ++j) op[j] = bi[j];
  }
}

// ---------------------------------------------------------------------------
// pre1: per-point factorized conv1 layer-1.
// ---------------------------------------------------------------------------
__global__ __launch_bounds__(256) void pre1_kernel(const float* __restrict__ pos,
                                                   const float* __restrict__ w1,
                                                   const float* __restrict__ b1,
                                                   float* __restrict__ U1,
                                                   float* __restrict__ V1) {
  const int t = threadIdx.x;
  const int c = t & 63;
  const int n = blockIdx.x * 4 + (t >> 6);
  const float p0 = pos[(size_t)n * 3 + 0];
  const float p1 = pos[(size_t)n * 3 + 1];
  const float p2 = pos[(size_t)n * 3 + 2];
  const float wt0 = w1[0 * 64 + c], wt1 = w1[1 * 64 + c], wt2 = w1[2 * 64 + c];
  const float wb0 = w1[3 * 64 + c], wb1 = w1[4 * 64 + c], wb2 = w1[5 * 64 + c];
  float v = p0 * wb0 + p1 * wb1 + p2 * wb2;
  float u = p0 * (wt0 - wb0) + p1 * (wt1 - wb1) + p2 * (wt2 - wb2) + b1[c];
  U1[(size_t)n * 64 + c] = u;
  V1[(size_t)n * 64 + c] = v;
}

// ---------------------------------------------------------------------------
// pre2: per-point factorized conv2 layer-1 (GEMM 16384x128 @ K=64, x2 halves).
// ---------------------------------------------------------------------------
__global__ __launch_bounds__(256) void pre2_kernel(const float* __restrict__ x1,
                                                   const float* __restrict__ w1,
                                                   const float* __restrict__ b1,
                                                   float* __restrict__ U,
                                                   float* __restrict__ V) {
  __shared__ float X[64][68];
  const int nbase = blockIdx.x * 64;
  const int t = threadIdx.x;
  for (int it = t; it < 1024; it += 256) {
    const int r = it >> 4, q = it & 15;
    *(float4*)&X[r][q * 4] = *(const float4*)&x1[(size_t)(nbase + r) * 64 + q * 4];
  }
  __syncthreads();
  const int ty = t >> 4, tx = t & 15;
  const int c0 = tx * 8;
  float accT[4][8], accB[4][8];
#pragma unroll
  for (int u = 0; u < 4; ++u)
#pragma unroll
    for (int i = 0; i < 8; ++i) { accT[u][i] = 0.f; accB[u][i] = 0.f; }
  for (int d0 = 0; d0 < 64; d0 += 4) {
    float4 a[4];
#pragma unroll
    for (int u = 0; u < 4; ++u) a[u] = *(const float4*)&X[ty * 4 + u][d0];
#pragma unroll
    for (int dd = 0; dd < 4; ++dd) {
      const float4 t0 = *(const float4*)&w1[(size_t)(d0 + dd) * 128 + c0];
      const float4 t1 = *(const float4*)&w1[(size_t)(d0 + dd) * 128 + c0 + 4];
      const float4 bb0 = *(const float4*)&w1[(size_t)(64 + d0 + dd) * 128 + c0];
      const float4 bb1 = *(const float4*)&w1[(size_t)(64 + d0 + dd) * 128 + c0 + 4];
#pragma unroll
      for (int u = 0; u < 4; ++u) {
        const float av = (dd == 0) ? a[u].x : (dd == 1) ? a[u].y : (dd == 2) ? a[u].z : a[u].w;
        accT[u][0] = fmaf(av, t0.x, accT[u][0]);
        accT[u][1] = fmaf(av, t0.y, accT[u][1]);
        accT[u][2] = fmaf(av, t0.z, accT[u][2]);
        accT[u][3] = fmaf(av, t0.w, accT[u][3]);
        accT[u][4] = fmaf(av, t1.x, accT[u][4]);
        accT[u][5] = fmaf(av, t1.y, accT[u][5]);
        accT[u][6] = fmaf(av, t1.z, accT[u][6]);
        accT[u][7] = fmaf(av, t1.w, accT[u][7]);
        accB[u][0] = fmaf(av, bb0.x, accB[u][0]);
        accB[u][1] = fmaf(av, bb0.y, accB[u][1]);
        accB[u][2] = fmaf(av, bb0.z, accB[u][2]);
        accB[u][3] = fmaf(av, bb0.w, accB[u][3]);
        accB[u][4] = fmaf(av, bb1.x, accB[u][4]);
        accB[u][5] = fmaf(av, bb1.y, accB[u][5]);
        accB[u][6] = fmaf(av, bb1.z, accB[u][6]);
        accB[u][7] = fmaf(av, bb1.w, accB[u][7]);
      }
    }
  }
  const float4 bA = *(const float4*)&b1[c0];
  const float4 bB = *(const float4*)&b1[c0 + 4];
#pragma unroll
  for (int u = 0; u < 4; ++u) {
    const size_t row = (size_t)(nbase + ty * 4 + u) * 128 + c0;
    float4 u0, u1, v0, v1;
    v0 = make_float4(accB[u][0], accB[u][1], accB[u][2], accB[u][3]);
    v1 = make_float4(accB[u][4], accB[u][5], accB[u][6], accB[u][7]);
    u0.x = accT[u][0] - accB[u][0] + bA.x;
    u0.y = accT[u][1] - accB[u][1] + bA.y;
    u0.z = accT[u][2] - accB[u][2] + bA.z;
    u0.w = accT[u][3] - accB[u][3] + bA.w;
    u1.x = accT[u][4] - accB[u][4] + bB.x;
    u1.y = accT[u][5] - accB[u][5] + bB.y;
    u1.z = accT[u][6] - accB[u][6] + bB.z;
    u1.w = accT[u][7] - accB[u][7] + bB.w;
    *(float4*)&U[row] = u0;
    *(float4*)&U[row + 4] = u1;
    *(float4*)&V[row] = v0;
    *(float4*)&V[row + 4] = v1;
  }
}

// ---------------------------------------------------------------------------
// conv1 EdgeConv layers 2,3 (64->64->64, max over 20 edges), 8 points/block.
// ---------------------------------------------------------------------------
__global__ __launch_bounds__(256) void conv1_kernel(
    const float* __restrict__ U1, const float* __restrict__ V1,
    const int* __restrict__ idx,
    const float* __restrict__ w2, const float* __restrict__ b2,
    const float* __restrict__ w3, const float* __restrict__ b3,
    float* __restrict__ xout) {
  __shared__ float H[160][68];
  __shared__ float pm[8][4][64];
  const int bid = blockIdx.x;
  const int b = bid >> 8;               // 256 blocks per cloud
  const int pbase = (bid & 255) * 8;
  const int t = threadIdx.x;
  const int ty = t >> 3, tx = t & 7;
  const int r0 = ty * 5, c0 = tx * 8;

  for (int it = t; it < 2560; it += 256) {
    const int r = it >> 4, q = it & 15;
    const int p = r / 20, k = r - (r / 20) * 20;
    const int n = b * NN + pbase + p;
    const int j = b * NN + idx[(size_t)n * KK + k];
    const float4 uv = *(const float4*)&U1[(size_t)n * 64 + q * 4];
    const float4 vv = *(const float4*)&V1[(size_t)j * 64 + q * 4];
    float4 h;
    h.x = fmaxf(uv.x + vv.x, 0.f);
    h.y = fmaxf(uv.y + vv.y, 0.f);
    h.z = fmaxf(uv.z + vv.z, 0.f);
    h.w = fmaxf(uv.w + vv.w, 0.f);
    *(float4*)&H[r][q * 4] = h;
  }
  __syncthreads();

  float acc[5][8];
  // ---- layer 2: 64 -> 64 (in-place H)
#pragma unroll
  for (int u = 0; u < 5; ++u)
#pragma unroll
    for (int i = 0; i < 8; ++i) acc[u][i] = 0.f;
  for (int d0 = 0; d0 < 64; d0 += 4) {
    float4 a[5];
#pragma unroll
    for (int u = 0; u < 5; ++u) a[u] = *(const float4*)&H[r0 + u][d0];
#pragma unroll
    for (int dd = 0; dd < 4; ++dd) {
      const float4 wA = *(const float4*)&w2[(size_t)(d0 + dd) * 64 + c0];
      const float4 wB = *(const float4*)&w2[(size_t)(d0 + dd) * 64 + c0 + 4];
#pragma unroll
      for (int u = 0; u < 5; ++u) {
        const float av = (dd == 0) ? a[u].x : (dd == 1) ? a[u].y : (dd == 2) ? a[u].z : a[u].w;
        acc[u][0] = fmaf(av, wA.x, acc[u][0]);
        acc[u][1] = fmaf(av, wA.y, acc[u][1]);
        acc[u][2] = fmaf(av, wA.z, acc[u][2]);
        acc[u][3] = fmaf(av, wA.w, acc[u][3]);
        acc[u][4] = fmaf(av, wB.x, acc[u][4]);
        acc[u][5] = fmaf(av, wB.y, acc[u][5]);
        acc[u][6] = fmaf(av, wB.z, acc[u][6]);
        acc[u][7] = fmaf(av, wB.w, acc[u][7]);
      }
    }
  }
  __syncthreads();
  {
    const float4 bA = *(const float4*)&b2[c0];
    const float4 bB = *(const float4*)&b2[c0 + 4];
#pragma unroll
    for (int u = 0; u < 5; ++u) {
      float4 oA, oB;
      oA.x = fmaxf(acc[u][0] + bA.x, 0.f); oA.y = fmaxf(acc[u][1] + bA.y, 0.f);
      oA.z = fmaxf(acc[u][2] + bA.z, 0.f); oA.w = fmaxf(acc[u][3] + bA.w, 0.f);
      oB.x = fmaxf(acc[u][4] + bB.x, 0.f); oB.y = fmaxf(acc[u][5] + bB.y, 0.f);
      oB.z = fmaxf(acc[u][6] + bB.z, 0.f); oB.w = fmaxf(acc[u][7] + bB.w, 0.f);
      *(float4*)&H[r0 + u][c0] = oA;
      *(float4*)&H[r0 + u][c0 + 4] = oB;
    }
  }
  __syncthreads();

  // ---- layer 3: 64 -> 64, then max over k
#pragma unroll
  for (int u = 0; u < 5; ++u)
#pragma unroll
    for (int i = 0; i < 8; ++i) acc[u][i] = 0.f;
  for (int d0 = 0; d0 < 64; d0 += 4) {
    float4 a[5];
#pragma unroll
    for (int u = 0; u < 5; ++u) a[u] = *(const float4*)&H[r0 + u][d0];
#pragma unroll
    for (int dd = 0; dd < 4; ++dd) {
      const float4 wA = *(const float4*)&w3[(size_t)(d0 + dd) * 64 + c0];
      const float4 wB = *(const float4*)&w3[(size_t)(d0 + dd) * 64 + c0 + 4];
#pragma unroll
      for (int u = 0; u < 5; ++u) {
        const float av = (dd == 0) ? a[u].x : (dd == 1) ? a[u].y : (dd == 2) ? a[u].z : a[u].w;
        acc[u][0] = fmaf(av, wA.x, acc[u][0]);
        acc[u][1] = fmaf(av, wA.y, acc[u][1]);
        acc[u][2] = fmaf(av, wA.z, acc[u][2]);
        acc[u][3] = fmaf(av, wA.w, acc[u][3]);
        acc[u][4] = fmaf(av, wB.x, acc[u][4]);
        acc[u][5] = fmaf(av, wB.y, acc[u][5]);
        acc[u][6] = fmaf(av, wB.z, acc[u][6]);
        acc[u][7] = fmaf(av, wB.w, acc[u][7]);
      }
    }
  }
  {
    const int p = ty >> 2, sub = ty & 3;
    float4 m0, m1;
    m0.x = fmaxf(fmaxf(fmaxf(acc[0][0], acc[1][0]), fmaxf(acc[2][0], acc[3][0])), acc[4][0]);
    m0.y = fmaxf(fmaxf(fmaxf(acc[0][1], acc[1][1]), fmaxf(acc[2][1], acc[3][1])), acc[4][1]);
    m0.z = fmaxf(fmaxf(fmaxf(acc[0][2], acc[1][2]), fmaxf(acc[2][2], acc[3][2])), acc[4][2]);
    m0.w = fmaxf(fmaxf(fmaxf(acc[0][3], acc[1][3]), fmaxf(acc[2][3], acc[3][3])), acc[4][3]);
    m1.x = fmaxf(fmaxf(fmaxf(acc[0][4], acc[1][4]), fmaxf(acc[2][4], acc[3][4])), acc[4][4]);
    m1.y = fmaxf(fmaxf(fmaxf(acc[0][5], acc[1][5]), fmaxf(acc[2][5], acc[3][5])), acc[4][5]);
    m1.z = fmaxf(fmaxf(fmaxf(acc[0][6], acc[1][6]), fmaxf(acc[2][6], acc[3][6])), acc[4][6]);
    m1.w = fmaxf(fmaxf(fmaxf(acc[0][7], acc[1][7]), fmaxf(acc[2][7], acc[3][7])), acc[4][7]);
    *(float4*)&pm[p][sub][c0] = m0;
    *(float4*)&pm[p][sub][c0 + 4] = m1;
  }
  __syncthreads();
  {
    const int pp = t >> 5;
    const int cc = (t & 31) * 2;
    float m0 = fmaxf(fmaxf(pm[pp][0][cc], pm[pp][1][cc]), fmaxf(pm[pp][2][cc], pm[pp][3][cc]));
    float m1 = fmaxf(fmaxf(pm[pp][0][cc + 1], pm[pp][1][cc + 1]),
                     fmaxf(pm[pp][2][cc + 1], pm[pp][3][cc + 1]));
    float2 o;
    o.x = fmaxf(m0 + b3[cc], 0.f);
    o.y = fmaxf(m1 + b3[cc + 1], 0.f);
    *(float2*)&xout[((size_t)bid) * 8 * 64 + (size_t)pp * 64 + cc] = o;
  }
}

// ---------------------------------------------------------------------------
// xsplit: x1 (fp32) -> xhi/xlo (split bf16) + s = sum(x^2) fp32.
// 8 threads per point row; shfl_xor tree keeps s deterministic.
// ---------------------------------------------------------------------------
__global__ __launch_bounds__(256) void xsplit_kernel(const float* __restrict__ x1,
                                                     unsigned short* __restrict__ xhi,
                                                     unsigned short* __restrict__ xlo,
                                                     float* __restrict__ s) {
  const int e = blockIdx.x * 256 + threadIdx.x;  // 131072 total
  const int n = e >> 3, q = e & 7;
  const float4 v0 = *(const float4*)&x1[(size_t)n * 64 + q * 8];
  const float4 v1 = *(const float4*)&x1[(size_t)n * 64 + q * 8 + 4];
  float ps = v0.x * v0.x + v0.y * v0.y + v0.z * v0.z + v0.w * v0.w +
             v1.x * v1.x + v1.y * v1.y + v1.z * v1.z + v1.w * v1.w;
  ps += __shfl_xor(ps, 1);
  ps += __shfl_xor(ps, 2);
  ps += __shfl_xor(ps, 4);
  if (q == 0) s[n] = ps;
  const float vv[8] = {v0.x, v0.y, v0.z, v0.w, v1.x, v1.y, v1.z, v1.w};
  unsigned short hb[8], lb[8];
#pragma unroll
  for (int i = 0; i < 8; ++i) {
    hb[i] = f2bf(vv[i]);
    lb[i] = f2bf(vv[i] - bf2f(hb[i]));
  }
  *(ushort4*)&xhi[(size_t)n * 64 + q * 8] = make_ushort4(hb[0], hb[1], hb[2], hb[3]);
  *(ushort4*)&xhi[(size_t)n * 64 + q * 8 + 4] = make_ushort4(hb[4], hb[5], hb[6], hb[7]);
  *(ushort4*)&xlo[(size_t)n * 64 + q * 8] = make_ushort4(lb[0], lb[1], lb[2], lb[3]);
  *(ushort4*)&xlo[(size_t)n * 64 + q * 8 + 4] = make_ushort4(lb[4], lb[5], lb[6], lb[7]);
}

// ---------------------------------------------------------------------------
// d2 + fused partial selection, GEMM via split-bf16 MFMA:
//   dot = hi.hi + hi.lo + lo.hi  (fp32 accum; rel err ~2^-16)
// Gram symmetry: A and B fragments both read the row-major [point][k] layout.
// Per block: 128x128 tile; wave owns 32 rows x 128 cols (2 M x 8 N tiles).
// T overlays the stage buffer after a barrier; selection identical to the
// proven fp32 version.
// ---------------------------------------------------------------------------
__global__ __launch_bounds__(256) void d2sel_kernel(const unsigned short* __restrict__ xhi,
                                                    const unsigned short* __restrict__ xlo,
                                                    const float* __restrict__ s,
                                                    float* __restrict__ candd,
                                                    int* __restrict__ candi) {
  // stage: AH/AL/BH/BL [128][72] bf16 (73728 B)  |  T[128][131] f32 (67072 B)
  __shared__ __align__(16) unsigned short SBUF[4 * 128 * 72];
  __shared__ float sA[128], sB[128];
  float (*T)[131] = (float(*)[131])SBUF;
  const int bid = blockIdx.x;
  const int b = bid >> 8;
  const int tile = bid & 255;
  const int ti = tile >> 4, tj = tile & 15;
  const int i0 = ti * 128, j0 = tj * 128;
  const int gb = b * NN;
  const int t = threadIdx.x;
  const int wave = t >> 6, lane = t & 63;
  const int lrow = lane & 15;
  const int lk8 = (lane >> 4) * 8;

  // ---- stage split-bf16 operands (padded rows: 72 bf16 = 144 B -> 2-way max)
  for (int it = t; it < 4096; it += 256) {
    const int part = it >> 10;           // 0:AH 1:AL 2:BH 3:BL
    const int r = (it >> 3) & 127;
    const int g = it & 7;
    const unsigned short* src = (part == 0) ? xhi : (part == 1) ? xlo
                               : (part == 2) ? xhi : xlo;
    const int base = (part < 2) ? i0 : j0;
    *(uint4*)&SBUF[part * 9216 + r * 72 + g * 8] =
        *(const uint4*)&src[((size_t)(gb + base + r)) * 64 + g * 8];
  }
  if (t < 128) sA[t] = s[gb + i0 + t];
  else sB[t - 128] = s[gb + j0 + (t - 128)];
  __syncthreads();

  // ---- GEMM: acc[mt][nt] = x_i . x_j via 3-term split MFMA
  bf16x8 ahi[2][2], alo[2][2];
#pragma unroll
  for (int mt = 0; mt < 2; ++mt) {
    const int r = wave * 32 + mt * 16 + lrow;
#pragma unroll
    for (int ks = 0; ks < 2; ++ks) {
      ahi[mt][ks] = *(const bf16x8*)&SBUF[0 * 9216 + r * 72 + ks * 32 + lk8];
      alo[mt][ks] = *(const bf16x8*)&SBUF[1 * 9216 + r * 72 + ks * 32 + lk8];
    }
  }
  f32x4 acc[2][8];
#pragma unroll
  for (int mt = 0; mt < 2; ++mt)
#pragma unroll
    for (int nt = 0; nt < 8; ++nt) acc[mt][nt] = (f32x4){0.f, 0.f, 0.f, 0.f};
#pragma unroll
  for (int nt = 0; nt < 8; ++nt) {
    bf16x8 bhi[2], blo[2];
#pragma unroll
    for (int ks = 0; ks < 2; ++ks) {
      bhi[ks] = *(const bf16x8*)&SBUF[2 * 9216 + (nt * 16 + lrow) * 72 + ks * 32 + lk8];
      blo[ks] = *(const bf16x8*)&SBUF[3 * 9216 + (nt * 16 + lrow) * 72 + ks * 32 + lk8];
    }
#pragma unroll
    for (int mt = 0; mt < 2; ++mt) {
#pragma unroll
      for (int ks = 0; ks < 2; ++ks) {
        acc[mt][nt] = __builtin_amdgcn_mfma_f32_16x16x32_bf16(ahi[mt][ks], bhi[ks], acc[mt][nt], 0, 0, 0);
        acc[mt][nt] = __builtin_amdgcn_mfma_f32_16x16x32_bf16(ahi[mt][ks], blo[ks], acc[mt][nt], 0, 0, 0);
        acc[mt][nt] = __builtin_amdgcn_mfma_f32_16x16x32_bf16(alo[mt][ks], bhi[ks], acc[mt][nt], 0, 0, 0);
      }
    }
  }
  __syncthreads();   // all stage reads done before T overlays SBUF

  // ---- T[i][j] = sA[i] + sB[j] - 2*dot  (C/D: col=lane&15, row=(lane>>4)*4+reg)
#pragma unroll
  for (int mt = 0; mt < 2; ++mt) {
    const int ib = wave * 32 + mt * 16 + ((lane >> 4) << 2);
#pragma unroll
    for (int nt = 0; nt < 8; ++nt) {
      const int j = nt * 16 + lrow;
      const float sj = sB[j];
#pragma unroll
      for (int reg = 0; reg < 4; ++reg) {
        T[ib + reg][j] = sA[ib + reg] + sj - 2.f * acc[mt][nt][reg];
      }
    }
  }
  __syncthreads();

  // ---- selection: column j = t>>1, half h = t&1 scans 64 rows (unchanged)
  const int j = t >> 1, h = t & 1;
  float bd[KK]; int bi[KK];
#pragma unroll
  for (int q = 0; q < KK; ++q) { bd[q] = INFINITY; bi[q] = 0; }
  float worst = INFINITY;
  int wslot = 0;
  const int mbase = i0 + h * 64;
  for (int r = 0; r < 64; ++r) {
    topk_insert(T[h * 64 + r][j], mbase + r, bd, bi, worst, wslot);
  }
  float od[KK]; int oi[KK];
#pragma unroll
  for (int q = 0; q < KK; ++q) {
    od[q] = __shfl_xor(bd[q], 1);
    oi[q] = __shfl_xor(bi[q], 1);
  }
#pragma unroll
  for (int q = 0; q < KK; ++q) topk_insert(od[q], oi[q], bd, bi, worst, wslot);
  if (h == 0) {
#pragma unroll
    for (int q = 0; q < KK; ++q) {
      const size_t o = ((size_t)(b * 16 + ti) * KK + q) * 2048 + (j0 + j);
      candd[o] = bd[q];
      candi[o] = bi[q];
    }
  }
}

// ---------------------------------------------------------------------------
// wprep: transpose+convert conv2 weights to bf16 [N][K] for MFMA B-fragments.
// ---------------------------------------------------------------------------
__global__ __launch_bounds__(256) void wprep_kernel(const float* __restrict__ w2,
                                                    const float* __restrict__ w3,
                                                    unsigned short* __restrict__ w2t,
                                                    unsigned short* __restrict__ w3t) {
  const int i = blockIdx.x * 256 + threadIdx.x;
  if (i < 16384) {
    const int d = i >> 7, c = i & 127;
    w2t[c * 128 + d] = f2bf(w2[i]);
  } else {
    const int j = i - 16384;           // j < 32768
    const int d = j >> 8, c = j & 255;
    w3t[c * 128 + d] = f2bf(w3[j]);
  }
}

// ---------------------------------------------------------------------------
// conv2 EdgeConv layers 2,3 via bf16 MFMA (16x16x32), 4 points/block.
// ---------------------------------------------------------------------------
__global__ __launch_bounds__(256) void conv2_kernel(
    const float* __restrict__ U, const float* __restrict__ V,
    const int* __restrict__ idx,
    const unsigned short* __restrict__ w2t, const float* __restrict__ b2,
    const unsigned short* __restrict__ w3t, const float* __restrict__ b3,
    float* __restrict__ xout) {
  __shared__ __align__(16) unsigned short E[80][136];
  __shared__ __align__(16) unsigned short E2[80][136];
  __shared__ unsigned int pm[4][256];
  const int bid = blockIdx.x;
  const int b = bid >> 9;               // 512 blocks per cloud
  const int pbase = (bid & 511) * 4;
  const int t = threadIdx.x;
  const int wave = t >> 6, lane = t & 63;
  const int lrow = lane & 15;           // A/B fragment row (M or N index)
  const int lk8 = (lane >> 4) * 8;      // k-offset of the 8-element fragment

  // ---- stage edge features (bf16) + init pm
  for (int it = t; it < 2560; it += 256) {
    const int r = it >> 5, q = it & 31;
    const int p = r / 20, k = r - (r / 20) * 20;
    const int n = b * NN + pbase + p;
    const int j = b * NN + idx[(size_t)n * KK + k];
    const float4 uv = *(const float4*)&U[(size_t)n * 128 + q * 4];
    const float4 vv = *(const float4*)&V[(size_t)j * 128 + q * 4];
    ushort4 h;
    h.x = f2bf(fmaxf(uv.x + vv.x, 0.f));
    h.y = f2bf(fmaxf(uv.y + vv.y, 0.f));
    h.z = f2bf(fmaxf(uv.z + vv.z, 0.f));
    h.w = f2bf(fmaxf(uv.w + vv.w, 0.f));
    *(ushort4*)&E[r][q * 4] = h;
  }
  for (int i = t; i < 1024; i += 256) ((unsigned int*)pm)[i] = 0u;
  __syncthreads();

  // ---- layer 2: [80x128] @ [128x128] -> E2 (bf16, relu+bias)
  {
    bf16x8 wf[2][4];
#pragma unroll
    for (int nt2 = 0; nt2 < 2; ++nt2) {
      const int ntg = wave * 2 + nt2;
#pragma unroll
      for (int ks = 0; ks < 4; ++ks)
        wf[nt2][ks] = *(const bf16x8*)&w2t[(size_t)(ntg * 16 + lrow) * 128 + ks * 32 + lk8];
    }
    const float bias0 = b2[wave * 32 + lrow];
    const float bias1 = b2[wave * 32 + 16 + lrow];
#pragma unroll
    for (int mt = 0; mt < 5; ++mt) {
      bf16x8 af[4];
#pragma unroll
      for (int ks = 0; ks < 4; ++ks)
        af[ks] = *(const bf16x8*)&E[mt * 16 + lrow][ks * 32 + lk8];
      f32x4 acc0 = {0.f, 0.f, 0.f, 0.f};
      f32x4 acc1 = {0.f, 0.f, 0.f, 0.f};
#pragma unroll
      for (int ks = 0; ks < 4; ++ks) {
        acc0 = __builtin_amdgcn_mfma_f32_16x16x32_bf16(af[ks], wf[0][ks], acc0, 0, 0, 0);
        acc1 = __builtin_amdgcn_mfma_f32_16x16x32_bf16(af[ks], wf[1][ks], acc1, 0, 0, 0);
      }
      const int r0 = mt * 16 + ((lane >> 4) << 2);
      const int c0 = wave * 32 + lrow;
#pragma unroll
      for (int reg = 0; reg < 4; ++reg) {
        E2[r0 + reg][c0]      = f2bf(fmaxf(acc0[reg] + bias0, 0.f));
        E2[r0 + reg][c0 + 16] = f2bf(fmaxf(acc1[reg] + bias1, 0.f));
      }
    }
  }
  __syncthreads();

  // ---- layer 3: [80x128] @ [128x256], relu+bias, max over edges into pm
  {
    bf16x8 wf[4][4];
#pragma unroll
    for (int nt4 = 0; nt4 < 4; ++nt4) {
      const int ntg = wave * 4 + nt4;
#pragma unroll
      for (int ks = 0; ks < 4; ++ks)
        wf[nt4][ks] = *(const bf16x8*)&w3t[(size_t)(ntg * 16 + lrow) * 128 + ks * 32 + lk8];
    }
#pragma unroll
    for (int mt = 0; mt < 5; ++mt) {
      bf16x8 af[4];
#pragma unroll
      for (int ks = 0; ks < 4; ++ks)
        af[ks] = *(const bf16x8*)&E2[mt * 16 + lrow][ks * 32 + lk8];
      f32x4 acc[4];
#pragma unroll
      for (int nt4 = 0; nt4 < 4; ++nt4) acc[nt4] = (f32x4){0.f, 0.f, 0.f, 0.f};
#pragma unroll
      for (int ks = 0; ks < 4; ++ks) {
#pragma unroll
        for (int nt4 = 0; nt4 < 4; ++nt4)
          acc[nt4] = __builtin_amdgcn_mfma_f32_16x16x32_bf16(af[ks], wf[nt4][ks], acc[nt4], 0, 0, 0);
      }
      const int r0 = mt * 16 + ((lane >> 4) << 2);
      const int pa = r0 / 20;
      const int pb = (r0 + 3) / 20;
#pragma unroll
      for (int nt4 = 0; nt4 < 4; ++nt4) {
        const int c = wave * 64 + nt4 * 16 + lrow;
        const float bias = b3[c];
        float v0 = fmaxf(acc[nt4][0] + bias, 0.f);
        float v1 = fmaxf(acc[nt4][1] + bias, 0.f);
        float v2 = fmaxf(acc[nt4][2] + bias, 0.f);
        float v3 = fmaxf(acc[nt4][3] + bias, 0.f);
        if (pa == pb) {
          atomicMax(&pm[pa][c], __float_as_uint(fmaxf(fmaxf(v0, v1), fmaxf(v2, v3))));
        } else {
          atomicMax(&pm[(r0 + 0) / 20][c], __float_as_uint(v0));
          atomicMax(&pm[(r0 + 1) / 20][c], __float_as_uint(v1));
          atomicMax(&pm[(r0 + 2) / 20][c], __float_as_uint(v2));
          atomicMax(&pm[(r0 + 3) / 20][c], __float_as_uint(v3));
        }
      }
    }
  }
  __syncthreads();

  // ---- write out: pm bit patterns are the (>=0) float results
  {
    const int p = t >> 6;
    const int c0 = (t & 63) * 4;
    const float4 o = *(const float4*)&pm[p][c0];
    *(float4*)&xout[((size_t)b * NN + pbase + p) * 256 + c0] = o;
  }
}

// ---------------------------------------------------------------------------
// l0 GEMM (16384x512 @ K=256) + relu + per-64-row max partials (unchanged).
// ---------------------------------------------------------------------------
__global__ __launch_bounds__(256) void l0_kernel(const float* __restrict__ x2,
                                                 const float* __restrict__ w,
                                                 const float* __restrict__ bias,
                                                 float* __restrict__ gp) {
  __shared__ float A[64][68];
  __shared__ float red[16][128];
  const int bid = blockIdx.x;
  const int b = bid >> 7;
  const int mblk = (bid >> 2) & 31;
  const int cblk = bid & 3;
  const int t = threadIdx.x;
  const int ty = t >> 4, tx = t & 15;
  const float* xb = x2 + ((size_t)b * NN + mblk * 64) * 256;
  float acc[4][8];
#pragma unroll
  for (int u = 0; u < 4; ++u)
#pragma unroll
    for (int i = 0; i < 8; ++i) acc[u][i] = 0.f;
  for (int kc = 0; kc < 4; ++kc) {
    {
      const int r = t >> 2, seg = (t & 3) * 16;
#pragma unroll
      for (int s4 = 0; s4 < 4; ++s4) {
        *(float4*)&A[r][seg + s4 * 4] =
            *(const float4*)&xb[(size_t)r * 256 + kc * 64 + seg + s4 * 4];
      }
    }
    __syncthreads();
    for (int d0 = 0; d0 < 64; d0 += 4) {
      float4 a[4];
#pragma unroll
      for (int u = 0; u < 4; ++u) a[u] = *(const float4*)&A[ty * 4 + u][d0];
#pragma unroll
      for (int dd = 0; dd < 4; ++dd) {
        const size_t wrow = (size_t)(kc * 64 + d0 + dd) * 512 + cblk * 128 + tx * 8;
        const float4 wA = *(const float4*)&w[wrow];
        const float4 wB = *(const float4*)&w[wrow + 4];
#pragma unroll
        for (int u = 0; u < 4; ++u) {
          const float av = (dd == 0) ? a[u].x : (dd == 1) ? a[u].y : (dd == 2) ? a[u].z : a[u].w;
          acc[u][0] = fmaf(av, wA.x, acc[u][0]);
          acc[u][1] = fmaf(av, wA.y, acc[u][1]);
          acc[u][2] = fmaf(av, wA.z, acc[u][2]);
          acc[u][3] = fmaf(av, wA.w, acc[u][3]);
          acc[u][4] = fmaf(av, wB.x, acc[u][4]);
          acc[u][5] = fmaf(av, wB.y, acc[u][5]);
          acc[u][6] = fmaf(av, wB.z, acc[u][6]);
          acc[u][7] = fmaf(av, wB.w, acc[u][7]);
        }
      }
    }
    __syncthreads();
  }
  {
    float4 m0, m1;
    m0.x = fmaxf(fmaxf(acc[0][0], acc[1][0]), fmaxf(acc[2][0], acc[3][0]));
    m0.y = fmaxf(fmaxf(acc[0][1], acc[1][1]), fmaxf(acc[2][1], acc[3][1]));
    m0.z = fmaxf(fmaxf(acc[0][2], acc[1][2]), fmaxf(acc[2][2], acc[3][2]));
    m0.w = fmaxf(fmaxf(acc[0][3], acc[1][3]), fmaxf(acc[2][3], acc[3][3]));
    m1.x = fmaxf(fmaxf(acc[0][4], acc[1][4]), fmaxf(acc[2][4], acc[3][4]));
    m1.y = fmaxf(fmaxf(acc[0][5], acc[1][5]), fmaxf(acc[2][5], acc[3][5]));
    m1.z = fmaxf(fmaxf(acc[0][6], acc[1][6]), fmaxf(acc[2][6], acc[3][6]));
    m1.w = fmaxf(fmaxf(acc[0][7], acc[1][7]), fmaxf(acc[2][7], acc[3][7]));
    *(float4*)&red[ty][tx * 8] = m0;
    *(float4*)&red[ty][tx * 8 + 4] = m1;
  }
  __syncthreads();
  if (t < 128) {
    float m = red[0][t];
#pragma unroll
    for (int q = 1; q < 16; ++q) m = fmaxf(m, red[q][t]);
    m = fmaxf(m + bias[cblk * 128 + t], 0.f);
    gp[((size_t)b * 32 + mblk) * 512 + cblk * 128 + t] = m;
  }
}

// ---------------------------------------------------------------------------
// final pool-reduce (32 partials) + classifier head + log_softmax (unchanged).
// ---------------------------------------------------------------------------
__global__ __launch_bounds__(256) void head_kernel(
    const float* __restrict__ gp,
    const float* __restrict__ l1w, const float* __restrict__ l1b,
    const float* __restrict__ l2w, const float* __restrict__ l2b,
    const float* __restrict__ l3w, const float* __restrict__ l3b,
    float* __restrict__ out) {
  __shared__ float g[512];
  __shared__ float h1[256];
  __shared__ float h2[256];
  __shared__ float logits[40];
  __shared__ float lse_s;
  const int b = blockIdx.x;
  const int t = threadIdx.x;
  for (int cidx = t; cidx < 512; cidx += 256) {
    float m = gp[(size_t)(b * 32) * 512 + cidx];
    for (int ch = 1; ch < 32; ++ch) m = fmaxf(m, gp[(size_t)(b * 32 + ch) * 512 + cidx]);
    g[cidx] = m;
  }
  __syncthreads();
  {
    float acc = 0.f;
    for (int d = 0; d < 512; d += 4) {
      const float4 gv = *(const float4*)&g[d];
      acc = fmaf(gv.x, l1w[(size_t)d * 256 + t], acc);
      acc = fmaf(gv.y, l1w[(size_t)(d + 1) * 256 + t], acc);
      acc = fmaf(gv.z, l1w[(size_t)(d + 2) * 256 + t], acc);
      acc = fmaf(gv.w, l1w[(size_t)(d + 3) * 256 + t], acc);
    }
    h1[t] = fmaxf(acc + l1b[t], 0.f);
  }
  __syncthreads();
  {
    float acc = 0.f;
    for (int d = 0; d < 256; d += 4) {
      const float4 hv = *(const float4*)&h1[d];
      acc = fmaf(hv.x, l2w[(size_t)d * 256 + t], acc);
      acc = fmaf(hv.y, l2w[(size_t)(d + 1) * 256 + t], acc);
      acc = fmaf(hv.z, l2w[(size_t)(d + 2) * 256 + t], acc);
      acc = fmaf(hv.w, l2w[(size_t)(d + 3) * 256 + t], acc);
    }
    h2[t] = fmaxf(acc + l2b[t], 0.f);
  }
  __syncthreads();
  if (t < 40) {
    float acc = 0.f;
    for (int d = 0; d < 256; ++d) acc = fmaf(h2[d], l3w[(size_t)d * 40 + t], acc);
    logits[t] = acc + l3b[t];
  }
  __syncthreads();
  if (t == 0) {
    float M = -INFINITY;
    for (int j = 0; j < 40; ++j) M = fmaxf(M, logits[j]);
    float ssum = 0.f;
    for (int j = 0; j < 40; ++j) ssum += expf(logits[j] - M);
    lse_s = M + logf(ssum);
  }
  __syncthreads();
  if (t < 40) out[(size_t)b * 40 + t] = logits[t] - lse_s;
}

// ---------------------------------------------------------------------------
extern "C" void kernel_launch(void* const* d_in, const int* in_sizes, int n_in,
                              void* d_out, int out_size, void* d_ws, size_t ws_size,
                              hipStream_t stream) {
  const float* pos  = (const float*)d_in[0];
  const float* c1w1 = (const float*)d_in[2];
  const float* c1b1 = (const float*)d_in[3];
  const float* c1w2 = (const float*)d_in[4];
  const float* c1b2 = (const float*)d_in[5];
  const float* c1w3 = (const float*)d_in[6];
  const float* c1b3 = (const float*)d_in[7];
  const float* c2w1 = (const float*)d_in[8];
  const float* c2b1 = (const float*)d_in[9];
  const float* c2w2 = (const float*)d_in[10];
  const float* c2b2 = (const float*)d_in[11];
  const float* c2w3 = (const float*)d_in[12];
  const float* c2b3 = (const float*)d_in[13];
  const float* l0w  = (const float*)d_in[14];
  const float* l0b  = (const float*)d_in[15];
  const float* l1w  = (const float*)d_in[16];
  const float* l1b  = (const float*)d_in[17];
  const float* l2w  = (const float*)d_in[18];
  const float* l2b  = (const float*)d_in[19];
  const float* l3w  = (const float*)d_in[20];
  const float* l3b  = (const float*)d_in[21];
  float* out = (float*)d_out;

  char* ws = (char*)d_ws;
  float* x1    = (float*)(ws + 0);                      // 4 MB    [8,2048,64]
  float* x2    = (float*)(ws + ((size_t)4 << 20));      // 16 MB   [8,2048,256]
  int*   idx1  = (int*)  (ws + ((size_t)20 << 20));     // 1.31 MB [16384,20]
  int*   idx2  = (int*)  (ws + ((size_t)22 << 20));     // 1.31 MB
  float* gp    = (float*)(ws + ((size_t)24 << 20));     // 512 KB  [8,32,512]
  unsigned short* w2t = (unsigned short*)(ws + ((size_t)24 << 20) + (512 << 10)); // 32 KB
  unsigned short* w3t = (unsigned short*)(ws + ((size_t)24 << 20) + (544 << 10)); // 64 KB
  float* candd = (float*)(ws + ((size_t)25 << 20));     // 21 MB   [8,16,20,2048]
  int*   candi = (int*)  (ws + ((size_t)46 << 20));     // 21 MB
  // Overlays (regions dead at time of use -- see launch order):
  float* U1 = (float*)(ws + ((size_t)25 << 20));        // 4 MB over candd (dead after merge1)
  float* V1 = (float*)(ws + ((size_t)29 << 20));        // 4 MB
  float* U  = (float*)(ws + ((size_t)46 << 20));        // 8 MB over candi (dead after merge2)
  float* Vv = (float*)(ws + ((size_t)54 << 20));        // 8 MB (ends at 62 MB)
  unsigned short* xhi = (unsigned short*)(ws + ((size_t)62 << 20));  // 2 MB
  unsigned short* xlo = (unsigned short*)(ws + ((size_t)64 << 20));  // 2 MB
  float* sbuf = (float*)(ws + ((size_t)66 << 20));                    // 64 KB

  knn1_part<<<512, 256, 0, stream>>>(pos, candd, candi);
  merge_topk2<8, 4><<<256, 256, 0, stream>>>(candd, candi, idx1);
  pre1_kernel<<<4096, 256, 0, stream>>>(pos, c1w1, c1b1, U1, V1);      // overwrites candd region
  conv1_kernel<<<2048, 256, 0, stream>>>(U1, V1, idx1, c1w2, c1b2, c1w3, c1b3, x1);
  xsplit_kernel<<<512, 256, 0, stream>>>(x1, xhi, xlo, sbuf);
  d2sel_kernel<<<2048, 256, 0, stream>>>(xhi, xlo, sbuf, candd, candi); // U1/V1 dead now
  merge_topk2<16, 8><<<512, 256, 0, stream>>>(candd, candi, idx2);
  pre2_kernel<<<256, 256, 0, stream>>>(x1, c2w1, c2b1, U, Vv);         // overwrites candi region
  wprep_kernel<<<192, 256, 0, stream>>>(c2w2, c2w3, w2t, w3t);
  conv2_kernel<<<4096, 256, 0, stream>>>(U, Vv, idx2, w2t, c2b2, w3t, c2b3, x2);
  l0_kernel<<<1024, 256, 0, stream>>>(x2, l0w, l0b, gp);
  head_kernel<<<8, 256, 0, stream>>>(gp, l1w, l1b, l2w, l2b, l3w, l3b, out);
}

// Round 7
// 652.203 us; speedup vs baseline: 3.8406x; 1.0531x over previous
//
#include <hip/hip_runtime.h>
#include <hip/hip_bf16.h>
#include <math.h>

#define BB 8
#define NN 2048
#define KK 20

typedef short bf16x8 __attribute__((ext_vector_type(8)));
typedef float f32x4 __attribute__((ext_vector_type(4)));

// fp32 -> bf16 (round-to-nearest-even), finite inputs only
__device__ __forceinline__ unsigned short f2bf(float f) {
  unsigned u = __float_as_uint(f);
  u += 0x7FFFu + ((u >> 16) & 1u);
  return (unsigned short)(u >> 16);
}
__device__ __forceinline__ float bf2f(unsigned short h) {
  return __uint_as_float(((unsigned)h) << 16);
}

// ---------------------------------------------------------------------------
// top-K (K=20) smallest-value tracker, fully register-resident.
// Strict < keeps the earliest-seen on ties.
// ---------------------------------------------------------------------------
__device__ __forceinline__ void topk_insert(float d, int m, float (&bd)[KK], int (&bi)[KK],
                                            float& worst, int& wslot) {
  if (d < worst) {
#pragma unroll
    for (int j = 0; j < KK; ++j) {
      if (j == wslot) { bd[j] = d; bi[j] = m; }
    }
    float w = -INFINITY;
    int s = 0;
#pragma unroll
    for (int j = 0; j < KK; ++j) {
      if (bd[j] > w) { w = bd[j]; s = j; }
    }
    worst = w;
    wslot = s;
  }
}

// ---------------------------------------------------------------------------
// kNN pass 1 for conv1 (D=3), m-chunked; min4-gated inserts (exact: skipped
// rows are all >= worst; attempted inserts stay in increasing-m order).
// ---------------------------------------------------------------------------
__global__ __launch_bounds__(256) void knn1_part(const float* __restrict__ pos,
                                                 float* __restrict__ candd,
                                                 int* __restrict__ candi) {
  __shared__ float xs0[256], xs1[256], xs2[256], ss[256];
  const int bid = blockIdx.x;
  const int b = bid >> 6;
  const int nc = (bid >> 3) & 7;
  const int mc = bid & 7;
  const int t = threadIdx.x;
  const float* posb = pos + (size_t)b * NN * 3;
  {
    const int m = mc * 256 + t;
    const float a0 = posb[m * 3 + 0];
    const float a1 = posb[m * 3 + 1];
    const float a2 = posb[m * 3 + 2];
    xs0[t] = a0; xs1[t] = a1; xs2[t] = a2;
    ss[t] = a0 * a0 + a1 * a1 + a2 * a2;
  }
  __syncthreads();
  const int n = nc * 256 + t;
  const float xn0 = posb[n * 3 + 0];
  const float xn1 = posb[n * 3 + 1];
  const float xn2 = posb[n * 3 + 2];
  const float sn = xn0 * xn0 + xn1 * xn1 + xn2 * xn2;  // same expr as ss -> self-dist exact 0
  float bd[KK]; int bi[KK];
#pragma unroll
  for (int j = 0; j < KK; ++j) { bd[j] = INFINITY; bi[j] = 0; }
  float worst = INFINITY;
  int wslot = 0;
  for (int lm = 0; lm < 256; lm += 8) {
    float dv[8];
#pragma unroll
    for (int u = 0; u < 8; ++u) {
      const int q = lm + u;
      dv[u] = sn + ss[q] - 2.f * (xn0 * xs0[q] + xn1 * xs1[q] + xn2 * xs2[q]);
    }
#pragma unroll
    for (int g = 0; g < 2; ++g) {
      const float a0 = dv[g * 4 + 0], a1 = dv[g * 4 + 1];
      const float a2 = dv[g * 4 + 2], a3 = dv[g * 4 + 3];
      const float m01 = a1 < a0 ? a1 : a0;
      const float m23 = a3 < a2 ? a3 : a2;
      const float mv = m23 < m01 ? m23 : m01;
      if (mv < worst) {
        const int rb = mc * 256 + lm + g * 4;
        topk_insert(a0, rb + 0, bd, bi, worst, wslot);
        topk_insert(a1, rb + 1, bd, bi, worst, wslot);
        topk_insert(a2, rb + 2, bd, bi, worst, wslot);
        topk_insert(a3, rb + 3, bd, bi, worst, wslot);
      }
    }
  }
#pragma unroll
  for (int j = 0; j < KK; ++j) {
    const size_t o = ((size_t)(b * 8 + mc) * KK + j) * 2048 + n;
    candd[o] = bd[j];
    candi[o] = bi[j];
  }
}

// ---------------------------------------------------------------------------
// merge v2: G threads per point; each merges NCH/G chunks (batched loads),
// then a shfl_xor tree combines the G partial lists.
// ---------------------------------------------------------------------------
template <int NCH, int G>
__global__ __launch_bounds__(256) void merge_topk2(const float* __restrict__ candd,
                                                   const int* __restrict__ candi,
                                                   int* __restrict__ idx_out) {
  const int gid = blockIdx.x * 256 + threadIdx.x;
  const int pt = gid / G;
  const int sub = gid % G;
  const int b = pt >> 11, n = pt & 2047;
  constexpr int CPT = NCH / G;
  float bd[KK]; int bi[KK];
#pragma unroll
  for (int j = 0; j < KK; ++j) { bd[j] = INFINITY; bi[j] = 0; }
  float worst = INFINITY;
  int wslot = 0;
#pragma unroll
  for (int cc = 0; cc < CPT; ++cc) {
    const int c = sub * CPT + cc;
    const size_t base = ((size_t)(b * NCH + c) * KK) * 2048 + n;
    float dv[KK]; int iv[KK];
#pragma unroll
    for (int j = 0; j < KK; ++j) dv[j] = candd[base + (size_t)j * 2048];
#pragma unroll
    for (int j = 0; j < KK; ++j) iv[j] = candi[base + (size_t)j * 2048];
#pragma unroll
    for (int j = 0; j < KK; ++j) topk_insert(dv[j], iv[j], bd, bi, worst, wslot);
  }
#pragma unroll
  for (int stride = 1; stride < G; stride <<= 1) {
    float od[KK]; int oi[KK];
#pragma unroll
    for (int q = 0; q < KK; ++q) {
      od[q] = __shfl_xor(bd[q], stride);
      oi[q] = __shfl_xor(bi[q], stride);
    }
#pragma unroll
    for (int q = 0; q < KK; ++q) topk_insert(od[q], oi[q], bd, bi, worst, wslot);
  }
  if (sub == 0) {
    int* op = idx_out + (size_t)pt * KK;
#pragma unroll
    for (int j = 0; j < KK; ++j) op[j] = bi[j];
  }
}

// ---------------------------------------------------------------------------
// pre1: per-point factorized conv1 layer-1.
// ---------------------------------------------------------------------------
__global__ __launch_bounds__(256) void pre1_kernel(const float* __restrict__ pos,
                                                   const float* __restrict__ w1,
                                                   const float* __restrict__ b1,
                                                   float* __restrict__ U1,
                                                   float* __restrict__ V1) {
  const int t = threadIdx.x;
  const int c = t & 63;
  const int n = blockIdx.x * 4 + (t >> 6);
  const float p0 = pos[(size_t)n * 3 + 0];
  const float p1 = pos[(size_t)n * 3 + 1];
  const float p2 = pos[(size_t)n * 3 + 2];
  const float wt0 = w1[0 * 64 + c], wt1 = w1[1 * 64 + c], wt2 = w1[2 * 64 + c];
  const float wb0 = w1[3 * 64 + c], wb1 = w1[4 * 64 + c], wb2 = w1[5 * 64 + c];
  float v = p0 * wb0 + p1 * wb1 + p2 * wb2;
  float u = p0 * (wt0 - wb0) + p1 * (wt1 - wb1) + p2 * (wt2 - wb2) + b1[c];
  U1[(size_t)n * 64 + c] = u;
  V1[(size_t)n * 64 + c] = v;
}

// ---------------------------------------------------------------------------
// pre2: per-point factorized conv2 layer-1 (GEMM 16384x128 @ K=64, x2 halves).
// ---------------------------------------------------------------------------
__global__ __launch_bounds__(256) void pre2_kernel(const float* __restrict__ x1,
                                                   const float* __restrict__ w1,
                                                   const float* __restrict__ b1,
                                                   float* __restrict__ U,
                                                   float* __restrict__ V) {
  __shared__ float X[64][68];
  const int nbase = blockIdx.x * 64;
  const int t = threadIdx.x;
  for (int it = t; it < 1024; it += 256) {
    const int r = it >> 4, q = it & 15;
    *(float4*)&X[r][q * 4] = *(const float4*)&x1[(size_t)(nbase + r) * 64 + q * 4];
  }
  __syncthreads();
  const int ty = t >> 4, tx = t & 15;
  const int c0 = tx * 8;
  float accT[4][8], accB[4][8];
#pragma unroll
  for (int u = 0; u < 4; ++u)
#pragma unroll
    for (int i = 0; i < 8; ++i) { accT[u][i] = 0.f; accB[u][i] = 0.f; }
  for (int d0 = 0; d0 < 64; d0 += 4) {
    float4 a[4];
#pragma unroll
    for (int u = 0; u < 4; ++u) a[u] = *(const float4*)&X[ty * 4 + u][d0];
#pragma unroll
    for (int dd = 0; dd < 4; ++dd) {
      const float4 t0 = *(const float4*)&w1[(size_t)(d0 + dd) * 128 + c0];
      const float4 t1 = *(const float4*)&w1[(size_t)(d0 + dd) * 128 + c0 + 4];
      const float4 bb0 = *(const float4*)&w1[(size_t)(64 + d0 + dd) * 128 + c0];
      const float4 bb1 = *(const float4*)&w1[(size_t)(64 + d0 + dd) * 128 + c0 + 4];
#pragma unroll
      for (int u = 0; u < 4; ++u) {
        const float av = (dd == 0) ? a[u].x : (dd == 1) ? a[u].y : (dd == 2) ? a[u].z : a[u].w;
        accT[u][0] = fmaf(av, t0.x, accT[u][0]);
        accT[u][1] = fmaf(av, t0.y, accT[u][1]);
        accT[u][2] = fmaf(av, t0.z, accT[u][2]);
        accT[u][3] = fmaf(av, t0.w, accT[u][3]);
        accT[u][4] = fmaf(av, t1.x, accT[u][4]);
        accT[u][5] = fmaf(av, t1.y, accT[u][5]);
        accT[u][6] = fmaf(av, t1.z, accT[u][6]);
        accT[u][7] = fmaf(av, t1.w, accT[u][7]);
        accB[u][0] = fmaf(av, bb0.x, accB[u][0]);
        accB[u][1] = fmaf(av, bb0.y, accB[u][1]);
        accB[u][2] = fmaf(av, bb0.z, accB[u][2]);
        accB[u][3] = fmaf(av, bb0.w, accB[u][3]);
        accB[u][4] = fmaf(av, bb1.x, accB[u][4]);
        accB[u][5] = fmaf(av, bb1.y, accB[u][5]);
        accB[u][6] = fmaf(av, bb1.z, accB[u][6]);
        accB[u][7] = fmaf(av, bb1.w, accB[u][7]);
      }
    }
  }
  const float4 bA = *(const float4*)&b1[c0];
  const float4 bB = *(const float4*)&b1[c0 + 4];
#pragma unroll
  for (int u = 0; u < 4; ++u) {
    const size_t row = (size_t)(nbase + ty * 4 + u) * 128 + c0;
    float4 u0, u1, v0, v1;
    v0 = make_float4(accB[u][0], accB[u][1], accB[u][2], accB[u][3]);
    v1 = make_float4(accB[u][4], accB[u][5], accB[u][6], accB[u][7]);
    u0.x = accT[u][0] - accB[u][0] + bA.x;
    u0.y = accT[u][1] - accB[u][1] + bA.y;
    u0.z = accT[u][2] - accB[u][2] + bA.z;
    u0.w = accT[u][3] - accB[u][3] + bA.w;
    u1.x = accT[u][4] - accB[u][4] + bB.x;
    u1.y = accT[u][5] - accB[u][5] + bB.y;
    u1.z = accT[u][6] - accB[u][6] + bB.z;
    u1.w = accT[u][7] - accB[u][7] + bB.w;
    *(float4*)&U[row] = u0;
    *(float4*)&U[row + 4] = u1;
    *(float4*)&V[row] = v0;
    *(float4*)&V[row + 4] = v1;
  }
}

// ---------------------------------------------------------------------------
// wprep: transpose+convert weights for MFMA B-fragments.
//   conv2: w2t[c][d], w3t[c][d] plain bf16 (proven R4 path).
//   conv1: w2/w3 -> SPLIT bf16 transposed (hi/lo), 64x64 each.
// ---------------------------------------------------------------------------
__global__ __launch_bounds__(256) void wprep_kernel(
    const float* __restrict__ c2w2, const float* __restrict__ c2w3,
    const float* __restrict__ c1w2, const float* __restrict__ c1w3,
    unsigned short* __restrict__ w2t, unsigned short* __restrict__ w3t,
    unsigned short* __restrict__ c1w2hi, unsigned short* __restrict__ c1w2lo,
    unsigned short* __restrict__ c1w3hi, unsigned short* __restrict__ c1w3lo) {
  const int i = blockIdx.x * 256 + threadIdx.x;
  if (i < 16384) {
    const int d = i >> 7, c = i & 127;
    w2t[c * 128 + d] = f2bf(c2w2[i]);
  } else if (i < 49152) {
    const int j = i - 16384;
    const int d = j >> 8, c = j & 255;
    w3t[c * 128 + d] = f2bf(c2w3[j]);
  } else if (i < 53248) {
    const int j = i - 49152;
    const int d = j >> 6, c = j & 63;
    const float v = c1w2[j];
    const unsigned short h = f2bf(v);
    c1w2hi[c * 64 + d] = h;
    c1w2lo[c * 64 + d] = f2bf(v - bf2f(h));
  } else {
    const int j = i - 53248;
    const int d = j >> 6, c = j & 63;
    const float v = c1w3[j];
    const unsigned short h = f2bf(v);
    c1w3hi[c * 64 + d] = h;
    c1w3lo[c * 64 + d] = f2bf(v - bf2f(h));
  }
}

// ---------------------------------------------------------------------------
// conv1 EdgeConv layers 2,3 via SPLIT-bf16 MFMA (fp32-accurate: hi.hi +
// hi.lo + lo.hi), 8 points/block, 160 edge rows, K=64. In-place A buffer
// (layer2 accs buffered in registers), max via LDS atomicMax (relu >= 0).
// x1 accuracy ~fp32 -> conv2 kNN graph unchanged.
// ---------------------------------------------------------------------------
__global__ __launch_bounds__(256) void conv1_kernel(
    const float* __restrict__ U1, const float* __restrict__ V1,
    const int* __restrict__ idx,
    const unsigned short* __restrict__ w2hi, const unsigned short* __restrict__ w2lo,
    const float* __restrict__ b2,
    const unsigned short* __restrict__ w3hi, const unsigned short* __restrict__ w3lo,
    const float* __restrict__ b3,
    float* __restrict__ xout) {
  __shared__ __align__(16) unsigned short A[160][2][76];  // [row][hi/lo][k + pad]
  __shared__ unsigned int pm[8][64];
  const int bid = blockIdx.x;
  const int b = bid >> 8;               // 256 blocks per cloud
  const int pbase = (bid & 255) * 8;
  const int t = threadIdx.x;
  const int wave = t >> 6, lane = t & 63;
  const int lrow = lane & 15;
  const int lk8 = (lane >> 4) * 8;
  const int c = wave * 16 + lrow;       // this thread's output column (both layers)

  // ---- stage split-bf16 edge features relu(U1[i]+V1[j]) + init pm
  for (int it = t; it < 2560; it += 256) {
    const int r = it >> 4, q = it & 15;
    const int p = r / 20, k = r - (r / 20) * 20;
    const int n = b * NN + pbase + p;
    const int j = b * NN + idx[(size_t)n * KK + k];
    const float4 uv = *(const float4*)&U1[(size_t)n * 64 + q * 4];
    const float4 vv = *(const float4*)&V1[(size_t)j * 64 + q * 4];
    float e[4];
    e[0] = fmaxf(uv.x + vv.x, 0.f);
    e[1] = fmaxf(uv.y + vv.y, 0.f);
    e[2] = fmaxf(uv.z + vv.z, 0.f);
    e[3] = fmaxf(uv.w + vv.w, 0.f);
    ushort4 hi, lo;
    hi.x = f2bf(e[0]); lo.x = f2bf(e[0] - bf2f(hi.x));
    hi.y = f2bf(e[1]); lo.y = f2bf(e[1] - bf2f(hi.y));
    hi.z = f2bf(e[2]); lo.z = f2bf(e[2] - bf2f(hi.z));
    hi.w = f2bf(e[3]); lo.w = f2bf(e[3] - bf2f(hi.w));
    *(ushort4*)&A[r][0][q * 4] = hi;
    *(ushort4*)&A[r][1][q * 4] = lo;
  }
  for (int i = t; i < 512; i += 256) ((unsigned int*)pm)[i] = 0u;
  __syncthreads();

  // ---- layer 2 (64 -> 64), in-place A with register-buffered accs
  {
    bf16x8 whi[2], wlo[2];
#pragma unroll
    for (int ks = 0; ks < 2; ++ks) {
      whi[ks] = *(const bf16x8*)&w2hi[(size_t)c * 64 + ks * 32 + lk8];
      wlo[ks] = *(const bf16x8*)&w2lo[(size_t)c * 64 + ks * 32 + lk8];
    }
    f32x4 acc2[10];
#pragma unroll
    for (int mt = 0; mt < 10; ++mt) {
      bf16x8 ahi[2], alo[2];
#pragma unroll
      for (int ks = 0; ks < 2; ++ks) {
        ahi[ks] = *(const bf16x8*)&A[mt * 16 + lrow][0][ks * 32 + lk8];
        alo[ks] = *(const bf16x8*)&A[mt * 16 + lrow][1][ks * 32 + lk8];
      }
      f32x4 acc = {0.f, 0.f, 0.f, 0.f};
#pragma unroll
      for (int ks = 0; ks < 2; ++ks) {
        acc = __builtin_amdgcn_mfma_f32_16x16x32_bf16(ahi[ks], whi[ks], acc, 0, 0, 0);
        acc = __builtin_amdgcn_mfma_f32_16x16x32_bf16(ahi[ks], wlo[ks], acc, 0, 0, 0);
        acc = __builtin_amdgcn_mfma_f32_16x16x32_bf16(alo[ks], whi[ks], acc, 0, 0, 0);
      }
      acc2[mt] = acc;
    }
    __syncthreads();   // all layer-2 A reads done before overwrite
    const float bias = b2[c];
#pragma unroll
    for (int mt = 0; mt < 10; ++mt) {
      const int r0 = mt * 16 + ((lane >> 4) << 2);
#pragma unroll
      for (int reg = 0; reg < 4; ++reg) {
        const float v = fmaxf(acc2[mt][reg] + bias, 0.f);
        const unsigned short h = f2bf(v);
        A[r0 + reg][0][c] = h;
        A[r0 + reg][1][c] = f2bf(v - bf2f(h));
      }
    }
  }
  __syncthreads();

  // ---- layer 3 (64 -> 64), relu+bias, max over edges via atomicMax
  {
    bf16x8 whi[2], wlo[2];
#pragma unroll
    for (int ks = 0; ks < 2; ++ks) {
      whi[ks] = *(const bf16x8*)&w3hi[(size_t)c * 64 + ks * 32 + lk8];
      wlo[ks] = *(const bf16x8*)&w3lo[(size_t)c * 64 + ks * 32 + lk8];
    }
    const float bias = b3[c];
#pragma unroll
    for (int mt = 0; mt < 10; ++mt) {
      bf16x8 ahi[2], alo[2];
#pragma unroll
      for (int ks = 0; ks < 2; ++ks) {
        ahi[ks] = *(const bf16x8*)&A[mt * 16 + lrow][0][ks * 32 + lk8];
        alo[ks] = *(const bf16x8*)&A[mt * 16 + lrow][1][ks * 32 + lk8];
      }
      f32x4 acc = {0.f, 0.f, 0.f, 0.f};
#pragma unroll
      for (int ks = 0; ks < 2; ++ks) {
        acc = __builtin_amdgcn_mfma_f32_16x16x32_bf16(ahi[ks], whi[ks], acc, 0, 0, 0);
        acc = __builtin_amdgcn_mfma_f32_16x16x32_bf16(ahi[ks], wlo[ks], acc, 0, 0, 0);
        acc = __builtin_amdgcn_mfma_f32_16x16x32_bf16(alo[ks], whi[ks], acc, 0, 0, 0);
      }
      const int r0 = mt * 16 + ((lane >> 4) << 2);
      const float v0 = fmaxf(acc[0] + bias, 0.f);
      const float v1 = fmaxf(acc[1] + bias, 0.f);
      const float v2 = fmaxf(acc[2] + bias, 0.f);
      const float v3 = fmaxf(acc[3] + bias, 0.f);
      if (r0 / 20 == (r0 + 3) / 20) {
        atomicMax(&pm[r0 / 20][c], __float_as_uint(fmaxf(fmaxf(v0, v1), fmaxf(v2, v3))));
      } else {
        atomicMax(&pm[(r0 + 0) / 20][c], __float_as_uint(v0));
        atomicMax(&pm[(r0 + 1) / 20][c], __float_as_uint(v1));
        atomicMax(&pm[(r0 + 2) / 20][c], __float_as_uint(v2));
        atomicMax(&pm[(r0 + 3) / 20][c], __float_as_uint(v3));
      }
    }
  }
  __syncthreads();

  // ---- write x1 (fp32 bit patterns; relu outputs >= 0)
  {
    const int p = t >> 5;
    const int cc = (t & 31) * 2;
    float2 o;
    o.x = __uint_as_float(pm[p][cc]);
    o.y = __uint_as_float(pm[p][cc + 1]);
    *(float2*)&xout[((size_t)(b * NN + pbase + p)) * 64 + cc] = o;
  }
}

// ---------------------------------------------------------------------------
// xsplit: x1 (fp32) -> xhi/xlo (split bf16) + s = sum(x^2) fp32.
// ---------------------------------------------------------------------------
__global__ __launch_bounds__(256) void xsplit_kernel(const float* __restrict__ x1,
                                                     unsigned short* __restrict__ xhi,
                                                     unsigned short* __restrict__ xlo,
                                                     float* __restrict__ s) {
  const int e = blockIdx.x * 256 + threadIdx.x;  // 131072 total
  const int n = e >> 3, q = e & 7;
  const float4 v0 = *(const float4*)&x1[(size_t)n * 64 + q * 8];
  const float4 v1 = *(const float4*)&x1[(size_t)n * 64 + q * 8 + 4];
  float ps = v0.x * v0.x + v0.y * v0.y + v0.z * v0.z + v0.w * v0.w +
             v1.x * v1.x + v1.y * v1.y + v1.z * v1.z + v1.w * v1.w;
  ps += __shfl_xor(ps, 1);
  ps += __shfl_xor(ps, 2);
  ps += __shfl_xor(ps, 4);
  if (q == 0) s[n] = ps;
  const float vv[8] = {v0.x, v0.y, v0.z, v0.w, v1.x, v1.y, v1.z, v1.w};
  unsigned short hb[8], lb[8];
#pragma unroll
  for (int i = 0; i < 8; ++i) {
    hb[i] = f2bf(vv[i]);
    lb[i] = f2bf(vv[i] - bf2f(hb[i]));
  }
  *(ushort4*)&xhi[(size_t)n * 64 + q * 8] = make_ushort4(hb[0], hb[1], hb[2], hb[3]);
  *(ushort4*)&xhi[(size_t)n * 64 + q * 8 + 4] = make_ushort4(hb[4], hb[5], hb[6], hb[7]);
  *(ushort4*)&xlo[(size_t)n * 64 + q * 8] = make_ushort4(lb[0], lb[1], lb[2], lb[3]);
  *(ushort4*)&xlo[(size_t)n * 64 + q * 8 + 4] = make_ushort4(lb[4], lb[5], lb[6], lb[7]);
}

// ---------------------------------------------------------------------------
// d2 + fused partial selection, split-bf16 MFMA GEMM. Distance tile now
// stored TRANSPOSED (Tt[col][row]) so selection reads are float4, and the
// per-column scan is min4-gated (exact; see knn1 argument).
// ---------------------------------------------------------------------------
__global__ __launch_bounds__(256) void d2sel_kernel(const unsigned short* __restrict__ xhi,
                                                    const unsigned short* __restrict__ xlo,
                                                    const float* __restrict__ s,
                                                    float* __restrict__ candd,
                                                    int* __restrict__ candi) {
  // stage: AH/AL/BH/BL [128][72] bf16 (73728 B)  |  Tt[128][132] f32 (67584 B)
  __shared__ __align__(16) unsigned short SBUF[4 * 128 * 72];
  __shared__ float sA[128], sB[128];
  float (*Tt)[132] = (float(*)[132])SBUF;
  const int bid = blockIdx.x;
  const int b = bid >> 8;
  const int tile = bid & 255;
  const int ti = tile >> 4, tj = tile & 15;
  const int i0 = ti * 128, j0 = tj * 128;
  const int gb = b * NN;
  const int t = threadIdx.x;
  const int wave = t >> 6, lane = t & 63;
  const int lrow = lane & 15;
  const int lk8 = (lane >> 4) * 8;

  for (int it = t; it < 4096; it += 256) {
    const int part = it >> 10;           // 0:AH 1:AL 2:BH 3:BL
    const int r = (it >> 3) & 127;
    const int g = it & 7;
    const unsigned short* src = (part == 0) ? xhi : (part == 1) ? xlo
                               : (part == 2) ? xhi : xlo;
    const int base = (part < 2) ? i0 : j0;
    *(uint4*)&SBUF[part * 9216 + r * 72 + g * 8] =
        *(const uint4*)&src[((size_t)(gb + base + r)) * 64 + g * 8];
  }
  if (t < 128) sA[t] = s[gb + i0 + t];
  else sB[t - 128] = s[gb + j0 + (t - 128)];
  __syncthreads();

  // ---- GEMM: acc[mt][nt] = x_i . x_j via 3-term split MFMA
  bf16x8 ahi[2][2], alo[2][2];
#pragma unroll
  for (int mt = 0; mt < 2; ++mt) {
    const int r = wave * 32 + mt * 16 + lrow;
#pragma unroll
    for (int ks = 0; ks < 2; ++ks) {
      ahi[mt][ks] = *(const bf16x8*)&SBUF[0 * 9216 + r * 72 + ks * 32 + lk8];
      alo[mt][ks] = *(const bf16x8*)&SBUF[1 * 9216 + r * 72 + ks * 32 + lk8];
    }
  }
  f32x4 acc[2][8];
#pragma unroll
  for (int mt = 0; mt < 2; ++mt)
#pragma unroll
    for (int nt = 0; nt < 8; ++nt) acc[mt][nt] = (f32x4){0.f, 0.f, 0.f, 0.f};
#pragma unroll
  for (int nt = 0; nt < 8; ++nt) {
    bf16x8 bhi[2], blo[2];
#pragma unroll
    for (int ks = 0; ks < 2; ++ks) {
      bhi[ks] = *(const bf16x8*)&SBUF[2 * 9216 + (nt * 16 + lrow) * 72 + ks * 32 + lk8];
      blo[ks] = *(const bf16x8*)&SBUF[3 * 9216 + (nt * 16 + lrow) * 72 + ks * 32 + lk8];
    }
#pragma unroll
    for (int mt = 0; mt < 2; ++mt) {
#pragma unroll
      for (int ks = 0; ks < 2; ++ks) {
        acc[mt][nt] = __builtin_amdgcn_mfma_f32_16x16x32_bf16(ahi[mt][ks], bhi[ks], acc[mt][nt], 0, 0, 0);
        acc[mt][nt] = __builtin_amdgcn_mfma_f32_16x16x32_bf16(ahi[mt][ks], blo[ks], acc[mt][nt], 0, 0, 0);
        acc[mt][nt] = __builtin_amdgcn_mfma_f32_16x16x32_bf16(alo[mt][ks], bhi[ks], acc[mt][nt], 0, 0, 0);
      }
    }
  }
  __syncthreads();   // all stage reads done before Tt overlays SBUF

  // ---- Tt[j][i] = sA[i] + sB[j] - 2*dot (float4 stores along i)
#pragma unroll
  for (int mt = 0; mt < 2; ++mt) {
    const int ib = wave * 32 + mt * 16 + ((lane >> 4) << 2);
#pragma unroll
    for (int nt = 0; nt < 8; ++nt) {
      const int jj = nt * 16 + lrow;
      const float sj = sB[jj];
      float4 o;
      o.x = sA[ib + 0] + sj - 2.f * acc[mt][nt][0];
      o.y = sA[ib + 1] + sj - 2.f * acc[mt][nt][1];
      o.z = sA[ib + 2] + sj - 2.f * acc[mt][nt][2];
      o.w = sA[ib + 3] + sj - 2.f * acc[mt][nt][3];
      *(float4*)&Tt[jj][ib] = o;
    }
  }
  __syncthreads();

  // ---- selection: column j = t>>1, half h = t&1 scans 64 rows, min4-gated
  const int j = t >> 1, h = t & 1;
  float bd[KK]; int bi[KK];
#pragma unroll
  for (int q = 0; q < KK; ++q) { bd[q] = INFINITY; bi[q] = 0; }
  float worst = INFINITY;
  int wslot = 0;
  const int mbase = i0 + h * 64;
  for (int r4 = 0; r4 < 16; ++r4) {
    const float4 v = *(const float4*)&Tt[j][h * 64 + r4 * 4];
    const float m01 = v.y < v.x ? v.y : v.x;
    const float m23 = v.w < v.z ? v.w : v.z;
    const float mv = m23 < m01 ? m23 : m01;
    if (mv < worst) {
      const int rb = mbase + r4 * 4;
      topk_insert(v.x, rb + 0, bd, bi, worst, wslot);
      topk_insert(v.y, rb + 1, bd, bi, worst, wslot);
      topk_insert(v.z, rb + 2, bd, bi, worst, wslot);
      topk_insert(v.w, rb + 3, bd, bi, worst, wslot);
    }
  }
  float od[KK]; int oi[KK];
#pragma unroll
  for (int q = 0; q < KK; ++q) {
    od[q] = __shfl_xor(bd[q], 1);
    oi[q] = __shfl_xor(bi[q], 1);
  }
#pragma unroll
  for (int q = 0; q < KK; ++q) topk_insert(od[q], oi[q], bd, bi, worst, wslot);
  if (h == 0) {
#pragma unroll
    for (int q = 0; q < KK; ++q) {
      const size_t o = ((size_t)(b * 16 + ti) * KK + q) * 2048 + (j0 + j);
      candd[o] = bd[q];
      candi[o] = bi[q];
    }
  }
}

// ---------------------------------------------------------------------------
// conv2 EdgeConv layers 2,3 via bf16 MFMA (16x16x32), 4 points/block.
// ---------------------------------------------------------------------------
__global__ __launch_bounds__(256) void conv2_kernel(
    const float* __restrict__ U, const float* __restrict__ V,
    const int* __restrict__ idx,
    const unsigned short* __restrict__ w2t, const float* __restrict__ b2,
    const unsigned short* __restrict__ w3t, const float* __restrict__ b3,
    float* __restrict__ xout) {
  __shared__ __align__(16) unsigned short E[80][136];
  __shared__ __align__(16) unsigned short E2[80][136];
  __shared__ unsigned int pm[4][256];
  const int bid = blockIdx.x;
  const int b = bid >> 9;               // 512 blocks per cloud
  const int pbase = (bid & 511) * 4;
  const int t = threadIdx.x;
  const int wave = t >> 6, lane = t & 63;
  const int lrow = lane & 15;
  const int lk8 = (lane >> 4) * 8;

  for (int it = t; it < 2560; it += 256) {
    const int r = it >> 5, q = it & 31;
    const int p = r / 20, k = r - (r / 20) * 20;
    const int n = b * NN + pbase + p;
    const int j = b * NN + idx[(size_t)n * KK + k];
    const float4 uv = *(const float4*)&U[(size_t)n * 128 + q * 4];
    const float4 vv = *(const float4*)&V[(size_t)j * 128 + q * 4];
    ushort4 h;
    h.x = f2bf(fmaxf(uv.x + vv.x, 0.f));
    h.y = f2bf(fmaxf(uv.y + vv.y, 0.f));
    h.z = f2bf(fmaxf(uv.z + vv.z, 0.f));
    h.w = f2bf(fmaxf(uv.w + vv.w, 0.f));
    *(ushort4*)&E[r][q * 4] = h;
  }
  for (int i = t; i < 1024; i += 256) ((unsigned int*)pm)[i] = 0u;
  __syncthreads();

  // ---- layer 2: [80x128] @ [128x128] -> E2 (bf16, relu+bias)
  {
    bf16x8 wf[2][4];
#pragma unroll
    for (int nt2 = 0; nt2 < 2; ++nt2) {
      const int ntg = wave * 2 + nt2;
#pragma unroll
      for (int ks = 0; ks < 4; ++ks)
        wf[nt2][ks] = *(const bf16x8*)&w2t[(size_t)(ntg * 16 + lrow) * 128 + ks * 32 + lk8];
    }
    const float bias0 = b2[wave * 32 + lrow];
    const float bias1 = b2[wave * 32 + 16 + lrow];
#pragma unroll
    for (int mt = 0; mt < 5; ++mt) {
      bf16x8 af[4];
#pragma unroll
      for (int ks = 0; ks < 4; ++ks)
        af[ks] = *(const bf16x8*)&E[mt * 16 + lrow][ks * 32 + lk8];
      f32x4 acc0 = {0.f, 0.f, 0.f, 0.f};
      f32x4 acc1 = {0.f, 0.f, 0.f, 0.f};
#pragma unroll
      for (int ks = 0; ks < 4; ++ks) {
        acc0 = __builtin_amdgcn_mfma_f32_16x16x32_bf16(af[ks], wf[0][ks], acc0, 0, 0, 0);
        acc1 = __builtin_amdgcn_mfma_f32_16x16x32_bf16(af[ks], wf[1][ks], acc1, 0, 0, 0);
      }
      const int r0 = mt * 16 + ((lane >> 4) << 2);
      const int c0 = wave * 32 + lrow;
#pragma unroll
      for (int reg = 0; reg < 4; ++reg) {
        E2[r0 + reg][c0]      = f2bf(fmaxf(acc0[reg] + bias0, 0.f));
        E2[r0 + reg][c0 + 16] = f2bf(fmaxf(acc1[reg] + bias1, 0.f));
      }
    }
  }
  __syncthreads();

  // ---- layer 3: [80x128] @ [128x256], relu+bias, max over edges into pm
  {
    bf16x8 wf[4][4];
#pragma unroll
    for (int nt4 = 0; nt4 < 4; ++nt4) {
      const int ntg = wave * 4 + nt4;
#pragma unroll
      for (int ks = 0; ks < 4; ++ks)
        wf[nt4][ks] = *(const bf16x8*)&w3t[(size_t)(ntg * 16 + lrow) * 128 + ks * 32 + lk8];
    }
#pragma unroll
    for (int mt = 0; mt < 5; ++mt) {
      bf16x8 af[4];
#pragma unroll
      for (int ks = 0; ks < 4; ++ks)
        af[ks] = *(const bf16x8*)&E2[mt * 16 + lrow][ks * 32 + lk8];
      f32x4 acc[4];
#pragma unroll
      for (int nt4 = 0; nt4 < 4; ++nt4) acc[nt4] = (f32x4){0.f, 0.f, 0.f, 0.f};
#pragma unroll
      for (int ks = 0; ks < 4; ++ks) {
#pragma unroll
        for (int nt4 = 0; nt4 < 4; ++nt4)
          acc[nt4] = __builtin_amdgcn_mfma_f32_16x16x32_bf16(af[ks], wf[nt4][ks], acc[nt4], 0, 0, 0);
      }
      const int r0 = mt * 16 + ((lane >> 4) << 2);
      const int pa = r0 / 20;
      const int pb = (r0 + 3) / 20;
#pragma unroll
      for (int nt4 = 0; nt4 < 4; ++nt4) {
        const int c = wave * 64 + nt4 * 16 + lrow;
        const float bias = b3[c];
        float v0 = fmaxf(acc[nt4][0] + bias, 0.f);
        float v1 = fmaxf(acc[nt4][1] + bias, 0.f);
        float v2 = fmaxf(acc[nt4][2] + bias, 0.f);
        float v3 = fmaxf(acc[nt4][3] + bias, 0.f);
        if (pa == pb) {
          atomicMax(&pm[pa][c], __float_as_uint(fmaxf(fmaxf(v0, v1), fmaxf(v2, v3))));
        } else {
          atomicMax(&pm[(r0 + 0) / 20][c], __float_as_uint(v0));
          atomicMax(&pm[(r0 + 1) / 20][c], __float_as_uint(v1));
          atomicMax(&pm[(r0 + 2) / 20][c], __float_as_uint(v2));
          atomicMax(&pm[(r0 + 3) / 20][c], __float_as_uint(v3));
        }
      }
    }
  }
  __syncthreads();

  {
    const int p = t >> 6;
    const int c0 = (t & 63) * 4;
    const float4 o = *(const float4*)&pm[p][c0];
    *(float4*)&xout[((size_t)b * NN + pbase + p) * 256 + c0] = o;
  }
}

// ---------------------------------------------------------------------------
// l0 GEMM (16384x512 @ K=256) + relu + per-64-row max partials (unchanged).
// ---------------------------------------------------------------------------
__global__ __launch_bounds__(256) void l0_kernel(const float* __restrict__ x2,
                                                 const float* __restrict__ w,
                                                 const float* __restrict__ bias,
                                                 float* __restrict__ gp) {
  __shared__ float A[64][68];
  __shared__ float red[16][128];
  const int bid = blockIdx.x;
  const int b = bid >> 7;
  const int mblk = (bid >> 2) & 31;
  const int cblk = bid & 3;
  const int t = threadIdx.x;
  const int ty = t >> 4, tx = t & 15;
  const float* xb = x2 + ((size_t)b * NN + mblk * 64) * 256;
  float acc[4][8];
#pragma unroll
  for (int u = 0; u < 4; ++u)
#pragma unroll
    for (int i = 0; i < 8; ++i) acc[u][i] = 0.f;
  for (int kc = 0; kc < 4; ++kc) {
    {
      const int r = t >> 2, seg = (t & 3) * 16;
#pragma unroll
      for (int s4 = 0; s4 < 4; ++s4) {
        *(float4*)&A[r][seg + s4 * 4] =
            *(const float4*)&xb[(size_t)r * 256 + kc * 64 + seg + s4 * 4];
      }
    }
    __syncthreads();
    for (int d0 = 0; d0 < 64; d0 += 4) {
      float4 a[4];
#pragma unroll
      for (int u = 0; u < 4; ++u) a[u] = *(const float4*)&A[ty * 4 + u][d0];
#pragma unroll
      for (int dd = 0; dd < 4; ++dd) {
        const size_t wrow = (size_t)(kc * 64 + d0 + dd) * 512 + cblk * 128 + tx * 8;
        const float4 wA = *(const float4*)&w[wrow];
        const float4 wB = *(const float4*)&w[wrow + 4];
#pragma unroll
        for (int u = 0; u < 4; ++u) {
          const float av = (dd == 0) ? a[u].x : (dd == 1) ? a[u].y : (dd == 2) ? a[u].z : a[u].w;
          acc[u][0] = fmaf(av, wA.x, acc[u][0]);
          acc[u][1] = fmaf(av, wA.y, acc[u][1]);
          acc[u][2] = fmaf(av, wA.z, acc[u][2]);
          acc[u][3] = fmaf(av, wA.w, acc[u][3]);
          acc[u][4] = fmaf(av, wB.x, acc[u][4]);
          acc[u][5] = fmaf(av, wB.y, acc[u][5]);
          acc[u][6] = fmaf(av, wB.z, acc[u][6]);
          acc[u][7] = fmaf(av, wB.w, acc[u][7]);
        }
      }
    }
    __syncthreads();
  }
  {
    float4 m0, m1;
    m0.x = fmaxf(fmaxf(acc[0][0], acc[1][0]), fmaxf(acc[2][0], acc[3][0]));
    m0.y = fmaxf(fmaxf(acc[0][1], acc[1][1]), fmaxf(acc[2][1], acc[3][1]));
    m0.z = fmaxf(fmaxf(acc[0][2], acc[1][2]), fmaxf(acc[2][2], acc[3][2]));
    m0.w = fmaxf(fmaxf(acc[0][3], acc[1][3]), fmaxf(acc[2][3], acc[3][3]));
    m1.x = fmaxf(fmaxf(acc[0][4], acc[1][4]), fmaxf(acc[2][4], acc[3][4]));
    m1.y = fmaxf(fmaxf(acc[0][5], acc[1][5]), fmaxf(acc[2][5], acc[3][5]));
    m1.z = fmaxf(fmaxf(acc[0][6], acc[1][6]), fmaxf(acc[2][6], acc[3][6]));
    m1.w = fmaxf(fmaxf(acc[0][7], acc[1][7]), fmaxf(acc[2][7], acc[3][7]));
    *(float4*)&red[ty][tx * 8] = m0;
    *(float4*)&red[ty][tx * 8 + 4] = m1;
  }
  __syncthreads();
  if (t < 128) {
    float m = red[0][t];
#pragma unroll
    for (int q = 1; q < 16; ++q) m = fmaxf(m, red[q][t]);
    m = fmaxf(m + bias[cblk * 128 + t], 0.f);
    gp[((size_t)b * 32 + mblk) * 512 + cblk * 128 + t] = m;
  }
}

// ---------------------------------------------------------------------------
// final pool-reduce (32 partials) + classifier head + log_softmax (unchanged).
// ---------------------------------------------------------------------------
__global__ __launch_bounds__(256) void head_kernel(
    const float* __restrict__ gp,
    const float* __restrict__ l1w, const float* __restrict__ l1b,
    const float* __restrict__ l2w, const float* __restrict__ l2b,
    const float* __restrict__ l3w, const float* __restrict__ l3b,
    float* __restrict__ out) {
  __shared__ float g[512];
  __shared__ float h1[256];
  __shared__ float h2[256];
  __shared__ float logits[40];
  __shared__ float lse_s;
  const int b = blockIdx.x;
  const int t = threadIdx.x;
  for (int cidx = t; cidx < 512; cidx += 256) {
    float m = gp[(size_t)(b * 32) * 512 + cidx];
    for (int ch = 1; ch < 32; ++ch) m = fmaxf(m, gp[(size_t)(b * 32 + ch) * 512 + cidx]);
    g[cidx] = m;
  }
  __syncthreads();
  {
    float acc = 0.f;
    for (int d = 0; d < 512; d += 4) {
      const float4 gv = *(const float4*)&g[d];
      acc = fmaf(gv.x, l1w[(size_t)d * 256 + t], acc);
      acc = fmaf(gv.y, l1w[(size_t)(d + 1) * 256 + t], acc);
      acc = fmaf(gv.z, l1w[(size_t)(d + 2) * 256 + t], acc);
      acc = fmaf(gv.w, l1w[(size_t)(d + 3) * 256 + t], acc);
    }
    h1[t] = fmaxf(acc + l1b[t], 0.f);
  }
  __syncthreads();
  {
    float acc = 0.f;
    for (int d = 0; d < 256; d += 4) {
      const float4 hv = *(const float4*)&h1[d];
      acc = fmaf(hv.x, l2w[(size_t)d * 256 + t], acc);
      acc = fmaf(hv.y, l2w[(size_t)(d + 1) * 256 + t], acc);
      acc = fmaf(hv.z, l2w[(size_t)(d + 2) * 256 + t], acc);
      acc = fmaf(hv.w, l2w[(size_t)(d + 3) * 256 + t], acc);
    }
    h2[t] = fmaxf(acc + l2b[t], 0.f);
  }
  __syncthreads();
  if (t < 40) {
    float acc = 0.f;
    for (int d = 0; d < 256; ++d) acc = fmaf(h2[d], l3w[(size_t)d * 40 + t], acc);
    logits[t] = acc + l3b[t];
  }
  __syncthreads();
  if (t == 0) {
    float M = -INFINITY;
    for (int j = 0; j < 40; ++j) M = fmaxf(M, logits[j]);
    float ssum = 0.f;
    for (int j = 0; j < 40; ++j) ssum += expf(logits[j] - M);
    lse_s = M + logf(ssum);
  }
  __syncthreads();
  if (t < 40) out[(size_t)b * 40 + t] = logits[t] - lse_s;
}

// ---------------------------------------------------------------------------
extern "C" void kernel_launch(void* const* d_in, const int* in_sizes, int n_in,
                              void* d_out, int out_size, void* d_ws, size_t ws_size,
                              hipStream_t stream) {
  const float* pos  = (const float*)d_in[0];
  const float* c1w1 = (const float*)d_in[2];
  const float* c1b1 = (const float*)d_in[3];
  const float* c1w2 = (const float*)d_in[4];
  const float* c1b2 = (const float*)d_in[5];
  const float* c1w3 = (const float*)d_in[6];
  const float* c1b3 = (const float*)d_in[7];
  const float* c2w1 = (const float*)d_in[8];
  const float* c2b1 = (const float*)d_in[9];
  const float* c2w2 = (const float*)d_in[10];
  const float* c2b2 = (const float*)d_in[11];
  const float* c2w3 = (const float*)d_in[12];
  const float* c2b3 = (const float*)d_in[13];
  const float* l0w  = (const float*)d_in[14];
  const float* l0b  = (const float*)d_in[15];
  const float* l1w  = (const float*)d_in[16];
  const float* l1b  = (const float*)d_in[17];
  const float* l2w  = (const float*)d_in[18];
  const float* l2b  = (const float*)d_in[19];
  const float* l3w  = (const float*)d_in[20];
  const float* l3b  = (const float*)d_in[21];
  float* out = (float*)d_out;

  char* ws = (char*)d_ws;
  float* x1    = (float*)(ws + 0);                      // 4 MB    [8,2048,64]
  float* x2    = (float*)(ws + ((size_t)4 << 20));      // 16 MB   [8,2048,256]
  int*   idx1  = (int*)  (ws + ((size_t)20 << 20));     // 1.31 MB [16384,20]
  int*   idx2  = (int*)  (ws + ((size_t)22 << 20));     // 1.31 MB
  float* gp    = (float*)(ws + ((size_t)24 << 20));     // 512 KB  [8,32,512]
  unsigned short* w2t    = (unsigned short*)(ws + ((size_t)24 << 20) + (512 << 10)); // 32 KB
  unsigned short* w3t    = (unsigned short*)(ws + ((size_t)24 << 20) + (544 << 10)); // 64 KB
  unsigned short* c1w2hi = (unsigned short*)(ws + ((size_t)24 << 20) + (608 << 10)); // 8 KB
  unsigned short* c1w2lo = (unsigned short*)(ws + ((size_t)24 << 20) + (616 << 10)); // 8 KB
  unsigned short* c1w3hi = (unsigned short*)(ws + ((size_t)24 << 20) + (624 << 10)); // 8 KB
  unsigned short* c1w3lo = (unsigned short*)(ws + ((size_t)24 << 20) + (632 << 10)); // 8 KB
  float* candd = (float*)(ws + ((size_t)25 << 20));     // 21 MB   [8,16,20,2048]
  int*   candi = (int*)  (ws + ((size_t)46 << 20));     // 21 MB
  // Overlays (regions dead at time of use -- see launch order):
  float* U1 = (float*)(ws + ((size_t)25 << 20));        // 4 MB over candd (dead after merge1)
  float* V1 = (float*)(ws + ((size_t)29 << 20));        // 4 MB
  float* U  = (float*)(ws + ((size_t)46 << 20));        // 8 MB over candi (dead after merge2)
  float* Vv = (float*)(ws + ((size_t)54 << 20));        // 8 MB (ends at 62 MB)
  unsigned short* xhi = (unsigned short*)(ws + ((size_t)62 << 20));  // 2 MB
  unsigned short* xlo = (unsigned short*)(ws + ((size_t)64 << 20));  // 2 MB
  float* sbuf = (float*)(ws + ((size_t)66 << 20));                    // 64 KB

  wprep_kernel<<<224, 256, 0, stream>>>(c2w2, c2w3, c1w2, c1w3,
                                        w2t, w3t, c1w2hi, c1w2lo, c1w3hi, c1w3lo);
  knn1_part<<<512, 256, 0, stream>>>(pos, candd, candi);
  merge_topk2<8, 4><<<256, 256, 0, stream>>>(candd, candi, idx1);
  pre1_kernel<<<4096, 256, 0, stream>>>(pos, c1w1, c1b1, U1, V1);      // overwrites candd region
  conv1_kernel<<<2048, 256, 0, stream>>>(U1, V1, idx1, c1w2hi, c1w2lo, c1b2,
                                         c1w3hi, c1w3lo, c1b3, x1);
  xsplit_kernel<<<512, 256, 0, stream>>>(x1, xhi, xlo, sbuf);
  d2sel_kernel<<<2048, 256, 0, stream>>>(xhi, xlo, sbuf, candd, candi); // U1/V1 dead now
  merge_topk2<16, 8><<<512, 256, 0, stream>>>(candd, candi, idx2);
  pre2_kernel<<<256, 256, 0, stream>>>(x1, c2w1, c2b1, U, Vv);         // overwrites candi region
  conv2_kernel<<<4096, 256, 0, stream>>>(U, Vv, idx2, w2t, c2b2, w3t, c2b3, x2);
  l0_kernel<<<1024, 256, 0, stream>>>(x2, l0w, l0b, gp);
  head_kernel<<<8, 256, 0, stream>>>(gp, l1w, l1b, l2w, l2b, l3w, l3b, out);
}

// Round 9
// 552.950 us; speedup vs baseline: 4.5300x; 1.1795x over previous
//
#include <hip/hip_runtime.h>
#include <hip/hip_bf16.h>
#include <math.h>

#define BB 8
#define NN 2048
#define KK 20

typedef short bf16x8 __attribute__((ext_vector_type(8)));
typedef float f32x4 __attribute__((ext_vector_type(4)));

// fp32 -> bf16 (round-to-nearest-even), finite inputs only
__device__ __forceinline__ unsigned short f2bf(float f) {
  unsigned u = __float_as_uint(f);
  u += 0x7FFFu + ((u >> 16) & 1u);
  return (unsigned short)(u >> 16);
}
__device__ __forceinline__ float bf2f(unsigned short h) {
  return __uint_as_float(((unsigned)h) << 16);
}

// ---------------------------------------------------------------------------
// top-K (K=20) smallest-value tracker (divergent version; used by merge only).
// Strict < keeps the earliest-seen on ties.
// ---------------------------------------------------------------------------
__device__ __forceinline__ void topk_insert(float d, int m, float (&bd)[KK], int (&bi)[KK],
                                            float& worst, int& wslot) {
  if (d < worst) {
#pragma unroll
    for (int j = 0; j < KK; ++j) {
      if (j == wslot) { bd[j] = d; bi[j] = m; }
    }
    float w = -INFINITY;
    int s = 0;
#pragma unroll
    for (int j = 0; j < KK; ++j) {
      if (bd[j] > w) { w = bd[j]; s = j; }
    }
    worst = w;
    wslot = s;
  }
}

// ---------------------------------------------------------------------------
// Branch-free sorted top-20 VALUE list (descending; s[0] = current 20th
// smallest). Insert = min/max chain, 40 VALU ops, self-filtering.
// ---------------------------------------------------------------------------
__device__ __forceinline__ void sins20(float (&s)[KK], float d) {
#pragma unroll
  for (int q = 0; q < KK - 1; ++q) s[q] = fminf(s[q], fmaxf(s[q + 1], d));
  s[KK - 1] = fminf(s[KK - 1], d);
}

// knn1 distance: explicit fmaf composition -> bit-identical across passes.
__device__ __forceinline__ float knn1_dist(float sn, float ssq,
                                           float x0, float x1, float x2,
                                           float y0, float y1, float y2) {
  const float dot = fmaf(x0, y0, fmaf(x1, y1, x2 * y2));
  return fmaf(-2.f, dot, sn + ssq);
}

// ---------------------------------------------------------------------------
// kNN pass 1 for conv1 (D=3), m-chunked. Pass 1: branch-free values-only
// sorted top-20 -> tau. Pass 2: count #(d<tau). Pass 3: emit (d,row):
// all d<tau first (<=19), then d==tau ties in row order, cap 20.
// ---------------------------------------------------------------------------
__global__ __launch_bounds__(256) void knn1_part(const float* __restrict__ pos,
                                                 float* __restrict__ candd,
                                                 int* __restrict__ candi) {
  __shared__ float xs0[256], xs1[256], xs2[256], ss[256];
  const int bid = blockIdx.x;
  const int b = bid >> 6;
  const int nc = (bid >> 3) & 7;
  const int mc = bid & 7;
  const int t = threadIdx.x;
  const float* posb = pos + (size_t)b * NN * 3;
  {
    const int m = mc * 256 + t;
    const float a0 = posb[m * 3 + 0];
    const float a1 = posb[m * 3 + 1];
    const float a2 = posb[m * 3 + 2];
    xs0[t] = a0; xs1[t] = a1; xs2[t] = a2;
    ss[t] = a0 * a0 + a1 * a1 + a2 * a2;
  }
  __syncthreads();
  const int n = nc * 256 + t;
  const float xn0 = posb[n * 3 + 0];
  const float xn1 = posb[n * 3 + 1];
  const float xn2 = posb[n * 3 + 2];
  const float sn = xn0 * xn0 + xn1 * xn1 + xn2 * xn2;

  float s[KK];
#pragma unroll
  for (int q = 0; q < KK; ++q) s[q] = INFINITY;
  for (int lm = 0; lm < 256; lm += 8) {
    float dv[8];
#pragma unroll
    for (int u = 0; u < 8; ++u)
      dv[u] = knn1_dist(sn, ss[lm + u], xn0, xn1, xn2, xs0[lm + u], xs1[lm + u], xs2[lm + u]);
#pragma unroll
    for (int u = 0; u < 8; ++u) sins20(s, dv[u]);
  }
  const float tau = s[0];

  int cA = 0;
  for (int lm = 0; lm < 256; lm += 8) {
#pragma unroll
    for (int u = 0; u < 8; ++u) {
      const float d = knn1_dist(sn, ss[lm + u], xn0, xn1, xn2, xs0[lm + u], xs1[lm + u], xs2[lm + u]);
      cA += (d < tau) ? 1 : 0;
    }
  }

  int posA = 0, posB = cA;   // cA <= 19 by definition of tau
  const int rbase = mc * 256;
  const size_t obase = ((size_t)(b * 8 + mc) * KK) * 2048 + n;
  for (int lm = 0; lm < 256; lm += 8) {
#pragma unroll
    for (int u = 0; u < 8; ++u) {
      const float d = knn1_dist(sn, ss[lm + u], xn0, xn1, xn2, xs0[lm + u], xs1[lm + u], xs2[lm + u]);
      if (d < tau) {
        candd[obase + (size_t)posA * 2048] = d;
        candi[obase + (size_t)posA * 2048] = rbase + lm + u;
        ++posA;
      } else if (d == tau && posB < KK) {
        candd[obase + (size_t)posB * 2048] = d;
        candi[obase + (size_t)posB * 2048] = rbase + lm + u;
        ++posB;
      }
    }
  }
}

// ---------------------------------------------------------------------------
// merge v2: G threads per point; each merges NCH/G chunks (batched loads),
// then a shfl_xor tree combines the G partial lists (unchanged, proven).
// ---------------------------------------------------------------------------
template <int NCH, int G>
__global__ __launch_bounds__(256) void merge_topk2(const float* __restrict__ candd,
                                                   const int* __restrict__ candi,
                                                   int* __restrict__ idx_out) {
  const int gid = blockIdx.x * 256 + threadIdx.x;
  const int pt = gid / G;
  const int sub = gid % G;
  const int b = pt >> 11, n = pt & 2047;
  constexpr int CPT = NCH / G;
  float bd[KK]; int bi[KK];
#pragma unroll
  for (int j = 0; j < KK; ++j) { bd[j] = INFINITY; bi[j] = 0; }
  float worst = INFINITY;
  int wslot = 0;
#pragma unroll
  for (int cc = 0; cc < CPT; ++cc) {
    const int c = sub * CPT + cc;
    const size_t base = ((size_t)(b * NCH + c) * KK) * 2048 + n;
    float dv[KK]; int iv[KK];
#pragma unroll
    for (int j = 0; j < KK; ++j) dv[j] = candd[base + (size_t)j * 2048];
#pragma unroll
    for (int j = 0; j < KK; ++j) iv[j] = candi[base + (size_t)j * 2048];
#pragma unroll
    for (int j = 0; j < KK; ++j) topk_insert(dv[j], iv[j], bd, bi, worst, wslot);
  }
#pragma unroll
  for (int stride = 1; stride < G; stride <<= 1) {
    float od[KK]; int oi[KK];
#pragma unroll
    for (int q = 0; q < KK; ++q) {
      od[q] = __shfl_xor(bd[q], stride);
      oi[q] = __shfl_xor(bi[q], stride);
    }
#pragma unroll
    for (int q = 0; q < KK; ++q) topk_insert(od[q], oi[q], bd, bi, worst, wslot);
  }
  if (sub == 0) {
    int* op = idx_out + (size_t)pt * KK;
#pragma unroll
    for (int j = 0; j < KK; ++j) op[j] = bi[j];
  }
}

// ---------------------------------------------------------------------------
// pre1: per-point factorized conv1 layer-1.
// ---------------------------------------------------------------------------
__global__ __launch_bounds__(256) void pre1_kernel(const float* __restrict__ pos,
                                                   const float* __restrict__ w1,
                                                   const float* __restrict__ b1,
                                                   float* __restrict__ U1,
                                                   float* __restrict__ V1) {
  const int t = threadIdx.x;
  const int c = t & 63;
  const int n = blockIdx.x * 4 + (t >> 6);
  const float p0 = pos[(size_t)n * 3 + 0];
  const float p1 = pos[(size_t)n * 3 + 1];
  const float p2 = pos[(size_t)n * 3 + 2];
  const float wt0 = w1[0 * 64 + c], wt1 = w1[1 * 64 + c], wt2 = w1[2 * 64 + c];
  const float wb0 = w1[3 * 64 + c], wb1 = w1[4 * 64 + c], wb2 = w1[5 * 64 + c];
  float v = p0 * wb0 + p1 * wb1 + p2 * wb2;
  float u = p0 * (wt0 - wb0) + p1 * (wt1 - wb1) + p2 * (wt2 - wb2) + b1[c];
  U1[(size_t)n * 64 + c] = u;
  V1[(size_t)n * 64 + c] = v;
}

// ---------------------------------------------------------------------------
// pre2: per-point factorized conv2 layer-1 (GEMM 16384x128 @ K=64, x2 halves).
// ---------------------------------------------------------------------------
__global__ __launch_bounds__(256) void pre2_kernel(const float* __restrict__ x1,
                                                   const float* __restrict__ w1,
                                                   const float* __restrict__ b1,
                                                   float* __restrict__ U,
                                                   float* __restrict__ V) {
  __shared__ float X[64][68];
  const int nbase = blockIdx.x * 64;
  const int t = threadIdx.x;
  for (int it = t; it < 1024; it += 256) {
    const int r = it >> 4, q = it & 15;
    *(float4*)&X[r][q * 4] = *(const float4*)&x1[(size_t)(nbase + r) * 64 + q * 4];
  }
  __syncthreads();
  const int ty = t >> 4, tx = t & 15;
  const int c0 = tx * 8;
  float accT[4][8], accB[4][8];
#pragma unroll
  for (int u = 0; u < 4; ++u)
#pragma unroll
    for (int i = 0; i < 8; ++i) { accT[u][i] = 0.f; accB[u][i] = 0.f; }
  for (int d0 = 0; d0 < 64; d0 += 4) {
    float4 a[4];
#pragma unroll
    for (int u = 0; u < 4; ++u) a[u] = *(const float4*)&X[ty * 4 + u][d0];
#pragma unroll
    for (int dd = 0; dd < 4; ++dd) {
      const float4 t0 = *(const float4*)&w1[(size_t)(d0 + dd) * 128 + c0];
      const float4 t1 = *(const float4*)&w1[(size_t)(d0 + dd) * 128 + c0 + 4];
      const float4 bb0 = *(const float4*)&w1[(size_t)(64 + d0 + dd) * 128 + c0];
      const float4 bb1 = *(const float4*)&w1[(size_t)(64 + d0 + dd) * 128 + c0 + 4];
#pragma unroll
      for (int u = 0; u < 4; ++u) {
        const float av = (dd == 0) ? a[u].x : (dd == 1) ? a[u].y : (dd == 2) ? a[u].z : a[u].w;
        accT[u][0] = fmaf(av, t0.x, accT[u][0]);
        accT[u][1] = fmaf(av, t0.y, accT[u][1]);
        accT[u][2] = fmaf(av, t0.z, accT[u][2]);
        accT[u][3] = fmaf(av, t0.w, accT[u][3]);
        accT[u][4] = fmaf(av, t1.x, accT[u][4]);
        accT[u][5] = fmaf(av, t1.y, accT[u][5]);
        accT[u][6] = fmaf(av, t1.z, accT[u][6]);
        accT[u][7] = fmaf(av, t1.w, accT[u][7]);
        accB[u][0] = fmaf(av, bb0.x, accB[u][0]);
        accB[u][1] = fmaf(av, bb0.y, accB[u][1]);
        accB[u][2] = fmaf(av, bb0.z, accB[u][2]);
        accB[u][3] = fmaf(av, bb0.w, accB[u][3]);
        accB[u][4] = fmaf(av, bb1.x, accB[u][4]);
        accB[u][5] = fmaf(av, bb1.y, accB[u][5]);
        accB[u][6] = fmaf(av, bb1.z, accB[u][6]);
        accB[u][7] = fmaf(av, bb1.w, accB[u][7]);
      }
    }
  }
  const float4 bA = *(const float4*)&b1[c0];
  const float4 bB = *(const float4*)&b1[c0 + 4];
#pragma unroll
  for (int u = 0; u < 4; ++u) {
    const size_t row = (size_t)(nbase + ty * 4 + u) * 128 + c0;
    float4 u0, u1, v0, v1;
    v0 = make_float4(accB[u][0], accB[u][1], accB[u][2], accB[u][3]);
    v1 = make_float4(accB[u][4], accB[u][5], accB[u][6], accB[u][7]);
    u0.x = accT[u][0] - accB[u][0] + bA.x;
    u0.y = accT[u][1] - accB[u][1] + bA.y;
    u0.z = accT[u][2] - accB[u][2] + bA.z;
    u0.w = accT[u][3] - accB[u][3] + bA.w;
    u1.x = accT[u][4] - accB[u][4] + bB.x;
    u1.y = accT[u][5] - accB[u][5] + bB.y;
    u1.z = accT[u][6] - accB[u][6] + bB.z;
    u1.w = accT[u][7] - accB[u][7] + bB.w;
    *(float4*)&U[row] = u0;
    *(float4*)&U[row + 4] = u1;
    *(float4*)&V[row] = v0;
    *(float4*)&V[row + 4] = v1;
  }
}

// ---------------------------------------------------------------------------
// wprep: transpose+convert weights for MFMA B-fragments.
// ---------------------------------------------------------------------------
__global__ __launch_bounds__(256) void wprep_kernel(
    const float* __restrict__ c2w2, const float* __restrict__ c2w3,
    const float* __restrict__ c1w2, const float* __restrict__ c1w3,
    unsigned short* __restrict__ w2t, unsigned short* __restrict__ w3t,
    unsigned short* __restrict__ c1w2hi, unsigned short* __restrict__ c1w2lo,
    unsigned short* __restrict__ c1w3hi, unsigned short* __restrict__ c1w3lo) {
  const int i = blockIdx.x * 256 + threadIdx.x;
  if (i < 16384) {
    const int d = i >> 7, c = i & 127;
    w2t[c * 128 + d] = f2bf(c2w2[i]);
  } else if (i < 49152) {
    const int j = i - 16384;
    const int d = j >> 8, c = j & 255;
    w3t[c * 128 + d] = f2bf(c2w3[j]);
  } else if (i < 53248) {
    const int j = i - 49152;
    const int d = j >> 6, c = j & 63;
    const float v = c1w2[j];
    const unsigned short h = f2bf(v);
    c1w2hi[c * 64 + d] = h;
    c1w2lo[c * 64 + d] = f2bf(v - bf2f(h));
  } else {
    const int j = i - 53248;
    const int d = j >> 6, c = j & 63;
    const float v = c1w3[j];
    const unsigned short h = f2bf(v);
    c1w3hi[c * 64 + d] = h;
    c1w3lo[c * 64 + d] = f2bf(v - bf2f(h));
  }
}

// ---------------------------------------------------------------------------
// conv1 EdgeConv layers 2,3 via SPLIT-bf16 MFMA (unchanged, proven round 7).
// ---------------------------------------------------------------------------
__global__ __launch_bounds__(256) void conv1_kernel(
    const float* __restrict__ U1, const float* __restrict__ V1,
    const int* __restrict__ idx,
    const unsigned short* __restrict__ w2hi, const unsigned short* __restrict__ w2lo,
    const float* __restrict__ b2,
    const unsigned short* __restrict__ w3hi, const unsigned short* __restrict__ w3lo,
    const float* __restrict__ b3,
    float* __restrict__ xout) {
  __shared__ __align__(16) unsigned short A[160][2][76];
  __shared__ unsigned int pm[8][64];
  const int bid = blockIdx.x;
  const int b = bid >> 8;
  const int pbase = (bid & 255) * 8;
  const int t = threadIdx.x;
  const int wave = t >> 6, lane = t & 63;
  const int lrow = lane & 15;
  const int lk8 = (lane >> 4) * 8;
  const int c = wave * 16 + lrow;

  for (int it = t; it < 2560; it += 256) {
    const int r = it >> 4, q = it & 15;
    const int p = r / 20, k = r - (r / 20) * 20;
    const int n = b * NN + pbase + p;
    const int j = b * NN + idx[(size_t)n * KK + k];
    const float4 uv = *(const float4*)&U1[(size_t)n * 64 + q * 4];
    const float4 vv = *(const float4*)&V1[(size_t)j * 64 + q * 4];
    float e[4];
    e[0] = fmaxf(uv.x + vv.x, 0.f);
    e[1] = fmaxf(uv.y + vv.y, 0.f);
    e[2] = fmaxf(uv.z + vv.z, 0.f);
    e[3] = fmaxf(uv.w + vv.w, 0.f);
    ushort4 hi, lo;
    hi.x = f2bf(e[0]); lo.x = f2bf(e[0] - bf2f(hi.x));
    hi.y = f2bf(e[1]); lo.y = f2bf(e[1] - bf2f(hi.y));
    hi.z = f2bf(e[2]); lo.z = f2bf(e[2] - bf2f(hi.z));
    hi.w = f2bf(e[3]); lo.w = f2bf(e[3] - bf2f(hi.w));
    *(ushort4*)&A[r][0][q * 4] = hi;
    *(ushort4*)&A[r][1][q * 4] = lo;
  }
  for (int i = t; i < 512; i += 256) ((unsigned int*)pm)[i] = 0u;
  __syncthreads();

  {
    bf16x8 whi[2], wlo[2];
#pragma unroll
    for (int ks = 0; ks < 2; ++ks) {
      whi[ks] = *(const bf16x8*)&w2hi[(size_t)c * 64 + ks * 32 + lk8];
      wlo[ks] = *(const bf16x8*)&w2lo[(size_t)c * 64 + ks * 32 + lk8];
    }
    f32x4 acc2[10];
#pragma unroll
    for (int mt = 0; mt < 10; ++mt) {
      bf16x8 ahi[2], alo[2];
#pragma unroll
      for (int ks = 0; ks < 2; ++ks) {
        ahi[ks] = *(const bf16x8*)&A[mt * 16 + lrow][0][ks * 32 + lk8];
        alo[ks] = *(const bf16x8*)&A[mt * 16 + lrow][1][ks * 32 + lk8];
      }
      f32x4 acc = {0.f, 0.f, 0.f, 0.f};
#pragma unroll
      for (int ks = 0; ks < 2; ++ks) {
        acc = __builtin_amdgcn_mfma_f32_16x16x32_bf16(ahi[ks], whi[ks], acc, 0, 0, 0);
        acc = __builtin_amdgcn_mfma_f32_16x16x32_bf16(ahi[ks], wlo[ks], acc, 0, 0, 0);
        acc = __builtin_amdgcn_mfma_f32_16x16x32_bf16(alo[ks], whi[ks], acc, 0, 0, 0);
      }
      acc2[mt] = acc;
    }
    __syncthreads();
    const float bias = b2[c];
#pragma unroll
    for (int mt = 0; mt < 10; ++mt) {
      const int r0 = mt * 16 + ((lane >> 4) << 2);
#pragma unroll
      for (int reg = 0; reg < 4; ++reg) {
        const float v = fmaxf(acc2[mt][reg] + bias, 0.f);
        const unsigned short h = f2bf(v);
        A[r0 + reg][0][c] = h;
        A[r0 + reg][1][c] = f2bf(v - bf2f(h));
      }
    }
  }
  __syncthreads();

  {
    bf16x8 whi[2], wlo[2];
#pragma unroll
    for (int ks = 0; ks < 2; ++ks) {
      whi[ks] = *(const bf16x8*)&w3hi[(size_t)c * 64 + ks * 32 + lk8];
      wlo[ks] = *(const bf16x8*)&w3lo[(size_t)c * 64 + ks * 32 + lk8];
    }
    const float bias = b3[c];
#pragma unroll
    for (int mt = 0; mt < 10; ++mt) {
      bf16x8 ahi[2], alo[2];
#pragma unroll
      for (int ks = 0; ks < 2; ++ks) {
        ahi[ks] = *(const bf16x8*)&A[mt * 16 + lrow][0][ks * 32 + lk8];
        alo[ks] = *(const bf16x8*)&A[mt * 16 + lrow][1][ks * 32 + lk8];
      }
      f32x4 acc = {0.f, 0.f, 0.f, 0.f};
#pragma unroll
      for (int ks = 0; ks < 2; ++ks) {
        acc = __builtin_amdgcn_mfma_f32_16x16x32_bf16(ahi[ks], whi[ks], acc, 0, 0, 0);
        acc = __builtin_amdgcn_mfma_f32_16x16x32_bf16(ahi[ks], wlo[ks], acc, 0, 0, 0);
        acc = __builtin_amdgcn_mfma_f32_16x16x32_bf16(alo[ks], whi[ks], acc, 0, 0, 0);
      }
      const int r0 = mt * 16 + ((lane >> 4) << 2);
      const float v0 = fmaxf(acc[0] + bias, 0.f);
      const float v1 = fmaxf(acc[1] + bias, 0.f);
      const float v2 = fmaxf(acc[2] + bias, 0.f);
      const float v3 = fmaxf(acc[3] + bias, 0.f);
      if (r0 / 20 == (r0 + 3) / 20) {
        atomicMax(&pm[r0 / 20][c], __float_as_uint(fmaxf(fmaxf(v0, v1), fmaxf(v2, v3))));
      } else {
        atomicMax(&pm[(r0 + 0) / 20][c], __float_as_uint(v0));
        atomicMax(&pm[(r0 + 1) / 20][c], __float_as_uint(v1));
        atomicMax(&pm[(r0 + 2) / 20][c], __float_as_uint(v2));
        atomicMax(&pm[(r0 + 3) / 20][c], __float_as_uint(v3));
      }
    }
  }
  __syncthreads();

  {
    const int p = t >> 5;
    const int cc = (t & 31) * 2;
    float2 o;
    o.x = __uint_as_float(pm[p][cc]);
    o.y = __uint_as_float(pm[p][cc + 1]);
    *(float2*)&xout[((size_t)(b * NN + pbase + p)) * 64 + cc] = o;
  }
}

// ---------------------------------------------------------------------------
// xsplit: x1 (fp32) -> xhi/xlo (split bf16) + s = sum(x^2) fp32.
// ---------------------------------------------------------------------------
__global__ __launch_bounds__(256) void xsplit_kernel(const float* __restrict__ x1,
                                                     unsigned short* __restrict__ xhi,
                                                     unsigned short* __restrict__ xlo,
                                                     float* __restrict__ s) {
  const int e = blockIdx.x * 256 + threadIdx.x;  // 131072 total
  const int n = e >> 3, q = e & 7;
  const float4 v0 = *(const float4*)&x1[(size_t)n * 64 + q * 8];
  const float4 v1 = *(const float4*)&x1[(size_t)n * 64 + q * 8 + 4];
  float ps = v0.x * v0.x + v0.y * v0.y + v0.z * v0.z + v0.w * v0.w +
             v1.x * v1.x + v1.y * v1.y + v1.z * v1.z + v1.w * v1.w;
  ps += __shfl_xor(ps, 1);
  ps += __shfl_xor(ps, 2);
  ps += __shfl_xor(ps, 4);
  if (q == 0) s[n] = ps;
  const float vv[8] = {v0.x, v0.y, v0.z, v0.w, v1.x, v1.y, v1.z, v1.w};
  unsigned short hb[8], lb[8];
#pragma unroll
  for (int i = 0; i < 8; ++i) {
    hb[i] = f2bf(vv[i]);
    lb[i] = f2bf(vv[i] - bf2f(hb[i]));
  }
  *(ushort4*)&xhi[(size_t)n * 64 + q * 8] = make_ushort4(hb[0], hb[1], hb[2], hb[3]);
  *(ushort4*)&xhi[(size_t)n * 64 + q * 8 + 4] = make_ushort4(hb[4], hb[5], hb[6], hb[7]);
  *(ushort4*)&xlo[(size_t)n * 64 + q * 8] = make_ushort4(lb[0], lb[1], lb[2], lb[3]);
  *(ushort4*)&xlo[(size_t)n * 64 + q * 8 + 4] = make_ushort4(lb[4], lb[5], lb[6], lb[7]);
}

// ---------------------------------------------------------------------------
// d2 + fused partial selection, split-bf16 MFMA GEMM. Selection: branch-free
// values-only sorted top-20, SNAPSHOT pair-merge (shfl all 20 first, THEN
// insert -- race-free), tau, then count + two-category emission.
// ---------------------------------------------------------------------------
__global__ __launch_bounds__(256) void d2sel_kernel(const unsigned short* __restrict__ xhi,
                                                    const unsigned short* __restrict__ xlo,
                                                    const float* __restrict__ s,
                                                    float* __restrict__ candd,
                                                    int* __restrict__ candi) {
  __shared__ __align__(16) unsigned short SBUF[4 * 128 * 72];
  __shared__ float sA[128], sB[128];
  float (*Tt)[132] = (float(*)[132])SBUF;
  const int bid = blockIdx.x;
  const int b = bid >> 8;
  const int tile = bid & 255;
  const int ti = tile >> 4, tj = tile & 15;
  const int i0 = ti * 128, j0 = tj * 128;
  const int gb = b * NN;
  const int t = threadIdx.x;
  const int wave = t >> 6, lane = t & 63;
  const int lrow = lane & 15;
  const int lk8 = (lane >> 4) * 8;

  for (int it = t; it < 4096; it += 256) {
    const int part = it >> 10;           // 0:AH 1:AL 2:BH 3:BL
    const int r = (it >> 3) & 127;
    const int g = it & 7;
    const unsigned short* src = (part == 0) ? xhi : (part == 1) ? xlo
                               : (part == 2) ? xhi : xlo;
    const int base = (part < 2) ? i0 : j0;
    *(uint4*)&SBUF[part * 9216 + r * 72 + g * 8] =
        *(const uint4*)&src[((size_t)(gb + base + r)) * 64 + g * 8];
  }
  if (t < 128) sA[t] = s[gb + i0 + t];
  else sB[t - 128] = s[gb + j0 + (t - 128)];
  __syncthreads();

  // ---- GEMM: acc[mt][nt] = x_i . x_j via 3-term split MFMA
  bf16x8 ahi[2][2], alo[2][2];
#pragma unroll
  for (int mt = 0; mt < 2; ++mt) {
    const int r = wave * 32 + mt * 16 + lrow;
#pragma unroll
    for (int ks = 0; ks < 2; ++ks) {
      ahi[mt][ks] = *(const bf16x8*)&SBUF[0 * 9216 + r * 72 + ks * 32 + lk8];
      alo[mt][ks] = *(const bf16x8*)&SBUF[1 * 9216 + r * 72 + ks * 32 + lk8];
    }
  }
  f32x4 acc[2][8];
#pragma unroll
  for (int mt = 0; mt < 2; ++mt)
#pragma unroll
    for (int nt = 0; nt < 8; ++nt) acc[mt][nt] = (f32x4){0.f, 0.f, 0.f, 0.f};
#pragma unroll
  for (int nt = 0; nt < 8; ++nt) {
    bf16x8 bhi[2], blo[2];
#pragma unroll
    for (int ks = 0; ks < 2; ++ks) {
      bhi[ks] = *(const bf16x8*)&SBUF[2 * 9216 + (nt * 16 + lrow) * 72 + ks * 32 + lk8];
      blo[ks] = *(const bf16x8*)&SBUF[3 * 9216 + (nt * 16 + lrow) * 72 + ks * 32 + lk8];
    }
#pragma unroll
    for (int mt = 0; mt < 2; ++mt) {
#pragma unroll
      for (int ks = 0; ks < 2; ++ks) {
        acc[mt][nt] = __builtin_amdgcn_mfma_f32_16x16x32_bf16(ahi[mt][ks], bhi[ks], acc[mt][nt], 0, 0, 0);
        acc[mt][nt] = __builtin_amdgcn_mfma_f32_16x16x32_bf16(ahi[mt][ks], blo[ks], acc[mt][nt], 0, 0, 0);
        acc[mt][nt] = __builtin_amdgcn_mfma_f32_16x16x32_bf16(alo[mt][ks], bhi[ks], acc[mt][nt], 0, 0, 0);
      }
    }
  }
  __syncthreads();   // all stage reads done before Tt overlays SBUF

  // ---- Tt[j][i] = sA[i] + sB[j] - 2*dot (float4 stores along i)
#pragma unroll
  for (int mt = 0; mt < 2; ++mt) {
    const int ib = wave * 32 + mt * 16 + ((lane >> 4) << 2);
#pragma unroll
    for (int nt = 0; nt < 8; ++nt) {
      const int jj = nt * 16 + lrow;
      const float sj = sB[jj];
      float4 o;
      o.x = sA[ib + 0] + sj - 2.f * acc[mt][nt][0];
      o.y = sA[ib + 1] + sj - 2.f * acc[mt][nt][1];
      o.z = sA[ib + 2] + sj - 2.f * acc[mt][nt][2];
      o.w = sA[ib + 3] + sj - 2.f * acc[mt][nt][3];
      *(float4*)&Tt[jj][ib] = o;
    }
  }
  __syncthreads();

  // ---- pass 1: branch-free values-only sorted top-20 over own 64 rows
  const int j = t >> 1, h = t & 1;
  float sl[KK];
#pragma unroll
  for (int q = 0; q < KK; ++q) sl[q] = INFINITY;
  for (int r4 = 0; r4 < 16; ++r4) {
    const float4 v = *(const float4*)&Tt[j][h * 64 + r4 * 4];
    sins20(sl, v.x);
    sins20(sl, v.y);
    sins20(sl, v.z);
    sins20(sl, v.w);
  }
  // pair-merge: SNAPSHOT partner's full list first (race-free), then insert
  {
    float od[KK];
#pragma unroll
    for (int q = 0; q < KK; ++q) od[q] = __shfl_xor(sl[q], 1);
#pragma unroll
    for (int q = 0; q < KK; ++q) sins20(sl, od[q]);
  }
  const float tau = sl[0];

  // ---- pass 2: counts
  int cA = 0, cB = 0;
  for (int r4 = 0; r4 < 16; ++r4) {
    const float4 v = *(const float4*)&Tt[j][h * 64 + r4 * 4];
    cA += (v.x < tau) + (v.y < tau) + (v.z < tau) + (v.w < tau);
    cB += (v.x == tau) + (v.y == tau) + (v.z == tau) + (v.w == tau);
  }
  const int pA = __shfl_xor(cA, 1);
  const int pB = __shfl_xor(cB, 1);
  const int nA = cA + pA;               // <= 19 by definition of tau
  int posA = h ? pA : 0;
  int posB = nA + (h ? pB : 0);

  // ---- pass 3: emission (A: all d<tau in row order; B: d==tau capped at 20)
  const size_t obase = ((size_t)(b * 16 + ti) * KK) * 2048 + (j0 + j);
  for (int r4 = 0; r4 < 16; ++r4) {
    const float4 v = *(const float4*)&Tt[j][h * 64 + r4 * 4];
    const float dd[4] = {v.x, v.y, v.z, v.w};
#pragma unroll
    for (int u = 0; u < 4; ++u) {
      const float d = dd[u];
      const int row = i0 + h * 64 + r4 * 4 + u;
      if (d < tau) {
        candd[obase + (size_t)posA * 2048] = d;
        candi[obase + (size_t)posA * 2048] = row;
        ++posA;
      } else if (d == tau && posB < KK) {
        candd[obase + (size_t)posB * 2048] = d;
        candi[obase + (size_t)posB * 2048] = row;
        ++posB;
      }
    }
  }
}

// ---------------------------------------------------------------------------
// conv2 EdgeConv layers 2,3 via bf16 MFMA (unchanged, proven round 4).
// ---------------------------------------------------------------------------
__global__ __launch_bounds__(256) void conv2_kernel(
    const float* __restrict__ U, const float* __restrict__ V,
    const int* __restrict__ idx,
    const unsigned short* __restrict__ w2t, const float* __restrict__ b2,
    const unsigned short* __restrict__ w3t, const float* __restrict__ b3,
    float* __restrict__ xout) {
  __shared__ __align__(16) unsigned short E[80][136];
  __shared__ __align__(16) unsigned short E2[80][136];
  __shared__ unsigned int pm[4][256];
  const int bid = blockIdx.x;
  const int b = bid >> 9;
  const int pbase = (bid & 511) * 4;
  const int t = threadIdx.x;
  const int wave = t >> 6, lane = t & 63;
  const int lrow = lane & 15;
  const int lk8 = (lane >> 4) * 8;

  for (int it = t; it < 2560; it += 256) {
    const int r = it >> 5, q = it & 31;
    const int p = r / 20, k = r - (r / 20) * 20;
    const int n = b * NN + pbase + p;
    const int j = b * NN + idx[(size_t)n * KK + k];
    const float4 uv = *(const float4*)&U[(size_t)n * 128 + q * 4];
    const float4 vv = *(const float4*)&V[(size_t)j * 128 + q * 4];
    ushort4 h;
    h.x = f2bf(fmaxf(uv.x + vv.x, 0.f));
    h.y = f2bf(fmaxf(uv.y + vv.y, 0.f));
    h.z = f2bf(fmaxf(uv.z + vv.z, 0.f));
    h.w = f2bf(fmaxf(uv.w + vv.w, 0.f));
    *(ushort4*)&E[r][q * 4] = h;
  }
  for (int i = t; i < 1024; i += 256) ((unsigned int*)pm)[i] = 0u;
  __syncthreads();

  {
    bf16x8 wf[2][4];
#pragma unroll
    for (int nt2 = 0; nt2 < 2; ++nt2) {
      const int ntg = wave * 2 + nt2;
#pragma unroll
      for (int ks = 0; ks < 4; ++ks)
        wf[nt2][ks] = *(const bf16x8*)&w2t[(size_t)(ntg * 16 + lrow) * 128 + ks * 32 + lk8];
    }
    const float bias0 = b2[wave * 32 + lrow];
    const float bias1 = b2[wave * 32 + 16 + lrow];
#pragma unroll
    for (int mt = 0; mt < 5; ++mt) {
      bf16x8 af[4];
#pragma unroll
      for (int ks = 0; ks < 4; ++ks)
        af[ks] = *(const bf16x8*)&E[mt * 16 + lrow][ks * 32 + lk8];
      f32x4 acc0 = {0.f, 0.f, 0.f, 0.f};
      f32x4 acc1 = {0.f, 0.f, 0.f, 0.f};
#pragma unroll
      for (int ks = 0; ks < 4; ++ks) {
        acc0 = __builtin_amdgcn_mfma_f32_16x16x32_bf16(af[ks], wf[0][ks], acc0, 0, 0, 0);
        acc1 = __builtin_amdgcn_mfma_f32_16x16x32_bf16(af[ks], wf[1][ks], acc1, 0, 0, 0);
      }
      const int r0 = mt * 16 + ((lane >> 4) << 2);
      const int c0 = wave * 32 + lrow;
#pragma unroll
      for (int reg = 0; reg < 4; ++reg) {
        E2[r0 + reg][c0]      = f2bf(fmaxf(acc0[reg] + bias0, 0.f));
        E2[r0 + reg][c0 + 16] = f2bf(fmaxf(acc1[reg] + bias1, 0.f));
      }
    }
  }
  __syncthreads();

  {
    bf16x8 wf[4][4];
#pragma unroll
    for (int nt4 = 0; nt4 < 4; ++nt4) {
      const int ntg = wave * 4 + nt4;
#pragma unroll
      for (int ks = 0; ks < 4; ++ks)
        wf[nt4][ks] = *(const bf16x8*)&w3t[(size_t)(ntg * 16 + lrow) * 128 + ks * 32 + lk8];
    }
#pragma unroll
    for (int mt = 0; mt < 5; ++mt) {
      bf16x8 af[4];
#pragma unroll
      for (int ks = 0; ks < 4; ++ks)
        af[ks] = *(const bf16x8*)&E2[mt * 16 + lrow][ks * 32 + lk8];
      f32x4 acc[4];
#pragma unroll
      for (int nt4 = 0; nt4 < 4; ++nt4) acc[nt4] = (f32x4){0.f, 0.f, 0.f, 0.f};
#pragma unroll
      for (int ks = 0; ks < 4; ++ks) {
#pragma unroll
        for (int nt4 = 0; nt4 < 4; ++nt4)
          acc[nt4] = __builtin_amdgcn_mfma_f32_16x16x32_bf16(af[ks], wf[nt4][ks], acc[nt4], 0, 0, 0);
      }
      const int r0 = mt * 16 + ((lane >> 4) << 2);
      const int pa = r0 / 20;
      const int pb = (r0 + 3) / 20;
#pragma unroll
      for (int nt4 = 0; nt4 < 4; ++nt4) {
        const int c = wave * 64 + nt4 * 16 + lrow;
        const float bias = b3[c];
        float v0 = fmaxf(acc[nt4][0] + bias, 0.f);
        float v1 = fmaxf(acc[nt4][1] + bias, 0.f);
        float v2 = fmaxf(acc[nt4][2] + bias, 0.f);
        float v3 = fmaxf(acc[nt4][3] + bias, 0.f);
        if (pa == pb) {
          atomicMax(&pm[pa][c], __float_as_uint(fmaxf(fmaxf(v0, v1), fmaxf(v2, v3))));
        } else {
          atomicMax(&pm[(r0 + 0) / 20][c], __float_as_uint(v0));
          atomicMax(&pm[(r0 + 1) / 20][c], __float_as_uint(v1));
          atomicMax(&pm[(r0 + 2) / 20][c], __float_as_uint(v2));
          atomicMax(&pm[(r0 + 3) / 20][c], __float_as_uint(v3));
        }
      }
    }
  }
  __syncthreads();

  {
    const int p = t >> 6;
    const int c0 = (t & 63) * 4;
    const float4 o = *(const float4*)&pm[p][c0];
    *(float4*)&xout[((size_t)b * NN + pbase + p) * 256 + c0] = o;
  }
}

// ---------------------------------------------------------------------------
// l0 GEMM (16384x512 @ K=256) + relu + per-64-row max partials (unchanged).
// ---------------------------------------------------------------------------
__global__ __launch_bounds__(256) void l0_kernel(const float* __restrict__ x2,
                                                 const float* __restrict__ w,
                                                 const float* __restrict__ bias,
                                                 float* __restrict__ gp) {
  __shared__ float A[64][68];
  __shared__ float red[16][128];
  const int bid = blockIdx.x;
  const int b = bid >> 7;
  const int mblk = (bid >> 2) & 31;
  const int cblk = bid & 3;
  const int t = threadIdx.x;
  const int ty = t >> 4, tx = t & 15;
  const float* xb = x2 + ((size_t)b * NN + mblk * 64) * 256;
  float acc[4][8];
#pragma unroll
  for (int u = 0; u < 4; ++u)
#pragma unroll
    for (int i = 0; i < 8; ++i) acc[u][i] = 0.f;
  for (int kc = 0; kc < 4; ++kc) {
    {
      const int r = t >> 2, seg = (t & 3) * 16;
#pragma unroll
      for (int s4 = 0; s4 < 4; ++s4) {
        *(float4*)&A[r][seg + s4 * 4] =
            *(const float4*)&xb[(size_t)r * 256 + kc * 64 + seg + s4 * 4];
      }
    }
    __syncthreads();
    for (int d0 = 0; d0 < 64; d0 += 4) {
      float4 a[4];
#pragma unroll
      for (int u = 0; u < 4; ++u) a[u] = *(const float4*)&A[ty * 4 + u][d0];
#pragma unroll
      for (int dd = 0; dd < 4; ++dd) {
        const size_t wrow = (size_t)(kc * 64 + d0 + dd) * 512 + cblk * 128 + tx * 8;
        const float4 wA = *(const float4*)&w[wrow];
        const float4 wB = *(const float4*)&w[wrow + 4];
#pragma unroll
        for (int u = 0; u < 4; ++u) {
          const float av = (dd == 0) ? a[u].x : (dd == 1) ? a[u].y : (dd == 2) ? a[u].z : a[u].w;
          acc[u][0] = fmaf(av, wA.x, acc[u][0]);
          acc[u][1] = fmaf(av, wA.y, acc[u][1]);
          acc[u][2] = fmaf(av, wA.z, acc[u][2]);
          acc[u][3] = fmaf(av, wA.w, acc[u][3]);
          acc[u][4] = fmaf(av, wB.x, acc[u][4]);
          acc[u][5] = fmaf(av, wB.y, acc[u][5]);
          acc[u][6] = fmaf(av, wB.z, acc[u][6]);
          acc[u][7] = fmaf(av, wB.w, acc[u][7]);
        }
      }
    }
    __syncthreads();
  }
  {
    float4 m0, m1;
    m0.x = fmaxf(fmaxf(acc[0][0], acc[1][0]), fmaxf(acc[2][0], acc[3][0]));
    m0.y = fmaxf(fmaxf(acc[0][1], acc[1][1]), fmaxf(acc[2][1], acc[3][1]));
    m0.z = fmaxf(fmaxf(acc[0][2], acc[1][2]), fmaxf(acc[2][2], acc[3][2]));
    m0.w = fmaxf(fmaxf(acc[0][3], acc[1][3]), fmaxf(acc[2][3], acc[3][3]));
    m1.x = fmaxf(fmaxf(acc[0][4], acc[1][4]), fmaxf(acc[2][4], acc[3][4]));
    m1.y = fmaxf(fmaxf(acc[0][5], acc[1][5]), fmaxf(acc[2][5], acc[3][5]));
    m1.z = fmaxf(fmaxf(acc[0][6], acc[1][6]), fmaxf(acc[2][6], acc[3][6]));
    m1.w = fmaxf(fmaxf(acc[0][7], acc[1][7]), fmaxf(acc[2][7], acc[3][7]));
    *(float4*)&red[ty][tx * 8] = m0;
    *(float4*)&red[ty][tx * 8 + 4] = m1;
  }
  __syncthreads();
  if (t < 128) {
    float m = red[0][t];
#pragma unroll
    for (int q = 1; q < 16; ++q) m = fmaxf(m, red[q][t]);
    m = fmaxf(m + bias[cblk * 128 + t], 0.f);
    gp[((size_t)b * 32 + mblk) * 512 + cblk * 128 + t] = m;
  }
}

// ---------------------------------------------------------------------------
// final pool-reduce (32 partials) + classifier head + log_softmax (unchanged).
// ---------------------------------------------------------------------------
__global__ __launch_bounds__(256) void head_kernel(
    const float* __restrict__ gp,
    const float* __restrict__ l1w, const float* __restrict__ l1b,
    const float* __restrict__ l2w, const float* __restrict__ l2b,
    const float* __restrict__ l3w, const float* __restrict__ l3b,
    float* __restrict__ out) {
  __shared__ float g[512];
  __shared__ float h1[256];
  __shared__ float h2[256];
  __shared__ float logits[40];
  __shared__ float lse_s;
  const int b = blockIdx.x;
  const int t = threadIdx.x;
  for (int cidx = t; cidx < 512; cidx += 256) {
    float m = gp[(size_t)(b * 32) * 512 + cidx];
    for (int ch = 1; ch < 32; ++ch) m = fmaxf(m, gp[(size_t)(b * 32 + ch) * 512 + cidx]);
    g[cidx] = m;
  }
  __syncthreads();
  {
    float acc = 0.f;
    for (int d = 0; d < 512; d += 4) {
      const float4 gv = *(const float4*)&g[d];
      acc = fmaf(gv.x, l1w[(size_t)d * 256 + t], acc);
      acc = fmaf(gv.y, l1w[(size_t)(d + 1) * 256 + t], acc);
      acc = fmaf(gv.z, l1w[(size_t)(d + 2) * 256 + t], acc);
      acc = fmaf(gv.w, l1w[(size_t)(d + 3) * 256 + t], acc);
    }
    h1[t] = fmaxf(acc + l1b[t], 0.f);
  }
  __syncthreads();
  {
    float acc = 0.f;
    for (int d = 0; d < 256; d += 4) {
      const float4 hv = *(const float4*)&h1[d];
      acc = fmaf(hv.x, l2w[(size_t)d * 256 + t], acc);
      acc = fmaf(hv.y, l2w[(size_t)(d + 1) * 256 + t], acc);
      acc = fmaf(hv.z, l2w[(size_t)(d + 2) * 256 + t], acc);
      acc = fmaf(hv.w, l2w[(size_t)(d + 3) * 256 + t], acc);
    }
    h2[t] = fmaxf(acc + l2b[t], 0.f);
  }
  __syncthreads();
  if (t < 40) {
    float acc = 0.f;
    for (int d = 0; d < 256; ++d) acc = fmaf(h2[d], l3w[(size_t)d * 40 + t], acc);
    logits[t] = acc + l3b[t];
  }
  __syncthreads();
  if (t == 0) {
    float M = -INFINITY;
    for (int j = 0; j < 40; ++j) M = fmaxf(M, logits[j]);
    float ssum = 0.f;
    for (int j = 0; j < 40; ++j) ssum += expf(logits[j] - M);
    lse_s = M + logf(ssum);
  }
  __syncthreads();
  if (t < 40) out[(size_t)b * 40 + t] = logits[t] - lse_s;
}

// ---------------------------------------------------------------------------
extern "C" void kernel_launch(void* const* d_in, const int* in_sizes, int n_in,
                              void* d_out, int out_size, void* d_ws, size_t ws_size,
                              hipStream_t stream) {
  const float* pos  = (const float*)d_in[0];
  const float* c1w1 = (const float*)d_in[2];
  const float* c1b1 = (const float*)d_in[3];
  const float* c1w2 = (const float*)d_in[4];
  const float* c1b2 = (const float*)d_in[5];
  const float* c1w3 = (const float*)d_in[6];
  const float* c1b3 = (const float*)d_in[7];
  const float* c2w1 = (const float*)d_in[8];
  const float* c2b1 = (const float*)d_in[9];
  const float* c2w2 = (const float*)d_in[10];
  const float* c2b2 = (const float*)d_in[11];
  const float* c2w3 = (const float*)d_in[12];
  const float* c2b3 = (const float*)d_in[13];
  const float* l0w  = (const float*)d_in[14];
  const float* l0b  = (const float*)d_in[15];
  const float* l1w  = (const float*)d_in[16];
  const float* l1b  = (const float*)d_in[17];
  const float* l2w  = (const float*)d_in[18];
  const float* l2b  = (const float*)d_in[19];
  const float* l3w  = (const float*)d_in[20];
  const float* l3b  = (const float*)d_in[21];
  float* out = (float*)d_out;

  char* ws = (char*)d_ws;
  float* x1    = (float*)(ws + 0);                      // 4 MB    [8,2048,64]
  float* x2    = (float*)(ws + ((size_t)4 << 20));      // 16 MB   [8,2048,256]
  int*   idx1  = (int*)  (ws + ((size_t)20 << 20));     // 1.31 MB [16384,20]
  int*   idx2  = (int*)  (ws + ((size_t)22 << 20));     // 1.31 MB
  float* gp    = (float*)(ws + ((size_t)24 << 20));     // 512 KB  [8,32,512]
  unsigned short* w2t    = (unsigned short*)(ws + ((size_t)24 << 20) + (512 << 10)); // 32 KB
  unsigned short* w3t    = (unsigned short*)(ws + ((size_t)24 << 20) + (544 << 10)); // 64 KB
  unsigned short* c1w2hi = (unsigned short*)(ws + ((size_t)24 << 20) + (608 << 10)); // 8 KB
  unsigned short* c1w2lo = (unsigned short*)(ws + ((size_t)24 << 20) + (616 << 10)); // 8 KB
  unsigned short* c1w3hi = (unsigned short*)(ws + ((size_t)24 << 20) + (624 << 10)); // 8 KB
  unsigned short* c1w3lo = (unsigned short*)(ws + ((size_t)24 << 20) + (632 << 10)); // 8 KB
  float* candd = (float*)(ws + ((size_t)25 << 20));     // 21 MB   [8,16,20,2048]
  int*   candi = (int*)  (ws + ((size_t)46 << 20));     // 21 MB
  // Overlays (regions dead at time of use -- see launch order):
  float* U1 = (float*)(ws + ((size_t)25 << 20));        // 4 MB over candd (dead after merge1)
  float* V1 = (float*)(ws + ((size_t)29 << 20));        // 4 MB
  float* U  = (float*)(ws + ((size_t)46 << 20));        // 8 MB over candi (dead after merge2)
  float* Vv = (float*)(ws + ((size_t)54 << 20));        // 8 MB (ends at 62 MB)
  unsigned short* xhi = (unsigned short*)(ws + ((size_t)62 << 20));  // 2 MB
  unsigned short* xlo = (unsigned short*)(ws + ((size_t)64 << 20));  // 2 MB
  float* sbuf = (float*)(ws + ((size_t)66 << 20));                    // 64 KB

  wprep_kernel<<<224, 256, 0, stream>>>(c2w2, c2w3, c1w2, c1w3,
                                        w2t, w3t, c1w2hi, c1w2lo, c1w3hi, c1w3lo);
  knn1_part<<<512, 256, 0, stream>>>(pos, candd, candi);
  merge_topk2<8, 4><<<256, 256, 0, stream>>>(candd, candi, idx1);
  pre1_kernel<<<4096, 256, 0, stream>>>(pos, c1w1, c1b1, U1, V1);      // overwrites candd region
  conv1_kernel<<<2048, 256, 0, stream>>>(U1, V1, idx1, c1w2hi, c1w2lo, c1b2,
                                         c1w3hi, c1w3lo, c1b3, x1);
  xsplit_kernel<<<512, 256, 0, stream>>>(x1, xhi, xlo, sbuf);
  d2sel_kernel<<<2048, 256, 0, stream>>>(xhi, xlo, sbuf, candd, candi); // U1/V1 dead now
  merge_topk2<16, 8><<<512, 256, 0, stream>>>(candd, candi, idx2);
  pre2_kernel<<<256, 256, 0, stream>>>(x1, c2w1, c2b1, U, Vv);         // overwrites candi region
  conv2_kernel<<<4096, 256, 0, stream>>>(U, Vv, idx2, w2t, c2b2, w3t, c2b3, x2);
  l0_kernel<<<1024, 256, 0, stream>>>(x2, l0w, l0b, gp);
  head_kernel<<<8, 256, 0, stream>>>(gp, l1w, l1b, l2w, l2b, l3w, l3b, out);
}

// Round 10
// 492.534 us; speedup vs baseline: 5.0857x; 1.1227x over previous
//
#include <hip/hip_runtime.h>
#include <hip/hip_bf16.h>
#include <math.h>

#define BB 8
#define NN 2048
#define KK 20

typedef short bf16x8 __attribute__((ext_vector_type(8)));
typedef float f32x4 __attribute__((ext_vector_type(4)));

// fp32 -> bf16 (round-to-nearest-even), finite inputs only
__device__ __forceinline__ unsigned short f2bf(float f) {
  unsigned u = __float_as_uint(f);
  u += 0x7FFFu + ((u >> 16) & 1u);
  return (unsigned short)(u >> 16);
}
__device__ __forceinline__ float bf2f(unsigned short h) {
  return __uint_as_float(((unsigned)h) << 16);
}

// ---------------------------------------------------------------------------
// top-K (K=20) smallest-value tracker (divergent; used by merge only).
// ---------------------------------------------------------------------------
__device__ __forceinline__ void topk_insert(float d, int m, float (&bd)[KK], int (&bi)[KK],
                                            float& worst, int& wslot) {
  if (d < worst) {
#pragma unroll
    for (int j = 0; j < KK; ++j) {
      if (j == wslot) { bd[j] = d; bi[j] = m; }
    }
    float w = -INFINITY;
    int s = 0;
#pragma unroll
    for (int j = 0; j < KK; ++j) {
      if (bd[j] > w) { w = bd[j]; s = j; }
    }
    worst = w;
    wslot = s;
  }
}

// ---------------------------------------------------------------------------
// Branch-free sorted top-20 VALUE list (descending; s[0] = current 20th
// smallest). Insert = min/max chain, self-filtering.
// ---------------------------------------------------------------------------
__device__ __forceinline__ void sins20(float (&s)[KK], float d) {
#pragma unroll
  for (int q = 0; q < KK - 1; ++q) s[q] = fminf(s[q], fmaxf(s[q + 1], d));
  s[KK - 1] = fminf(s[KK - 1], d);
}

// knn1 distance: explicit fmaf composition -> bit-identical across passes.
__device__ __forceinline__ float knn1_dist(float sn, float ssq,
                                           float x0, float x1, float x2,
                                           float y0, float y1, float y2) {
  const float dot = fmaf(x0, y0, fmaf(x1, y1, x2 * y2));
  return fmaf(-2.f, dot, sn + ssq);
}

// ---------------------------------------------------------------------------
// kNN pass 1 for conv1 (D=3), m-chunked; 3-pass tau selection (proven R9).
// ---------------------------------------------------------------------------
__global__ __launch_bounds__(256) void knn1_part(const float* __restrict__ pos,
                                                 float* __restrict__ candd,
                                                 int* __restrict__ candi) {
  __shared__ float xs0[256], xs1[256], xs2[256], ss[256];
  const int bid = blockIdx.x;
  const int b = bid >> 6;
  const int nc = (bid >> 3) & 7;
  const int mc = bid & 7;
  const int t = threadIdx.x;
  const float* posb = pos + (size_t)b * NN * 3;
  {
    const int m = mc * 256 + t;
    const float a0 = posb[m * 3 + 0];
    const float a1 = posb[m * 3 + 1];
    const float a2 = posb[m * 3 + 2];
    xs0[t] = a0; xs1[t] = a1; xs2[t] = a2;
    ss[t] = a0 * a0 + a1 * a1 + a2 * a2;
  }
  __syncthreads();
  const int n = nc * 256 + t;
  const float xn0 = posb[n * 3 + 0];
  const float xn1 = posb[n * 3 + 1];
  const float xn2 = posb[n * 3 + 2];
  const float sn = xn0 * xn0 + xn1 * xn1 + xn2 * xn2;

  float s[KK];
#pragma unroll
  for (int q = 0; q < KK; ++q) s[q] = INFINITY;
  for (int lm = 0; lm < 256; lm += 8) {
    float dv[8];
#pragma unroll
    for (int u = 0; u < 8; ++u)
      dv[u] = knn1_dist(sn, ss[lm + u], xn0, xn1, xn2, xs0[lm + u], xs1[lm + u], xs2[lm + u]);
#pragma unroll
    for (int u = 0; u < 8; ++u) sins20(s, dv[u]);
  }
  const float tau = s[0];

  int cA = 0;
  for (int lm = 0; lm < 256; lm += 8) {
#pragma unroll
    for (int u = 0; u < 8; ++u) {
      const float d = knn1_dist(sn, ss[lm + u], xn0, xn1, xn2, xs0[lm + u], xs1[lm + u], xs2[lm + u]);
      cA += (d < tau) ? 1 : 0;
    }
  }

  int posA = 0, posB = cA;   // cA <= 19 by definition of tau
  const int rbase = mc * 256;
  const size_t obase = ((size_t)(b * 8 + mc) * KK) * 2048 + n;
  for (int lm = 0; lm < 256; lm += 8) {
#pragma unroll
    for (int u = 0; u < 8; ++u) {
      const float d = knn1_dist(sn, ss[lm + u], xn0, xn1, xn2, xs0[lm + u], xs1[lm + u], xs2[lm + u]);
      if (d < tau) {
        candd[obase + (size_t)posA * 2048] = d;
        candi[obase + (size_t)posA * 2048] = rbase + lm + u;
        ++posA;
      } else if (d == tau && posB < KK) {
        candd[obase + (size_t)posB * 2048] = d;
        candi[obase + (size_t)posB * 2048] = rbase + lm + u;
        ++posB;
      }
    }
  }
}

// ---------------------------------------------------------------------------
// merge v2 (unchanged, proven).
// ---------------------------------------------------------------------------
template <int NCH, int G>
__global__ __launch_bounds__(256) void merge_topk2(const float* __restrict__ candd,
                                                   const int* __restrict__ candi,
                                                   int* __restrict__ idx_out) {
  const int gid = blockIdx.x * 256 + threadIdx.x;
  const int pt = gid / G;
  const int sub = gid % G;
  const int b = pt >> 11, n = pt & 2047;
  constexpr int CPT = NCH / G;
  float bd[KK]; int bi[KK];
#pragma unroll
  for (int j = 0; j < KK; ++j) { bd[j] = INFINITY; bi[j] = 0; }
  float worst = INFINITY;
  int wslot = 0;
#pragma unroll
  for (int cc = 0; cc < CPT; ++cc) {
    const int c = sub * CPT + cc;
    const size_t base = ((size_t)(b * NCH + c) * KK) * 2048 + n;
    float dv[KK]; int iv[KK];
#pragma unroll
    for (int j = 0; j < KK; ++j) dv[j] = candd[base + (size_t)j * 2048];
#pragma unroll
    for (int j = 0; j < KK; ++j) iv[j] = candi[base + (size_t)j * 2048];
#pragma unroll
    for (int j = 0; j < KK; ++j) topk_insert(dv[j], iv[j], bd, bi, worst, wslot);
  }
#pragma unroll
  for (int stride = 1; stride < G; stride <<= 1) {
    float od[KK]; int oi[KK];
#pragma unroll
    for (int q = 0; q < KK; ++q) {
      od[q] = __shfl_xor(bd[q], stride);
      oi[q] = __shfl_xor(bi[q], stride);
    }
#pragma unroll
    for (int q = 0; q < KK; ++q) topk_insert(od[q], oi[q], bd, bi, worst, wslot);
  }
  if (sub == 0) {
    int* op = idx_out + (size_t)pt * KK;
#pragma unroll
    for (int j = 0; j < KK; ++j) op[j] = bi[j];
  }
}

// ---------------------------------------------------------------------------
// pre1: per-point factorized conv1 layer-1.
// ---------------------------------------------------------------------------
__global__ __launch_bounds__(256) void pre1_kernel(const float* __restrict__ pos,
                                                   const float* __restrict__ w1,
                                                   const float* __restrict__ b1,
                                                   float* __restrict__ U1,
                                                   float* __restrict__ V1) {
  const int t = threadIdx.x;
  const int c = t & 63;
  const int n = blockIdx.x * 4 + (t >> 6);
  const float p0 = pos[(size_t)n * 3 + 0];
  const float p1 = pos[(size_t)n * 3 + 1];
  const float p2 = pos[(size_t)n * 3 + 2];
  const float wt0 = w1[0 * 64 + c], wt1 = w1[1 * 64 + c], wt2 = w1[2 * 64 + c];
  const float wb0 = w1[3 * 64 + c], wb1 = w1[4 * 64 + c], wb2 = w1[5 * 64 + c];
  float v = p0 * wb0 + p1 * wb1 + p2 * wb2;
  float u = p0 * (wt0 - wb0) + p1 * (wt1 - wb1) + p2 * (wt2 - wb2) + b1[c];
  U1[(size_t)n * 64 + c] = u;
  V1[(size_t)n * 64 + c] = v;
}

// ---------------------------------------------------------------------------
// pre2: per-point factorized conv2 layer-1 (unchanged).
// ---------------------------------------------------------------------------
__global__ __launch_bounds__(256) void pre2_kernel(const float* __restrict__ x1,
                                                   const float* __restrict__ w1,
                                                   const float* __restrict__ b1,
                                                   float* __restrict__ U,
                                                   float* __restrict__ V) {
  __shared__ float X[64][68];
  const int nbase = blockIdx.x * 64;
  const int t = threadIdx.x;
  for (int it = t; it < 1024; it += 256) {
    const int r = it >> 4, q = it & 15;
    *(float4*)&X[r][q * 4] = *(const float4*)&x1[(size_t)(nbase + r) * 64 + q * 4];
  }
  __syncthreads();
  const int ty = t >> 4, tx = t & 15;
  const int c0 = tx * 8;
  float accT[4][8], accB[4][8];
#pragma unroll
  for (int u = 0; u < 4; ++u)
#pragma unroll
    for (int i = 0; i < 8; ++i) { accT[u][i] = 0.f; accB[u][i] = 0.f; }
  for (int d0 = 0; d0 < 64; d0 += 4) {
    float4 a[4];
#pragma unroll
    for (int u = 0; u < 4; ++u) a[u] = *(const float4*)&X[ty * 4 + u][d0];
#pragma unroll
    for (int dd = 0; dd < 4; ++dd) {
      const float4 t0 = *(const float4*)&w1[(size_t)(d0 + dd) * 128 + c0];
      const float4 t1 = *(const float4*)&w1[(size_t)(d0 + dd) * 128 + c0 + 4];
      const float4 bb0 = *(const float4*)&w1[(size_t)(64 + d0 + dd) * 128 + c0];
      const float4 bb1 = *(const float4*)&w1[(size_t)(64 + d0 + dd) * 128 + c0 + 4];
#pragma unroll
      for (int u = 0; u < 4; ++u) {
        const float av = (dd == 0) ? a[u].x : (dd == 1) ? a[u].y : (dd == 2) ? a[u].z : a[u].w;
        accT[u][0] = fmaf(av, t0.x, accT[u][0]);
        accT[u][1] = fmaf(av, t0.y, accT[u][1]);
        accT[u][2] = fmaf(av, t0.z, accT[u][2]);
        accT[u][3] = fmaf(av, t0.w, accT[u][3]);
        accT[u][4] = fmaf(av, t1.x, accT[u][4]);
        accT[u][5] = fmaf(av, t1.y, accT[u][5]);
        accT[u][6] = fmaf(av, t1.z, accT[u][6]);
        accT[u][7] = fmaf(av, t1.w, accT[u][7]);
        accB[u][0] = fmaf(av, bb0.x, accB[u][0]);
        accB[u][1] = fmaf(av, bb0.y, accB[u][1]);
        accB[u][2] = fmaf(av, bb0.z, accB[u][2]);
        accB[u][3] = fmaf(av, bb0.w, accB[u][3]);
        accB[u][4] = fmaf(av, bb1.x, accB[u][4]);
        accB[u][5] = fmaf(av, bb1.y, accB[u][5]);
        accB[u][6] = fmaf(av, bb1.z, accB[u][6]);
        accB[u][7] = fmaf(av, bb1.w, accB[u][7]);
      }
    }
  }
  const float4 bA = *(const float4*)&b1[c0];
  const float4 bB = *(const float4*)&b1[c0 + 4];
#pragma unroll
  for (int u = 0; u < 4; ++u) {
    const size_t row = (size_t)(nbase + ty * 4 + u) * 128 + c0;
    float4 u0, u1, v0, v1;
    v0 = make_float4(accB[u][0], accB[u][1], accB[u][2], accB[u][3]);
    v1 = make_float4(accB[u][4], accB[u][5], accB[u][6], accB[u][7]);
    u0.x = accT[u][0] - accB[u][0] + bA.x;
    u0.y = accT[u][1] - accB[u][1] + bA.y;
    u0.z = accT[u][2] - accB[u][2] + bA.z;
    u0.w = accT[u][3] - accB[u][3] + bA.w;
    u1.x = accT[u][4] - accB[u][4] + bB.x;
    u1.y = accT[u][5] - accB[u][5] + bB.y;
    u1.z = accT[u][6] - accB[u][6] + bB.z;
    u1.w = accT[u][7] - accB[u][7] + bB.w;
    *(float4*)&U[row] = u0;
    *(float4*)&U[row + 4] = u1;
    *(float4*)&V[row] = v0;
    *(float4*)&V[row + 4] = v1;
  }
}

// ---------------------------------------------------------------------------
// wprep: transpose+convert weights for MFMA B-fragments.
//   conv2: w2t/w3t plain bf16. conv1: split hi/lo. l0: split hi/lo [512][256].
// ---------------------------------------------------------------------------
__global__ __launch_bounds__(256) void wprep_kernel(
    const float* __restrict__ c2w2, const float* __restrict__ c2w3,
    const float* __restrict__ c1w2, const float* __restrict__ c1w3,
    const float* __restrict__ l0w,
    unsigned short* __restrict__ w2t, unsigned short* __restrict__ w3t,
    unsigned short* __restrict__ c1w2hi, unsigned short* __restrict__ c1w2lo,
    unsigned short* __restrict__ c1w3hi, unsigned short* __restrict__ c1w3lo,
    unsigned short* __restrict__ l0thi, unsigned short* __restrict__ l0tlo) {
  const int i = blockIdx.x * 256 + threadIdx.x;
  if (i < 16384) {
    const int d = i >> 7, c = i & 127;
    w2t[c * 128 + d] = f2bf(c2w2[i]);
  } else if (i < 49152) {
    const int j = i - 16384;
    const int d = j >> 8, c = j & 255;
    w3t[c * 128 + d] = f2bf(c2w3[j]);
  } else if (i < 53248) {
    const int j = i - 49152;
    const int d = j >> 6, c = j & 63;
    const float v = c1w2[j];
    const unsigned short h = f2bf(v);
    c1w2hi[c * 64 + d] = h;
    c1w2lo[c * 64 + d] = f2bf(v - bf2f(h));
  } else if (i < 57344) {
    const int j = i - 53248;
    const int d = j >> 6, c = j & 63;
    const float v = c1w3[j];
    const unsigned short h = f2bf(v);
    c1w3hi[c * 64 + d] = h;
    c1w3lo[c * 64 + d] = f2bf(v - bf2f(h));
  } else if (i < 188416) {
    const int j = i - 57344;             // < 131072 = 256*512
    const int d = j >> 9, c = j & 511;
    const float v = l0w[j];
    const unsigned short h = f2bf(v);
    l0thi[c * 256 + d] = h;
    l0tlo[c * 256 + d] = f2bf(v - bf2f(h));
  }
}

// ---------------------------------------------------------------------------
// conv1 EdgeConv layers 2,3 via SPLIT-bf16 MFMA (unchanged, proven).
// ---------------------------------------------------------------------------
__global__ __launch_bounds__(256) void conv1_kernel(
    const float* __restrict__ U1, const float* __restrict__ V1,
    const int* __restrict__ idx,
    const unsigned short* __restrict__ w2hi, const unsigned short* __restrict__ w2lo,
    const float* __restrict__ b2,
    const unsigned short* __restrict__ w3hi, const unsigned short* __restrict__ w3lo,
    const float* __restrict__ b3,
    float* __restrict__ xout) {
  __shared__ __align__(16) unsigned short A[160][2][76];
  __shared__ unsigned int pm[8][64];
  const int bid = blockIdx.x;
  const int b = bid >> 8;
  const int pbase = (bid & 255) * 8;
  const int t = threadIdx.x;
  const int wave = t >> 6, lane = t & 63;
  const int lrow = lane & 15;
  const int lk8 = (lane >> 4) * 8;
  const int c = wave * 16 + lrow;

  for (int it = t; it < 2560; it += 256) {
    const int r = it >> 4, q = it & 15;
    const int p = r / 20, k = r - (r / 20) * 20;
    const int n = b * NN + pbase + p;
    const int j = b * NN + idx[(size_t)n * KK + k];
    const float4 uv = *(const float4*)&U1[(size_t)n * 64 + q * 4];
    const float4 vv = *(const float4*)&V1[(size_t)j * 64 + q * 4];
    float e[4];
    e[0] = fmaxf(uv.x + vv.x, 0.f);
    e[1] = fmaxf(uv.y + vv.y, 0.f);
    e[2] = fmaxf(uv.z + vv.z, 0.f);
    e[3] = fmaxf(uv.w + vv.w, 0.f);
    ushort4 hi, lo;
    hi.x = f2bf(e[0]); lo.x = f2bf(e[0] - bf2f(hi.x));
    hi.y = f2bf(e[1]); lo.y = f2bf(e[1] - bf2f(hi.y));
    hi.z = f2bf(e[2]); lo.z = f2bf(e[2] - bf2f(hi.z));
    hi.w = f2bf(e[3]); lo.w = f2bf(e[3] - bf2f(hi.w));
    *(ushort4*)&A[r][0][q * 4] = hi;
    *(ushort4*)&A[r][1][q * 4] = lo;
  }
  for (int i = t; i < 512; i += 256) ((unsigned int*)pm)[i] = 0u;
  __syncthreads();

  {
    bf16x8 whi[2], wlo[2];
#pragma unroll
    for (int ks = 0; ks < 2; ++ks) {
      whi[ks] = *(const bf16x8*)&w2hi[(size_t)c * 64 + ks * 32 + lk8];
      wlo[ks] = *(const bf16x8*)&w2lo[(size_t)c * 64 + ks * 32 + lk8];
    }
    f32x4 acc2[10];
#pragma unroll
    for (int mt = 0; mt < 10; ++mt) {
      bf16x8 ahi[2], alo[2];
#pragma unroll
      for (int ks = 0; ks < 2; ++ks) {
        ahi[ks] = *(const bf16x8*)&A[mt * 16 + lrow][0][ks * 32 + lk8];
        alo[ks] = *(const bf16x8*)&A[mt * 16 + lrow][1][ks * 32 + lk8];
      }
      f32x4 acc = {0.f, 0.f, 0.f, 0.f};
#pragma unroll
      for (int ks = 0; ks < 2; ++ks) {
        acc = __builtin_amdgcn_mfma_f32_16x16x32_bf16(ahi[ks], whi[ks], acc, 0, 0, 0);
        acc = __builtin_amdgcn_mfma_f32_16x16x32_bf16(ahi[ks], wlo[ks], acc, 0, 0, 0);
        acc = __builtin_amdgcn_mfma_f32_16x16x32_bf16(alo[ks], whi[ks], acc, 0, 0, 0);
      }
      acc2[mt] = acc;
    }
    __syncthreads();
    const float bias = b2[c];
#pragma unroll
    for (int mt = 0; mt < 10; ++mt) {
      const int r0 = mt * 16 + ((lane >> 4) << 2);
#pragma unroll
      for (int reg = 0; reg < 4; ++reg) {
        const float v = fmaxf(acc2[mt][reg] + bias, 0.f);
        const unsigned short h = f2bf(v);
        A[r0 + reg][0][c] = h;
        A[r0 + reg][1][c] = f2bf(v - bf2f(h));
      }
    }
  }
  __syncthreads();

  {
    bf16x8 whi[2], wlo[2];
#pragma unroll
    for (int ks = 0; ks < 2; ++ks) {
      whi[ks] = *(const bf16x8*)&w3hi[(size_t)c * 64 + ks * 32 + lk8];
      wlo[ks] = *(const bf16x8*)&w3lo[(size_t)c * 64 + ks * 32 + lk8];
    }
    const float bias = b3[c];
#pragma unroll
    for (int mt = 0; mt < 10; ++mt) {
      bf16x8 ahi[2], alo[2];
#pragma unroll
      for (int ks = 0; ks < 2; ++ks) {
        ahi[ks] = *(const bf16x8*)&A[mt * 16 + lrow][0][ks * 32 + lk8];
        alo[ks] = *(const bf16x8*)&A[mt * 16 + lrow][1][ks * 32 + lk8];
      }
      f32x4 acc = {0.f, 0.f, 0.f, 0.f};
#pragma unroll
      for (int ks = 0; ks < 2; ++ks) {
        acc = __builtin_amdgcn_mfma_f32_16x16x32_bf16(ahi[ks], whi[ks], acc, 0, 0, 0);
        acc = __builtin_amdgcn_mfma_f32_16x16x32_bf16(ahi[ks], wlo[ks], acc, 0, 0, 0);
        acc = __builtin_amdgcn_mfma_f32_16x16x32_bf16(alo[ks], whi[ks], acc, 0, 0, 0);
      }
      const int r0 = mt * 16 + ((lane >> 4) << 2);
      const float v0 = fmaxf(acc[0] + bias, 0.f);
      const float v1 = fmaxf(acc[1] + bias, 0.f);
      const float v2 = fmaxf(acc[2] + bias, 0.f);
      const float v3 = fmaxf(acc[3] + bias, 0.f);
      if (r0 / 20 == (r0 + 3) / 20) {
        atomicMax(&pm[r0 / 20][c], __float_as_uint(fmaxf(fmaxf(v0, v1), fmaxf(v2, v3))));
      } else {
        atomicMax(&pm[(r0 + 0) / 20][c], __float_as_uint(v0));
        atomicMax(&pm[(r0 + 1) / 20][c], __float_as_uint(v1));
        atomicMax(&pm[(r0 + 2) / 20][c], __float_as_uint(v2));
        atomicMax(&pm[(r0 + 3) / 20][c], __float_as_uint(v3));
      }
    }
  }
  __syncthreads();

  {
    const int p = t >> 5;
    const int cc = (t & 31) * 2;
    float2 o;
    o.x = __uint_as_float(pm[p][cc]);
    o.y = __uint_as_float(pm[p][cc + 1]);
    *(float2*)&xout[((size_t)(b * NN + pbase + p)) * 64 + cc] = o;
  }
}

// ---------------------------------------------------------------------------
// xsplit: x1 (fp32) -> xhi/xlo (split bf16) + s = sum(x^2) fp32.
// ---------------------------------------------------------------------------
__global__ __launch_bounds__(256) void xsplit_kernel(const float* __restrict__ x1,
                                                     unsigned short* __restrict__ xhi,
                                                     unsigned short* __restrict__ xlo,
                                                     float* __restrict__ s) {
  const int e = blockIdx.x * 256 + threadIdx.x;  // 131072 total
  const int n = e >> 3, q = e & 7;
  const float4 v0 = *(const float4*)&x1[(size_t)n * 64 + q * 8];
  const float4 v1 = *(const float4*)&x1[(size_t)n * 64 + q * 8 + 4];
  float ps = v0.x * v0.x + v0.y * v0.y + v0.z * v0.z + v0.w * v0.w +
             v1.x * v1.x + v1.y * v1.y + v1.z * v1.z + v1.w * v1.w;
  ps += __shfl_xor(ps, 1);
  ps += __shfl_xor(ps, 2);
  ps += __shfl_xor(ps, 4);
  if (q == 0) s[n] = ps;
  const float vv[8] = {v0.x, v0.y, v0.z, v0.w, v1.x, v1.y, v1.z, v1.w};
  unsigned short hb[8], lb[8];
#pragma unroll
  for (int i = 0; i < 8; ++i) {
    hb[i] = f2bf(vv[i]);
    lb[i] = f2bf(vv[i] - bf2f(hb[i]));
  }
  *(ushort4*)&xhi[(size_t)n * 64 + q * 8] = make_ushort4(hb[0], hb[1], hb[2], hb[3]);
  *(ushort4*)&xhi[(size_t)n * 64 + q * 8 + 4] = make_ushort4(hb[4], hb[5], hb[6], hb[7]);
  *(ushort4*)&xlo[(size_t)n * 64 + q * 8] = make_ushort4(lb[0], lb[1], lb[2], lb[3]);
  *(ushort4*)&xlo[(size_t)n * 64 + q * 8 + 4] = make_ushort4(lb[4], lb[5], lb[6], lb[7]);
}

// ---------------------------------------------------------------------------
// d2 + fused partial selection (unchanged, proven R9).
// ---------------------------------------------------------------------------
__global__ __launch_bounds__(256) void d2sel_kernel(const unsigned short* __restrict__ xhi,
                                                    const unsigned short* __restrict__ xlo,
                                                    const float* __restrict__ s,
                                                    float* __restrict__ candd,
                                                    int* __restrict__ candi) {
  __shared__ __align__(16) unsigned short SBUF[4 * 128 * 72];
  __shared__ float sA[128], sB[128];
  float (*Tt)[132] = (float(*)[132])SBUF;
  const int bid = blockIdx.x;
  const int b = bid >> 8;
  const int tile = bid & 255;
  const int ti = tile >> 4, tj = tile & 15;
  const int i0 = ti * 128, j0 = tj * 128;
  const int gb = b * NN;
  const int t = threadIdx.x;
  const int wave = t >> 6, lane = t & 63;
  const int lrow = lane & 15;
  const int lk8 = (lane >> 4) * 8;

  for (int it = t; it < 4096; it += 256) {
    const int part = it >> 10;           // 0:AH 1:AL 2:BH 3:BL
    const int r = (it >> 3) & 127;
    const int g = it & 7;
    const unsigned short* src = (part == 0) ? xhi : (part == 1) ? xlo
                               : (part == 2) ? xhi : xlo;
    const int base = (part < 2) ? i0 : j0;
    *(uint4*)&SBUF[part * 9216 + r * 72 + g * 8] =
        *(const uint4*)&src[((size_t)(gb + base + r)) * 64 + g * 8];
  }
  if (t < 128) sA[t] = s[gb + i0 + t];
  else sB[t - 128] = s[gb + j0 + (t - 128)];
  __syncthreads();

  bf16x8 ahi[2][2], alo[2][2];
#pragma unroll
  for (int mt = 0; mt < 2; ++mt) {
    const int r = wave * 32 + mt * 16 + lrow;
#pragma unroll
    for (int ks = 0; ks < 2; ++ks) {
      ahi[mt][ks] = *(const bf16x8*)&SBUF[0 * 9216 + r * 72 + ks * 32 + lk8];
      alo[mt][ks] = *(const bf16x8*)&SBUF[1 * 9216 + r * 72 + ks * 32 + lk8];
    }
  }
  f32x4 acc[2][8];
#pragma unroll
  for (int mt = 0; mt < 2; ++mt)
#pragma unroll
    for (int nt = 0; nt < 8; ++nt) acc[mt][nt] = (f32x4){0.f, 0.f, 0.f, 0.f};
#pragma unroll
  for (int nt = 0; nt < 8; ++nt) {
    bf16x8 bhi[2], blo[2];
#pragma unroll
    for (int ks = 0; ks < 2; ++ks) {
      bhi[ks] = *(const bf16x8*)&SBUF[2 * 9216 + (nt * 16 + lrow) * 72 + ks * 32 + lk8];
      blo[ks] = *(const bf16x8*)&SBUF[3 * 9216 + (nt * 16 + lrow) * 72 + ks * 32 + lk8];
    }
#pragma unroll
    for (int mt = 0; mt < 2; ++mt) {
#pragma unroll
      for (int ks = 0; ks < 2; ++ks) {
        acc[mt][nt] = __builtin_amdgcn_mfma_f32_16x16x32_bf16(ahi[mt][ks], bhi[ks], acc[mt][nt], 0, 0, 0);
        acc[mt][nt] = __builtin_amdgcn_mfma_f32_16x16x32_bf16(ahi[mt][ks], blo[ks], acc[mt][nt], 0, 0, 0);
        acc[mt][nt] = __builtin_amdgcn_mfma_f32_16x16x32_bf16(alo[mt][ks], bhi[ks], acc[mt][nt], 0, 0, 0);
      }
    }
  }
  __syncthreads();   // all stage reads done before Tt overlays SBUF

#pragma unroll
  for (int mt = 0; mt < 2; ++mt) {
    const int ib = wave * 32 + mt * 16 + ((lane >> 4) << 2);
#pragma unroll
    for (int nt = 0; nt < 8; ++nt) {
      const int jj = nt * 16 + lrow;
      const float sj = sB[jj];
      float4 o;
      o.x = sA[ib + 0] + sj - 2.f * acc[mt][nt][0];
      o.y = sA[ib + 1] + sj - 2.f * acc[mt][nt][1];
      o.z = sA[ib + 2] + sj - 2.f * acc[mt][nt][2];
      o.w = sA[ib + 3] + sj - 2.f * acc[mt][nt][3];
      *(float4*)&Tt[jj][ib] = o;
    }
  }
  __syncthreads();

  const int j = t >> 1, h = t & 1;
  float sl[KK];
#pragma unroll
  for (int q = 0; q < KK; ++q) sl[q] = INFINITY;
  for (int r4 = 0; r4 < 16; ++r4) {
    const float4 v = *(const float4*)&Tt[j][h * 64 + r4 * 4];
    sins20(sl, v.x);
    sins20(sl, v.y);
    sins20(sl, v.z);
    sins20(sl, v.w);
  }
  {
    float od[KK];
#pragma unroll
    for (int q = 0; q < KK; ++q) od[q] = __shfl_xor(sl[q], 1);
#pragma unroll
    for (int q = 0; q < KK; ++q) sins20(sl, od[q]);
  }
  const float tau = sl[0];

  int cA = 0, cB = 0;
  for (int r4 = 0; r4 < 16; ++r4) {
    const float4 v = *(const float4*)&Tt[j][h * 64 + r4 * 4];
    cA += (v.x < tau) + (v.y < tau) + (v.z < tau) + (v.w < tau);
    cB += (v.x == tau) + (v.y == tau) + (v.z == tau) + (v.w == tau);
  }
  const int pA = __shfl_xor(cA, 1);
  const int pB = __shfl_xor(cB, 1);
  const int nA = cA + pA;
  int posA = h ? pA : 0;
  int posB = nA + (h ? pB : 0);

  const size_t obase = ((size_t)(b * 16 + ti) * KK) * 2048 + (j0 + j);
  for (int r4 = 0; r4 < 16; ++r4) {
    const float4 v = *(const float4*)&Tt[j][h * 64 + r4 * 4];
    const float dd[4] = {v.x, v.y, v.z, v.w};
#pragma unroll
    for (int u = 0; u < 4; ++u) {
      const float d = dd[u];
      const int row = i0 + h * 64 + r4 * 4 + u;
      if (d < tau) {
        candd[obase + (size_t)posA * 2048] = d;
        candi[obase + (size_t)posA * 2048] = row;
        ++posA;
      } else if (d == tau && posB < KK) {
        candd[obase + (size_t)posB * 2048] = d;
        candi[obase + (size_t)posB * 2048] = row;
        ++posB;
      }
    }
  }
}

// ---------------------------------------------------------------------------
// conv2 EdgeConv layers 2,3 via bf16 MFMA; IN-PLACE E (layer-2 accs reg-
// buffered, conv1-proven pattern) -> 25.9 KB LDS. Epilogue emits split-bf16
// x2hi/x2lo directly for the MFMA l0.
// ---------------------------------------------------------------------------
__global__ __launch_bounds__(256) void conv2_kernel(
    const float* __restrict__ U, const float* __restrict__ V,
    const int* __restrict__ idx,
    const unsigned short* __restrict__ w2t, const float* __restrict__ b2,
    const unsigned short* __restrict__ w3t, const float* __restrict__ b3,
    unsigned short* __restrict__ x2hi, unsigned short* __restrict__ x2lo) {
  __shared__ __align__(16) unsigned short E[80][136];
  __shared__ unsigned int pm[4][256];
  const int bid = blockIdx.x;
  const int b = bid >> 9;
  const int pbase = (bid & 511) * 4;
  const int t = threadIdx.x;
  const int wave = t >> 6, lane = t & 63;
  const int lrow = lane & 15;
  const int lk8 = (lane >> 4) * 8;

  for (int it = t; it < 2560; it += 256) {
    const int r = it >> 5, q = it & 31;
    const int p = r / 20, k = r - (r / 20) * 20;
    const int n = b * NN + pbase + p;
    const int j = b * NN + idx[(size_t)n * KK + k];
    const float4 uv = *(const float4*)&U[(size_t)n * 128 + q * 4];
    const float4 vv = *(const float4*)&V[(size_t)j * 128 + q * 4];
    ushort4 h;
    h.x = f2bf(fmaxf(uv.x + vv.x, 0.f));
    h.y = f2bf(fmaxf(uv.y + vv.y, 0.f));
    h.z = f2bf(fmaxf(uv.z + vv.z, 0.f));
    h.w = f2bf(fmaxf(uv.w + vv.w, 0.f));
    *(ushort4*)&E[r][q * 4] = h;
  }
  for (int i = t; i < 1024; i += 256) ((unsigned int*)pm)[i] = 0u;
  __syncthreads();

  // ---- layer 2: [80x128] @ [128x128], in-place (accs reg-buffered)
  {
    bf16x8 wf[2][4];
#pragma unroll
    for (int nt2 = 0; nt2 < 2; ++nt2) {
      const int ntg = wave * 2 + nt2;
#pragma unroll
      for (int ks = 0; ks < 4; ++ks)
        wf[nt2][ks] = *(const bf16x8*)&w2t[(size_t)(ntg * 16 + lrow) * 128 + ks * 32 + lk8];
    }
    f32x4 a0buf[5], a1buf[5];
#pragma unroll
    for (int mt = 0; mt < 5; ++mt) {
      bf16x8 af[4];
#pragma unroll
      for (int ks = 0; ks < 4; ++ks)
        af[ks] = *(const bf16x8*)&E[mt * 16 + lrow][ks * 32 + lk8];
      f32x4 acc0 = {0.f, 0.f, 0.f, 0.f};
      f32x4 acc1 = {0.f, 0.f, 0.f, 0.f};
#pragma unroll
      for (int ks = 0; ks < 4; ++ks) {
        acc0 = __builtin_amdgcn_mfma_f32_16x16x32_bf16(af[ks], wf[0][ks], acc0, 0, 0, 0);
        acc1 = __builtin_amdgcn_mfma_f32_16x16x32_bf16(af[ks], wf[1][ks], acc1, 0, 0, 0);
      }
      a0buf[mt] = acc0;
      a1buf[mt] = acc1;
    }
    __syncthreads();   // all layer-2 E reads done before overwrite
    const float bias0 = b2[wave * 32 + lrow];
    const float bias1 = b2[wave * 32 + 16 + lrow];
#pragma unroll
    for (int mt = 0; mt < 5; ++mt) {
      const int r0 = mt * 16 + ((lane >> 4) << 2);
      const int c0 = wave * 32 + lrow;
#pragma unroll
      for (int reg = 0; reg < 4; ++reg) {
        E[r0 + reg][c0]      = f2bf(fmaxf(a0buf[mt][reg] + bias0, 0.f));
        E[r0 + reg][c0 + 16] = f2bf(fmaxf(a1buf[mt][reg] + bias1, 0.f));
      }
    }
  }
  __syncthreads();

  // ---- layer 3: [80x128] @ [128x256], relu+bias, max over edges into pm
  {
    bf16x8 wf[4][4];
#pragma unroll
    for (int nt4 = 0; nt4 < 4; ++nt4) {
      const int ntg = wave * 4 + nt4;
#pragma unroll
      for (int ks = 0; ks < 4; ++ks)
        wf[nt4][ks] = *(const bf16x8*)&w3t[(size_t)(ntg * 16 + lrow) * 128 + ks * 32 + lk8];
    }
#pragma unroll
    for (int mt = 0; mt < 5; ++mt) {
      bf16x8 af[4];
#pragma unroll
      for (int ks = 0; ks < 4; ++ks)
        af[ks] = *(const bf16x8*)&E[mt * 16 + lrow][ks * 32 + lk8];
      f32x4 acc[4];
#pragma unroll
      for (int nt4 = 0; nt4 < 4; ++nt4) acc[nt4] = (f32x4){0.f, 0.f, 0.f, 0.f};
#pragma unroll
      for (int ks = 0; ks < 4; ++ks) {
#pragma unroll
        for (int nt4 = 0; nt4 < 4; ++nt4)
          acc[nt4] = __builtin_amdgcn_mfma_f32_16x16x32_bf16(af[ks], wf[nt4][ks], acc[nt4], 0, 0, 0);
      }
      const int r0 = mt * 16 + ((lane >> 4) << 2);
      const int pa = r0 / 20;
      const int pb = (r0 + 3) / 20;
#pragma unroll
      for (int nt4 = 0; nt4 < 4; ++nt4) {
        const int c = wave * 64 + nt4 * 16 + lrow;
        const float bias = b3[c];
        float v0 = fmaxf(acc[nt4][0] + bias, 0.f);
        float v1 = fmaxf(acc[nt4][1] + bias, 0.f);
        float v2 = fmaxf(acc[nt4][2] + bias, 0.f);
        float v3 = fmaxf(acc[nt4][3] + bias, 0.f);
        if (pa == pb) {
          atomicMax(&pm[pa][c], __float_as_uint(fmaxf(fmaxf(v0, v1), fmaxf(v2, v3))));
        } else {
          atomicMax(&pm[(r0 + 0) / 20][c], __float_as_uint(v0));
          atomicMax(&pm[(r0 + 1) / 20][c], __float_as_uint(v1));
          atomicMax(&pm[(r0 + 2) / 20][c], __float_as_uint(v2));
          atomicMax(&pm[(r0 + 3) / 20][c], __float_as_uint(v3));
        }
      }
    }
  }
  __syncthreads();

  // ---- write split-bf16 x2 (values >= 0)
  {
    const int p = t >> 6;
    const int c0 = (t & 63) * 4;
    const float4 o = *(const float4*)&pm[p][c0];
    ushort4 hi, lo;
    hi.x = f2bf(o.x); lo.x = f2bf(o.x - bf2f(hi.x));
    hi.y = f2bf(o.y); lo.y = f2bf(o.y - bf2f(hi.y));
    hi.z = f2bf(o.z); lo.z = f2bf(o.z - bf2f(hi.z));
    hi.w = f2bf(o.w); lo.w = f2bf(o.w - bf2f(hi.w));
    const size_t base = ((size_t)b * NN + pbase + p) * 256 + c0;
    *(ushort4*)&x2hi[base] = hi;
    *(ushort4*)&x2lo[base] = lo;
  }
}

// ---------------------------------------------------------------------------
// l0 via split-bf16 MFMA: [16384x512] @ K=256, fused relu + per-64-row max
// partials. Grid: 8 b x 32 mblk(64 rows) x 2 cblk(256 cols). Wave owns 4
// N-tiles x all 4 M-tiles; K staged in 64-chunks in LDS.
// ---------------------------------------------------------------------------
__global__ __launch_bounds__(256) void l0_kernel(
    const unsigned short* __restrict__ x2hi, const unsigned short* __restrict__ x2lo,
    const unsigned short* __restrict__ l0thi, const unsigned short* __restrict__ l0tlo,
    const float* __restrict__ bias, float* __restrict__ gp) {
  __shared__ __align__(16) unsigned short Ahi[64][72];
  __shared__ __align__(16) unsigned short Alo[64][72];
  __shared__ unsigned int pm[256];
  const int bid = blockIdx.x;
  const int cblk = bid & 1;
  const int mblk = (bid >> 1) & 31;
  const int b = bid >> 6;
  const int t = threadIdx.x;
  const int wave = t >> 6, lane = t & 63;
  const int lrow = lane & 15;
  const int lk8 = (lane >> 4) * 8;
  const size_t rowbase = (size_t)(b * NN + mblk * 64);
  const int cbase = cblk * 256;

  pm[t] = 0u;

  f32x4 acc[4][4];
#pragma unroll
  for (int mt = 0; mt < 4; ++mt)
#pragma unroll
    for (int nt = 0; nt < 4; ++nt) acc[mt][nt] = (f32x4){0.f, 0.f, 0.f, 0.f};

  for (int kc = 0; kc < 4; ++kc) {
    for (int it = t; it < 1024; it += 256) {
      const int buf = it >> 9;
      const int r = (it >> 3) & 63;
      const int g = it & 7;
      const unsigned short* src = buf ? x2lo : x2hi;
      const uint4 v = *(const uint4*)&src[(rowbase + r) * 256 + kc * 64 + g * 8];
      if (buf) *(uint4*)&Alo[r][g * 8] = v;
      else     *(uint4*)&Ahi[r][g * 8] = v;
    }
    __syncthreads();

    bf16x8 bhi[4][2], blo[4][2];
#pragma unroll
    for (int nt = 0; nt < 4; ++nt) {
      const size_t c = (size_t)(cbase + wave * 64 + nt * 16 + lrow);
#pragma unroll
      for (int ks = 0; ks < 2; ++ks) {
        bhi[nt][ks] = *(const bf16x8*)&l0thi[c * 256 + kc * 64 + ks * 32 + lk8];
        blo[nt][ks] = *(const bf16x8*)&l0tlo[c * 256 + kc * 64 + ks * 32 + lk8];
      }
    }
#pragma unroll
    for (int mt = 0; mt < 4; ++mt) {
      bf16x8 ahi[2], alo[2];
#pragma unroll
      for (int ks = 0; ks < 2; ++ks) {
        ahi[ks] = *(const bf16x8*)&Ahi[mt * 16 + lrow][ks * 32 + lk8];
        alo[ks] = *(const bf16x8*)&Alo[mt * 16 + lrow][ks * 32 + lk8];
      }
#pragma unroll
      for (int nt = 0; nt < 4; ++nt) {
#pragma unroll
        for (int ks = 0; ks < 2; ++ks) {
          acc[mt][nt] = __builtin_amdgcn_mfma_f32_16x16x32_bf16(ahi[ks], bhi[nt][ks], acc[mt][nt], 0, 0, 0);
          acc[mt][nt] = __builtin_amdgcn_mfma_f32_16x16x32_bf16(ahi[ks], blo[nt][ks], acc[mt][nt], 0, 0, 0);
          acc[mt][nt] = __builtin_amdgcn_mfma_f32_16x16x32_bf16(alo[ks], bhi[nt][ks], acc[mt][nt], 0, 0, 0);
        }
      }
    }
    __syncthreads();
  }

  // epilogue: bias + relu + max over the 64 rows (each thread: same col for
  // all mt/reg -> local max then one atomicMax per nt)
#pragma unroll
  for (int nt = 0; nt < 4; ++nt) {
    const int cl = wave * 64 + nt * 16 + lrow;
    const float bv = bias[cbase + cl];
    float mx = 0.f;
#pragma unroll
    for (int mt = 0; mt < 4; ++mt)
#pragma unroll
      for (int reg = 0; reg < 4; ++reg)
        mx = fmaxf(mx, fmaxf(acc[mt][nt][reg] + bv, 0.f));
    atomicMax(&pm[cl], __float_as_uint(mx));
  }
  __syncthreads();
  gp[((size_t)(b * 32 + mblk)) * 512 + cbase + t] = __uint_as_float(pm[t]);
}

// ---------------------------------------------------------------------------
// final pool-reduce (32 partials) + classifier head + log_softmax (unchanged).
// ---------------------------------------------------------------------------
__global__ __launch_bounds__(256) void head_kernel(
    const float* __restrict__ gp,
    const float* __restrict__ l1w, const float* __restrict__ l1b,
    const float* __restrict__ l2w, const float* __restrict__ l2b,
    const float* __restrict__ l3w, const float* __restrict__ l3b,
    float* __restrict__ out) {
  __shared__ float g[512];
  __shared__ float h1[256];
  __shared__ float h2[256];
  __shared__ float logits[40];
  __shared__ float lse_s;
  const int b = blockIdx.x;
  const int t = threadIdx.x;
  for (int cidx = t; cidx < 512; cidx += 256) {
    float m = gp[(size_t)(b * 32) * 512 + cidx];
    for (int ch = 1; ch < 32; ++ch) m = fmaxf(m, gp[(size_t)(b * 32 + ch) * 512 + cidx]);
    g[cidx] = m;
  }
  __syncthreads();
  {
    float acc = 0.f;
    for (int d = 0; d < 512; d += 4) {
      const float4 gv = *(const float4*)&g[d];
      acc = fmaf(gv.x, l1w[(size_t)d * 256 + t], acc);
      acc = fmaf(gv.y, l1w[(size_t)(d + 1) * 256 + t], acc);
      acc = fmaf(gv.z, l1w[(size_t)(d + 2) * 256 + t], acc);
      acc = fmaf(gv.w, l1w[(size_t)(d + 3) * 256 + t], acc);
    }
    h1[t] = fmaxf(acc + l1b[t], 0.f);
  }
  __syncthreads();
  {
    float acc = 0.f;
    for (int d = 0; d < 256; d += 4) {
      const float4 hv = *(const float4*)&h1[d];
      acc = fmaf(hv.x, l2w[(size_t)d * 256 + t], acc);
      acc = fmaf(hv.y, l2w[(size_t)(d + 1) * 256 + t], acc);
      acc = fmaf(hv.z, l2w[(size_t)(d + 2) * 256 + t], acc);
      acc = fmaf(hv.w, l2w[(size_t)(d + 3) * 256 + t], acc);
    }
    h2[t] = fmaxf(acc + l2b[t], 0.f);
  }
  __syncthreads();
  if (t < 40) {
    float acc = 0.f;
    for (int d = 0; d < 256; ++d) acc = fmaf(h2[d], l3w[(size_t)d * 40 + t], acc);
    logits[t] = acc + l3b[t];
  }
  __syncthreads();
  if (t == 0) {
    float M = -INFINITY;
    for (int j = 0; j < 40; ++j) M = fmaxf(M, logits[j]);
    float ssum = 0.f;
    for (int j = 0; j < 40; ++j) ssum += expf(logits[j] - M);
    lse_s = M + logf(ssum);
  }
  __syncthreads();
  if (t < 40) out[(size_t)b * 40 + t] = logits[t] - lse_s;
}

// ---------------------------------------------------------------------------
extern "C" void kernel_launch(void* const* d_in, const int* in_sizes, int n_in,
                              void* d_out, int out_size, void* d_ws, size_t ws_size,
                              hipStream_t stream) {
  const float* pos  = (const float*)d_in[0];
  const float* c1w1 = (const float*)d_in[2];
  const float* c1b1 = (const float*)d_in[3];
  const float* c1w2 = (const float*)d_in[4];
  const float* c1b2 = (const float*)d_in[5];
  const float* c1w3 = (const float*)d_in[6];
  const float* c1b3 = (const float*)d_in[7];
  const float* c2w1 = (const float*)d_in[8];
  const float* c2b1 = (const float*)d_in[9];
  const float* c2w2 = (const float*)d_in[10];
  const float* c2b2 = (const float*)d_in[11];
  const float* c2w3 = (const float*)d_in[12];
  const float* c2b3 = (const float*)d_in[13];
  const float* l0w  = (const float*)d_in[14];
  const float* l0b  = (const float*)d_in[15];
  const float* l1w  = (const float*)d_in[16];
  const float* l1b  = (const float*)d_in[17];
  const float* l2w  = (const float*)d_in[18];
  const float* l2b  = (const float*)d_in[19];
  const float* l3w  = (const float*)d_in[20];
  const float* l3b  = (const float*)d_in[21];
  float* out = (float*)d_out;

  char* ws = (char*)d_ws;
  float* x1    = (float*)(ws + 0);                      // 4 MB    [8,2048,64]
  int*   idx1  = (int*)  (ws + ((size_t)20 << 20));     // 1.31 MB [16384,20]
  int*   idx2  = (int*)  (ws + ((size_t)22 << 20));     // 1.31 MB
  float* gp    = (float*)(ws + ((size_t)24 << 20));     // 512 KB  [8,32,512]
  unsigned short* w2t    = (unsigned short*)(ws + ((size_t)24 << 20) + (512 << 10)); // 32 KB
  unsigned short* w3t    = (unsigned short*)(ws + ((size_t)24 << 20) + (544 << 10)); // 64 KB
  unsigned short* c1w2hi = (unsigned short*)(ws + ((size_t)24 << 20) + (608 << 10)); // 8 KB
  unsigned short* c1w2lo = (unsigned short*)(ws + ((size_t)24 << 20) + (616 << 10)); // 8 KB
  unsigned short* c1w3hi = (unsigned short*)(ws + ((size_t)24 << 20) + (624 << 10)); // 8 KB
  unsigned short* c1w3lo = (unsigned short*)(ws + ((size_t)24 << 20) + (632 << 10)); // 8 KB
  float* candd = (float*)(ws + ((size_t)25 << 20));     // 21 MB   [8,16,20,2048]
  int*   candi = (int*)  (ws + ((size_t)46 << 20));     // 21 MB (ends 67 MB)
  // Overlays (regions dead at time of use):
  float* U1 = (float*)(ws + ((size_t)25 << 20));        // 4 MB over candd (dead after merge1)
  float* V1 = (float*)(ws + ((size_t)29 << 20));        // 4 MB
  float* U  = (float*)(ws + ((size_t)46 << 20));        // 8 MB over candi (dead after merge2)
  float* Vv = (float*)(ws + ((size_t)54 << 20));        // 8 MB (ends at 62 MB)
  // Non-overlapping tail (ws >= 153 MB proven in round 1):
  unsigned short* xhi  = (unsigned short*)(ws + ((size_t)68 << 20));  // 2 MB
  unsigned short* xlo  = (unsigned short*)(ws + ((size_t)70 << 20));  // 2 MB
  float*          sbuf = (float*)         (ws + ((size_t)72 << 20));  // 64 KB
  unsigned short* x2hi = (unsigned short*)(ws + ((size_t)73 << 20));  // 8 MB
  unsigned short* x2lo = (unsigned short*)(ws + ((size_t)81 << 20));  // 8 MB
  unsigned short* l0thi = (unsigned short*)(ws + ((size_t)89 << 20));            // 256 KB
  unsigned short* l0tlo = (unsigned short*)(ws + ((size_t)89 << 20) + (256 << 10)); // 256 KB

  wprep_kernel<<<736, 256, 0, stream>>>(c2w2, c2w3, c1w2, c1w3, l0w,
                                        w2t, w3t, c1w2hi, c1w2lo, c1w3hi, c1w3lo,
                                        l0thi, l0tlo);
  knn1_part<<<512, 256, 0, stream>>>(pos, candd, candi);
  merge_topk2<8, 4><<<256, 256, 0, stream>>>(candd, candi, idx1);
  pre1_kernel<<<4096, 256, 0, stream>>>(pos, c1w1, c1b1, U1, V1);      // overwrites candd region
  conv1_kernel<<<2048, 256, 0, stream>>>(U1, V1, idx1, c1w2hi, c1w2lo, c1b2,
                                         c1w3hi, c1w3lo, c1b3, x1);
  xsplit_kernel<<<512, 256, 0, stream>>>(x1, xhi, xlo, sbuf);
  d2sel_kernel<<<2048, 256, 0, stream>>>(xhi, xlo, sbuf, candd, candi); // U1/V1 dead now
  merge_topk2<16, 8><<<512, 256, 0, stream>>>(candd, candi, idx2);
  pre2_kernel<<<256, 256, 0, stream>>>(x1, c2w1, c2b1, U, Vv);         // overwrites candi region
  conv2_kernel<<<4096, 256, 0, stream>>>(U, Vv, idx2, w2t, c2b2, w3t, c2b3, x2hi, x2lo);
  l0_kernel<<<512, 256, 0, stream>>>(x2hi, x2lo, l0thi, l0tlo, l0b, gp);
  head_kernel<<<8, 256, 0, stream>>>(gp, l1w, l1b, l2w, l2b, l3w, l3b, out);
}